// Round 3
// baseline (1072.037 us; speedup 1.0000x reference)
//
#include <hip/hip_runtime.h>
#include <hip/hip_cooperative_groups.h>
#include <math.h>

namespace cg = cooperative_groups;

// Problem constants
constexpr int B = 8;
constexpr int D = 256;     // model dim
constexpr int C = 1024;    // expanded channels
constexpr int H = 32, W = 32;
constexpr int P = H * W;            // 1024 spatial positions
constexpr int M = B * P;            // 8192 rows
constexpr float EPS = 1e-5f;

typedef unsigned short u16;
typedef unsigned int u32;
typedef __attribute__((ext_vector_type(8))) short short8;
typedef __attribute__((ext_vector_type(4))) float floatx4;

// ---------------- workspace layout (in floats) ----------------
constexpr size_t WS_CHSUM1 = 0;                  // 1024
constexpr size_t WS_CHSQ1  = 1024;               // 1024
constexpr size_t WS_GAPSUM = 2048;               // 8192
constexpr size_t WS_CHSUM3 = 10240;              // 256
constexpr size_t WS_CHSQ3  = 10496;              // 256
constexpr size_t WS_CHSUM2 = 10752;              // 1024
constexpr size_t WS_CHSQ2  = 11776;              // 1024
constexpr size_t WS_BSUM2  = 12800;              // 8192
constexpr size_t WS_UMAX2  = 20992;              // 8192 (u32 keys)
constexpr size_t WS_UMAXN2 = 29184;              // 8192 (u32 keys of -min)
constexpr size_t WS_ACC_COUNT = 37376;
constexpr size_t WS_SCALE1 = 37376;              // 1024
constexpr size_t WS_SHIFT1 = 38400;              // 1024
constexpr size_t WS_KW     = 39424;              // 256 (72 used)
constexpr size_t WS_SCALE2 = 39680;              // 1024
constexpr size_t WS_SHIFT2 = 40704;              // 1024
constexpr size_t WS_SATT   = 41728;              // 8192
constexpr size_t WS_AVGO   = 49920;              // 8192
constexpr size_t WS_MAXO   = 58112;              // 8192
constexpr size_t WS_SP     = 66304;              // 8192
constexpr size_t WS_PRE    = 74496;              // 2097152
constexpr size_t WS_T1B    = 2171648;            // bf16 t1
constexpr size_t WS_T2B    = 6365952;            // bf16 t2
constexpr size_t WS_XB     = 10560256;           // bf16 x
constexpr size_t WS_W1B    = 11608832;
constexpr size_t WS_PWB    = 11739904;
constexpr size_t WS_YB     = 11870976;           // (unused now, kept for layout stability)

struct KParams {
    const float *x, *w1, *b1, *g1, *be1, *aw1, *ab1, *aw2, *ab2, *g2, *be2;
    const float *caw1, *caw2, *pw, *pb, *g3, *be3, *sw, *sb;
    float* out;
    float* ws;
};

__device__ __forceinline__ float gelu_exact(float v) {
    return 0.5f * v * (1.0f + erff(v * 0.70710678118654752440f));
}

__device__ __forceinline__ u16 f2bf(float f) {
    u32 u = __float_as_uint(f);
    u += 0x7fff + ((u >> 16) & 1);   // round-to-nearest-even
    return (u16)(u >> 16);
}

__device__ __forceinline__ float bf2f(u16 v) {
    return __uint_as_float(((u32)v) << 16);
}

__device__ __forceinline__ u32 fkey(float f) {
    u32 u = __float_as_uint(f);
    return (u & 0x80000000u) ? ~u : (u | 0x80000000u);
}
__device__ __forceinline__ float fkeyinv(u32 k) {
    return __uint_as_float((k & 0x80000000u) ? (k ^ 0x80000000u) : ~k);
}

#define GLOAD(SRC, DST) __builtin_amdgcn_global_load_lds( \
    (const __attribute__((address_space(1))) void*)(SRC), \
    (__attribute__((address_space(3))) void*)(DST), 16, 0, 0)

// ---------------- Phase 0: zero accumulators + cast fp32 -> bf16 ----------------
__device__ __forceinline__ void phase_cvt(const KParams& p, int bid) {
    const int t = threadIdx.x;
    float* acc_zero = p.ws;
    u16* xb  = (u16*)(p.ws + WS_XB);
    u16* w1b = (u16*)(p.ws + WS_W1B);
    u16* pwb = (u16*)(p.ws + WS_PWB);
    const int stride = gridDim.x * 256;
    for (int i = bid * 256 + t; i < 655360; i += stride) {
        if (i < (int)WS_ACC_COUNT) acc_zero[i] = 0.f;
        const float* src; u16* dst; int off;
        if (i < 524288)      { src = p.x;  dst = xb;  off = i; }
        else if (i < 589824) { src = p.w1; dst = w1b; off = i - 524288; }
        else                 { src = p.pw; dst = pwb; off = i - 589824; }
        const float4 v = *(const float4*)(src + (size_t)off * 4);
        uint2 o;
        o.x = ((u32)f2bf(v.x)) | ((u32)f2bf(v.y) << 16);
        o.y = ((u32)f2bf(v.z)) | ((u32)f2bf(v.w) << 16);
        *(uint2*)(dst + (size_t)off * 4) = o;
    }
}

// ---------------- GEMM phase (BK=32 dbuf, counted vmcnt, XCD swizzle) ----------------
template<int KD, int EPI, int NS, int MB, int NB>
__device__ void phase_gemm(const KParams& p, int bid, u16* smem,
                           const u16* __restrict__ A, const u16* __restrict__ Bw,
                           const float* __restrict__ bias, const float* __restrict__ rowscale,
                           void* __restrict__ outv,
                           float* __restrict__ csum, float* __restrict__ csq,
                           float* __restrict__ gsum) {
    constexpr int MI = MB / 32;
    constexpr int NJ = NB / 32;
    constexpr int ABUF = MB * 32;
    constexpr int BBUF = NB * 32;
    constexpr int BUFSZ = ABUF + BBUF;
    constexpr int GA = MB / 64;
    constexpr int GB = NB / 64;
    constexpr int LD = GA + GB;
    constexpr int NCH = KD / 32;
    constexpr int GX = NS / NB;
    constexpr int NWG = (M / MB) * GX;
    constexpr int CPX = NWG / 8;
    const int t = threadIdx.x;
    const int lane = t & 63;

    const int lin = bid;
    const int swz = (lin & 7) * CPX + (lin >> 3);
    const int bx = swz % GX;
    const int by = swz / GX;
    const int row0 = by * MB;
    const int col0 = bx * NB;

    const int wv = t >> 6;
    const int wrow = (wv >> 1) * (MB / 2);
    const int wcol = (wv & 1) * (NB / 2);
    const int lm = lane & 15;
    const int lk8 = (lane >> 4) * 8;
    const int srow = t >> 2;
    const int scol = (t & 3) * 8;
    const u16* gA = A + (size_t)(row0 + srow) * KD + scol;
    const u16* gB = Bw + (size_t)(col0 + srow) * KD + scol;

    const floatx4 zero = {0.f, 0.f, 0.f, 0.f};
    floatx4 acc[MI][NJ];
#pragma unroll
    for (int i = 0; i < MI; ++i)
#pragma unroll
        for (int j = 0; j < NJ; ++j) acc[i][j] = zero;

    auto stage = [&](u16* buf, int c) {
        const int kk = c * 32;
        u16* As = buf;
        u16* Bs = buf + ABUF;
#pragma unroll
        for (int g = 0; g < GA; ++g)
            GLOAD(gA + (size_t)g * 64 * KD + kk, As + g * 2048 + t * 8);
#pragma unroll
        for (int g = 0; g < GB; ++g)
            GLOAD(gB + (size_t)g * 64 * KD + kk, Bs + g * 2048 + t * 8);
    };
    auto compute = [&](const u16* buf) {
        const u16* As = buf;
        const u16* Bs = buf + ABUF;
        short8 af[MI], bf[NJ];
#pragma unroll
        for (int i = 0; i < MI; ++i)
            af[i] = *(const short8*)(As + (wrow + i * 16 + lm) * 32 + lk8);
#pragma unroll
        for (int j = 0; j < NJ; ++j)
            bf[j] = *(const short8*)(Bs + (wcol + j * 16 + lm) * 32 + lk8);
#pragma unroll
        for (int i = 0; i < MI; ++i)
#pragma unroll
            for (int j = 0; j < NJ; ++j)
                acc[i][j] = __builtin_amdgcn_mfma_f32_16x16x32_bf16(af[i], bf[j], acc[i][j], 0, 0, 0);
    };

    stage(smem, 0);
    for (int c = 0; c < NCH; ++c) {
        u16* curb = smem + (c & 1) * BUFSZ;
        if (c + 1 < NCH) {
            stage(smem + ((c + 1) & 1) * BUFSZ, c + 1);
            if constexpr (LD == 2) asm volatile("s_waitcnt vmcnt(2)" ::: "memory");
            else                   asm volatile("s_waitcnt vmcnt(3)" ::: "memory");
        } else {
            asm volatile("s_waitcnt vmcnt(0)" ::: "memory");
        }
        __builtin_amdgcn_s_barrier();
        compute(curb);
        asm volatile("s_waitcnt lgkmcnt(0)" ::: "memory");
        __builtin_amdgcn_s_barrier();
    }

    float colsum[NJ], colsq[NJ];
#pragma unroll
    for (int j = 0; j < NJ; ++j) { colsum[j] = 0.f; colsq[j] = 0.f; }

    if (EPI == 0) {
        u16* Cs = smem;
#pragma unroll
        for (int i = 0; i < MI; ++i) {
#pragma unroll
            for (int r = 0; r < 4; ++r) {
                const int lrow = wrow + i * 16 + (lane >> 4) * 4 + r;
#pragma unroll
                for (int j = 0; j < NJ; ++j) {
                    const int lcol = wcol + j * 16 + lm;
                    const float tv = gelu_exact(acc[i][j][r] + bias[col0 + lcol]);
                    Cs[lrow * NB + lcol] = f2bf(tv);
                    colsum[j] += tv;
                    colsq[j] = fmaf(tv, tv, colsq[j]);
                }
            }
        }
        __syncthreads();
        constexpr int TPR = NB / 8;
        constexpr int RPP = 256 / TPR;
        u16* outp = (u16*)outv;
#pragma unroll
        for (int pp = 0; pp < MB / RPP; ++pp) {
            const int r = pp * RPP + t / TPR;
            const int cc = (t % TPR) * 8;
            *(uint4*)(outp + (size_t)(row0 + r) * NS + col0 + cc) =
                *(const uint4*)(Cs + r * NB + cc);
        }
    } else {
        float* Cs = (float*)smem;
#pragma unroll
        for (int i = 0; i < MI; ++i) {
#pragma unroll
            for (int r = 0; r < 4; ++r) {
                const int lrow = wrow + i * 16 + (lane >> 4) * 4 + r;
                const float rs = rowscale[row0 + lrow];
#pragma unroll
                for (int j = 0; j < NJ; ++j) {
                    const int lcol = wcol + j * 16 + lm;
                    const float tv = rs * acc[i][j][r] + bias[col0 + lcol];
                    Cs[lrow * NB + lcol] = tv;
                    colsum[j] += tv;
                    colsq[j] = fmaf(tv, tv, colsq[j]);
                }
            }
        }
        __syncthreads();
        constexpr int TPR = NB / 4;
        constexpr int RPP = 256 / TPR;
        float* outp = (float*)outv;
#pragma unroll
        for (int pp = 0; pp < MB / RPP; ++pp) {
            const int r = pp * RPP + t / TPR;
            const int cc = (t % TPR) * 4;
            *(float4*)(outp + (size_t)(row0 + r) * NS + col0 + cc) =
                *(const float4*)(Cs + r * NB + cc);
        }
    }

    const int bb = (by * MB) >> 10;
#pragma unroll
    for (int j = 0; j < NJ; ++j) {
        float s = colsum[j];
        float q = colsq[j];
        s += __shfl_xor(s, 16); s += __shfl_xor(s, 32);
        q += __shfl_xor(q, 16); q += __shfl_xor(q, 32);
        if (lane < 16) {
            const int c = col0 + wcol + j * 16 + lm;
            atomicAdd(&csum[c], s);
            atomicAdd(&csq[c], q);
            if (EPI == 0) atomicAdd(&gsum[bb * NS + c], s);
        }
    }
}

// ---------------- Phase 2: dynamic-kernel MLP + BN1 finalize (blocks 0..7) ----------------
__device__ void phase_dynmlp(const KParams& p, int b, u16* smemu) {
    const int t = threadIdx.x, wave = t >> 6, lane = t & 63;
    float* g  = (float*)smemu;   // 1024
    float* h1 = g + 1024;        // 128
    float* lg = h1 + 128;        // 12
    const float* chsum1 = p.ws + WS_CHSUM1;
    const float* chsq1  = p.ws + WS_CHSQ1;
    const float* gapsum = p.ws + WS_GAPSUM;
    float* scale1 = p.ws + WS_SCALE1;
    float* shift1 = p.ws + WS_SHIFT1;
    float* kw = p.ws + WS_KW;
#pragma unroll
    for (int j = 0; j < 4; ++j) {
        const int c = t + 256 * j;
        const float m = chsum1[c] * (1.0f / (float)M);
        const float var = chsq1[c] * (1.0f / (float)M) - m * m;
        const float sc = rsqrtf(var + EPS) * p.g1[c];
        const float sh = p.be1[c] - m * sc;
        if (b == 0) { scale1[c] = sc; shift1[c] = sh; }
        g[c] = gapsum[b * C + c] * (1.0f / (float)P) * sc + sh;
    }
    __syncthreads();
    for (int k = 0; k < 32; ++k) {
        const int u = wave * 32 + k;
        const float4* wr = (const float4*)(p.aw1 + (size_t)u * C);
        float s = 0.f;
#pragma unroll
        for (int ch = 0; ch < 4; ++ch) {
            const float4 wv = wr[lane + 64 * ch];
            const float4 sv = *(const float4*)(g + 4 * lane + 256 * ch);
            s += wv.x * sv.x + wv.y * sv.y + wv.z * sv.z + wv.w * sv.w;
        }
#pragma unroll
        for (int off = 1; off < 64; off <<= 1) s += __shfl_xor(s, off);
        if (lane == 0) h1[u] = fmaxf(s + p.ab1[u], 0.f);
    }
    __syncthreads();
    if (wave == 0) {
        for (int k9 = 0; k9 < 9; ++k9) {
            float s = p.aw2[k9 * 128 + lane] * h1[lane]
                    + p.aw2[k9 * 128 + 64 + lane] * h1[64 + lane];
#pragma unroll
            for (int off = 1; off < 64; off <<= 1) s += __shfl_xor(s, off);
            if (lane == 0) lg[k9] = s + p.ab2[k9];
        }
    }
    __syncthreads();
    if (t == 0) {
        float mx = lg[0];
        for (int i = 1; i < 9; ++i) mx = fmaxf(mx, lg[i]);
        float e[9], den = 0.f;
        for (int i = 0; i < 9; ++i) { e[i] = expf(lg[i] - mx); den += e[i]; }
        const float inv = 1.0f / den;
        for (int i = 0; i < 9; ++i) kw[b * 9 + i] = e[i] * inv;
    }
}

// ---------------- Phase 3: dyn depthwise conv (24KB LDS, 128-ch chunks, 2 units/block) ----
__device__ void phase_dwconv(const KParams& p, int bid, u16* smemu) {
    u16* rows = smemu;   // 3 rows x 32 w x 128 ch = 24576 B
    const u16* t1b = (const u16*)(p.ws + WS_T1B);
    const float* scale1 = p.ws + WS_SCALE1;
    const float* shift1 = p.ws + WS_SHIFT1;
    const float* kw = p.ws + WS_KW;
    u16* t2b = (u16*)(p.ws + WS_T2B);
    float* chsum2 = p.ws + WS_CHSUM2;
    float* chsq2  = p.ws + WS_CHSQ2;
    float* bsum2  = p.ws + WS_BSUM2;
    u32* umax2  = (u32*)(p.ws + WS_UMAX2);
    u32* umaxn2 = (u32*)(p.ws + WS_UMAXN2);
    const int t = threadIdx.x;

    for (int u = bid; u < 2048; u += gridDim.x) {
        if (u != bid) __syncthreads();       // protect LDS before restage
        const int swz = (u & 7) * 256 + (u >> 3);   // XCD-chunked bijective over 2048
        const int cq = swz & 7;              // 128-channel chunk
        const int bh = swz >> 3;
        const int b = bh >> 5;
        const int h = bh & 31;

        const u16* gbase = t1b + (size_t)b * P * C + cq * 128;
#pragma unroll
        for (int i = 0; i < 6; ++i) {
            const int lin3 = i * 256 + t;
            const int chunk = lin3 >> 4;     // (r*32 + w) in [0,96)
            const int r = chunk >> 5;
            const int w = chunk & 31;
            const int off8 = (lin3 & 15) * 8;
            const int hr = h + r - 1;
            uint4 v = {0u, 0u, 0u, 0u};
            if (hr >= 0 && hr < H)
                v = *(const uint4*)(gbase + (size_t)(hr * W + w) * C + off8);
            *(uint4*)(&rows[chunk * 128 + off8]) = v;
        }
        __syncthreads();

        const int c2 = t & 127;
        const int wh = t >> 7;               // half of the w-range
        const int gc = cq * 128 + c2;
        float kk[9];
#pragma unroll
        for (int i = 0; i < 9; ++i) kk[i] = kw[b * 9 + i];
        const float sc = scale1[gc];
        const float sh = shift1[gc];
        float scm[3], shm[3];
        scm[0] = (h > 0)     ? sc : 0.f;  shm[0] = (h > 0)     ? sh : 0.f;
        scm[1] = sc;                      shm[1] = sh;
        scm[2] = (h < H - 1) ? sc : 0.f;  shm[2] = (h < H - 1) ? sh : 0.f;

        const u16* rp0 = rows + c2;
#define DWVAL(ri, w_) fmaf(bf2f(rp0[((ri) * 32 + (w_)) * 128]), scm[ri], shm[ri])
        const int w0 = wh * 16;
        float vm0 = (w0 > 0) ? DWVAL(0, w0 - 1) : 0.f;
        float vm1 = (w0 > 0) ? DWVAL(1, w0 - 1) : 0.f;
        float vm2 = (w0 > 0) ? DWVAL(2, w0 - 1) : 0.f;
        float vc0 = DWVAL(0, w0), vc1 = DWVAL(1, w0), vc2 = DWVAL(2, w0);
        float vp0 = DWVAL(0, w0 + 1), vp1 = DWVAL(1, w0 + 1), vp2 = DWVAL(2, w0 + 1);

        float s = 0.f, q = 0.f, mx = -INFINITY, mn = INFINITY;
        u16* orow = t2b + ((size_t)b * P + h * W) * C + gc;
        for (int w = w0; w < w0 + 16; ++w) {
            float acc;
            acc = kk[0] * vm0;
            acc = fmaf(kk[1], vc0, acc);
            acc = fmaf(kk[2], vp0, acc);
            acc = fmaf(kk[3], vm1, acc);
            acc = fmaf(kk[4], vc1, acc);
            acc = fmaf(kk[5], vp1, acc);
            acc = fmaf(kk[6], vm2, acc);
            acc = fmaf(kk[7], vc2, acc);
            acc = fmaf(kk[8], vp2, acc);
            const float y = gelu_exact(acc);
            orow[(size_t)w * C] = f2bf(y);
            s += y;
            q = fmaf(y, y, q);
            mx = fmaxf(mx, y);
            mn = fminf(mn, y);
            vm0 = vc0; vc0 = vp0;
            vm1 = vc1; vc1 = vp1;
            vm2 = vc2; vc2 = vp2;
            if (w + 2 < W) {
                vp0 = DWVAL(0, w + 2);
                vp1 = DWVAL(1, w + 2);
                vp2 = DWVAL(2, w + 2);
            } else {
                vp0 = 0.f; vp1 = 0.f; vp2 = 0.f;
            }
        }
#undef DWVAL
        atomicAdd(&chsum2[gc], s);
        atomicAdd(&chsq2[gc], q);
        atomicAdd(&bsum2[b * C + gc], s);
        atomicMax(&umax2[b * C + gc], fkey(mx));
        atomicMax(&umaxn2[b * C + gc], fkey(-mn));
    }
}

// ---------------- Phase 4: channel attention + BN2 finalize (blocks 0..7) ----------------
__device__ void phase_chatt(const KParams& p, int b, u16* smemu) {
    const int t = threadIdx.x, wave = t >> 6, lane = t & 63;
    float* la = (float*)smemu;   // 1024
    float* lx = la + 1024;       // 1024
    float* ha = lx + 1024;       // 64
    float* hm = ha + 64;         // 64
    const float* chsum2 = p.ws + WS_CHSUM2;
    const float* chsq2  = p.ws + WS_CHSQ2;
    const float* bsum2  = p.ws + WS_BSUM2;
    const u32* umax2  = (const u32*)(p.ws + WS_UMAX2);
    const u32* umaxn2 = (const u32*)(p.ws + WS_UMAXN2);
    float* scale2 = p.ws + WS_SCALE2;
    float* shift2 = p.ws + WS_SHIFT2;
    float* s_att  = p.ws + WS_SATT;
#pragma unroll
    for (int j = 0; j < 4; ++j) {
        const int c = t + 256 * j;
        const float m = chsum2[c] * (1.0f / (float)M);
        const float var = chsq2[c] * (1.0f / (float)M) - m * m;
        const float sc = rsqrtf(var + EPS) * p.g2[c];
        const float sh = p.be2[c] - m * sc;
        if (b == 0) { scale2[c] = sc; shift2[c] = sh; }
        la[c] = bsum2[b * C + c] * (1.0f / (float)P) * sc + sh;
        const float mx = fkeyinv(umax2[b * C + c]);
        const float mn = -fkeyinv(umaxn2[b * C + c]);
        lx[c] = (sc >= 0.f ? mx : mn) * sc + sh;
    }
    __syncthreads();
    for (int k = 0; k < 32; ++k) {
        const int u = wave * 32 + k;         // 0..127
        const int row = u & 63;
        const float* src = (u < 64) ? la : lx;
        const float4* wr = (const float4*)(p.caw1 + (size_t)row * C);
        float s = 0.f;
#pragma unroll
        for (int ch = 0; ch < 4; ++ch) {
            const float4 wv = wr[lane + 64 * ch];
            const float4 sv = *(const float4*)(src + 4 * lane + 256 * ch);
            s += wv.x * sv.x + wv.y * sv.y + wv.z * sv.z + wv.w * sv.w;
        }
#pragma unroll
        for (int off = 1; off < 64; off <<= 1) s += __shfl_xor(s, off);
        if (lane == 0) {
            s = fmaxf(s, 0.f);
            if (u < 64) ha[row] = s; else hm[row] = s;
        }
    }
    __syncthreads();
#pragma unroll
    for (int j = 0; j < 4; ++j) {
        const int c = t + 256 * j;
        const float4* w2 = (const float4*)(p.caw2 + (size_t)c * 64);
        float s = 0.f;
#pragma unroll
        for (int q = 0; q < 16; ++q) {
            const float4 wv = w2[q];
            s += wv.x * (ha[q * 4 + 0] + hm[q * 4 + 0]);
            s += wv.y * (ha[q * 4 + 1] + hm[q * 4 + 1]);
            s += wv.z * (ha[q * 4 + 2] + hm[q * 4 + 2]);
            s += wv.w * (ha[q * 4 + 3] + hm[q * 4 + 3]);
        }
        s_att[b * C + c] = 1.0f / (1.0f + expf(-s));
    }
}

// ---------------- Phase 5: y = s_att*bn2(t2) -> bf16 yb + per-row avg/max --------------
__device__ void phase_yq(const KParams& p, int bid, u16* smemu) {
    float* ss = (float*)smemu;
    float* sm = ss + 4;
    const u16* t2b = (const u16*)(p.ws + WS_T2B);
    const float* scale2 = p.ws + WS_SCALE2;
    const float* shift2 = p.ws + WS_SHIFT2;
    const float* s_att  = p.ws + WS_SATT;
    u16* yb = (u16*)(p.ws + WS_YB);
    float* avg_o = p.ws + WS_AVGO;
    float* max_o = p.ws + WS_MAXO;
    const int t = threadIdx.x;
    const int wave = t >> 6, lane = t & 63;
    const int c0 = t * 4;
    for (int row = bid; row < M; row += gridDim.x) {
        const int b = row >> 10;
        const uint2 vv = *(const uint2*)(t2b + (size_t)row * C + c0);
        const float v0 = bf2f((u16)(vv.x & 0xffff));
        const float v1 = bf2f((u16)(vv.x >> 16));
        const float v2 = bf2f((u16)(vv.y & 0xffff));
        const float v3 = bf2f((u16)(vv.y >> 16));
        const float4 sc = *(const float4*)(scale2 + c0);
        const float4 sh = *(const float4*)(shift2 + c0);
        const float4 sa = *(const float4*)(s_att + (size_t)b * C + c0);
        const float y0 = fmaf(v0, sc.x, sh.x) * sa.x;
        const float y1 = fmaf(v1, sc.y, sh.y) * sa.y;
        const float y2 = fmaf(v2, sc.z, sh.z) * sa.z;
        const float y3 = fmaf(v3, sc.w, sh.w) * sa.w;
        uint2 o;
        o.x = ((u32)f2bf(y0)) | ((u32)f2bf(y1) << 16);
        o.y = ((u32)f2bf(y2)) | ((u32)f2bf(y3) << 16);
        *(uint2*)(yb + (size_t)row * C + c0) = o;
        float s = (y0 + y1) + (y2 + y3);
        float mx = fmaxf(fmaxf(y0, y1), fmaxf(y2, y3));
#pragma unroll
        for (int off = 32; off > 0; off >>= 1) {
            s += __shfl_down(s, off);
            mx = fmaxf(mx, __shfl_down(mx, off));
        }
        if (lane == 0) { ss[wave] = s; sm[wave] = mx; }
        __syncthreads();
        if (t == 0) {
            const float S = ss[0] + ss[1] + ss[2] + ss[3];
            const float Mx = fmaxf(fmaxf(sm[0], sm[1]), fmaxf(sm[2], sm[3]));
            avg_o[row] = S * (1.0f / (float)C);
            max_o[row] = Mx;
        }
        __syncthreads();
    }
}

// ---------------- Phase 6: 7x7 spatial conv + sigmoid (blocks 0..7) ----------------
__device__ void phase_spconv(const KParams& p, int b, u16* smemu) {
    float* pa = (float*)smemu;   // 1024
    float* pm = pa + 1024;       // 1024
    float* wsh = pm + 1024;      // 98
    const float* avg_o = p.ws + WS_AVGO;
    const float* max_o = p.ws + WS_MAXO;
    float* sp = p.ws + WS_SP;
    const int t = threadIdx.x;
#pragma unroll
    for (int j = 0; j < 4; ++j) {
        const int pix = t + 256 * j;
        pa[pix] = avg_o[b * P + pix];
        pm[pix] = max_o[b * P + pix];
    }
    if (t < 98) wsh[t] = p.sw[t];
    const float sbv = p.sb[0];
    __syncthreads();
#pragma unroll
    for (int j = 0; j < 4; ++j) {
        const int pix = t + 256 * j;
        const int h = pix >> 5, w = pix & 31;
        float acc = sbv;
#pragma unroll
        for (int i = 0; i < 7; ++i) {
            const int hh = h + i - 3;
            if (hh < 0 || hh >= H) continue;
#pragma unroll
            for (int j7 = 0; j7 < 7; ++j7) {
                const int ww = w + j7 - 3;
                if (ww < 0 || ww >= W) continue;
                const int pidx = hh * W + ww;
                acc = fmaf(wsh[i * 7 + j7], pa[pidx], acc);
                acc = fmaf(wsh[49 + i * 7 + j7], pm[pidx], acc);
            }
        }
        sp[b * P + pix] = 1.0f / (1.0f + expf(-acc));
    }
}

// ---------------- Phase 8: final residual add + BN3 finalize ----------------
__device__ void phase_final(const KParams& p, int bid, u16* smemu) {
    float* lsc = (float*)smemu;   // 256
    float* lsh = lsc + 256;       // 256
    const float* chsum3 = p.ws + WS_CHSUM3;
    const float* chsq3  = p.ws + WS_CHSQ3;
    const float* pre    = p.ws + WS_PRE;
    const int t = threadIdx.x;
    {
        const float m = chsum3[t] * (1.0f / (float)M);
        const float var = chsq3[t] * (1.0f / (float)M) - m * m;
        const float rstd = rsqrtf(var + EPS);
        const float sc = rstd * p.g3[t];
        lsc[t] = sc;
        lsh[t] = p.be3[t] - m * sc;
    }
    __syncthreads();
    const int stride = gridDim.x * 256;
    for (int i = bid * 256 + t; i < 524288; i += stride) {
        const int e = i * 4;
        const int d = e & 255;
        const float4 xv = *(const float4*)(p.x + e);
        const float4 pv = *(const float4*)(pre + e);
        const float4 sc = *(const float4*)(lsc + d);
        const float4 sh = *(const float4*)(lsh + d);
        float4 o;
        o.x = xv.x + fmaf(pv.x, sc.x, sh.x);
        o.y = xv.y + fmaf(pv.y, sc.y, sh.y);
        o.z = xv.z + fmaf(pv.z, sc.z, sh.z);
        o.w = xv.w + fmaf(pv.w, sc.w, sh.w);
        *(float4*)(p.out + e) = o;
    }
}

// ---------------- phase dispatch helpers (shared between mega + fallback) -----------
__device__ __forceinline__ void run_gemm1(const KParams& p, int bid, u16* smem) {
    phase_gemm<256, 0, C, 128, 64>(p, bid, smem,
        (const u16*)(p.ws + WS_XB), (const u16*)(p.ws + WS_W1B), p.b1, nullptr,
        (u16*)(p.ws + WS_T1B), p.ws + WS_CHSUM1, p.ws + WS_CHSQ1, p.ws + WS_GAPSUM);
}
__device__ __forceinline__ void run_gemm2(const KParams& p, int bid, u16* smem) {
    phase_gemm<1024, 1, D, 64, 64>(p, bid, smem,
        (const u16*)(p.ws + WS_YB), (const u16*)(p.ws + WS_PWB), p.pb, p.ws + WS_SP,
        p.ws + WS_PRE, p.ws + WS_CHSUM3, p.ws + WS_CHSQ3, nullptr);
}

// ---------------- Mega kernel: one cooperative launch, 8 grid syncs ----------------
__global__ __launch_bounds__(256, 4) void mega_kernel(KParams p) {
    extern __shared__ u16 smem[];
    cg::grid_group grid = cg::this_grid();
    const int bid = blockIdx.x;

    phase_cvt(p, bid);
    grid.sync();
    run_gemm1(p, bid, smem);
    grid.sync();
    if (bid < 8) phase_dynmlp(p, bid, smem);
    grid.sync();
    phase_dwconv(p, bid, smem);
    grid.sync();
    if (bid < 8) phase_chatt(p, bid, smem);
    grid.sync();
    phase_yq(p, bid, smem);
    grid.sync();
    if (bid < 8) phase_spconv(p, bid, smem);
    grid.sync();
    if (bid < 512) run_gemm2(p, bid, smem);
    grid.sync();
    phase_final(p, bid, smem);
}

// ---------------- Fallback wrappers (9-kernel path, same phase code) ----------------
__global__ __launch_bounds__(256) void k_cvt(KParams p)    { phase_cvt(p, blockIdx.x); }
__global__ __launch_bounds__(256) void k_gemm1(KParams p)  { extern __shared__ u16 s[]; run_gemm1(p, blockIdx.x, s); }
__global__ __launch_bounds__(256) void k_dynmlp(KParams p) { extern __shared__ u16 s[]; phase_dynmlp(p, blockIdx.x, s); }
__global__ __launch_bounds__(256) void k_dwconv(KParams p) { extern __shared__ u16 s[]; phase_dwconv(p, blockIdx.x, s); }
__global__ __launch_bounds__(256) void k_chatt(KParams p)  { extern __shared__ u16 s[]; phase_chatt(p, blockIdx.x, s); }
__global__ __launch_bounds__(256) void k_yq(KParams p)     { extern __shared__ u16 s[]; phase_yq(p, blockIdx.x, s); }
__global__ __launch_bounds__(256) void k_spconv(KParams p) { extern __shared__ u16 s[]; phase_spconv(p, blockIdx.x, s); }
__global__ __launch_bounds__(256) void k_gemm2(KParams p)  { extern __shared__ u16 s[]; run_gemm2(p, blockIdx.x, s); }
__global__ __launch_bounds__(256) void k_final(KParams p)  { extern __shared__ u16 s[]; phase_final(p, blockIdx.x, s); }

extern "C" void kernel_launch(void* const* d_in, const int* in_sizes, int n_in,
                              void* d_out, int out_size, void* d_ws, size_t ws_size,
                              hipStream_t stream) {
    KParams kp;
    kp.x    = (const float*)d_in[0];
    kp.w1   = (const float*)d_in[1];
    kp.b1   = (const float*)d_in[2];
    kp.g1   = (const float*)d_in[3];
    kp.be1  = (const float*)d_in[4];
    kp.aw1  = (const float*)d_in[5];
    kp.ab1  = (const float*)d_in[6];
    kp.aw2  = (const float*)d_in[7];
    kp.ab2  = (const float*)d_in[8];
    kp.g2   = (const float*)d_in[9];
    kp.be2  = (const float*)d_in[10];
    kp.caw1 = (const float*)d_in[11];
    kp.caw2 = (const float*)d_in[12];
    kp.pw   = (const float*)d_in[13];
    kp.pb   = (const float*)d_in[14];
    kp.g3   = (const float*)d_in[15];
    kp.be3  = (const float*)d_in[16];
    kp.sw   = (const float*)d_in[17];
    kp.sb   = (const float*)d_in[18];
    kp.out  = (float*)d_out;
    kp.ws   = (float*)d_ws;

    void* args[] = { &kp };
    hipError_t err = hipLaunchCooperativeKernel((const void*)mega_kernel,
                                                dim3(1024), dim3(256), args, 24576, stream);
    if (err == hipSuccess) return;
    (void)hipGetLastError();   // clear error state, take the 9-kernel fallback

    k_cvt<<<dim3(2560), 256, 0, stream>>>(kp);
    k_gemm1<<<dim3(1024), 256, 24576, stream>>>(kp);
    k_dynmlp<<<dim3(8), 256, 24576, stream>>>(kp);
    k_dwconv<<<dim3(1024), 256, 24576, stream>>>(kp);
    k_chatt<<<dim3(8), 256, 24576, stream>>>(kp);
    k_yq<<<dim3(1024), 256, 24576, stream>>>(kp);
    k_spconv<<<dim3(8), 256, 24576, stream>>>(kp);
    k_gemm2<<<dim3(512), 256, 24576, stream>>>(kp);
    k_final<<<dim3(1024), 256, 24576, stream>>>(kp);
}

// Round 4
// 265.473 us; speedup vs baseline: 4.0382x; 4.0382x over previous
//
#include <hip/hip_runtime.h>
#include <math.h>

// Problem constants
constexpr int B = 8;
constexpr int D = 256;     // model dim
constexpr int C = 1024;    // expanded channels
constexpr int H = 32, W = 32;
constexpr int P = H * W;            // 1024 spatial positions
constexpr int M = B * P;            // 8192 rows
constexpr float EPS = 1e-5f;

typedef unsigned short u16;
typedef unsigned int u32;
typedef __attribute__((ext_vector_type(8))) short short8;
typedef __attribute__((ext_vector_type(4))) float floatx4;

// ---------------- workspace layout (in floats) ----------------
constexpr size_t WS_CHSUM1 = 0;                  // 1024
constexpr size_t WS_CHSQ1  = 1024;               // 1024
constexpr size_t WS_GAPSUM = 2048;               // 8192
constexpr size_t WS_CHSUM3 = 10240;              // 256
constexpr size_t WS_CHSQ3  = 10496;              // 256
constexpr size_t WS_CHSUM2 = 10752;              // 1024
constexpr size_t WS_CHSQ2  = 11776;              // 1024
constexpr size_t WS_BSUM2  = 12800;              // 8192
constexpr size_t WS_UMAX2  = 20992;              // 8192 (u32 keys)
constexpr size_t WS_UMAXN2 = 29184;              // 8192 (u32 keys of -min)
constexpr size_t WS_ACC_COUNT = 37376;
constexpr size_t WS_SCALE1 = 37376;              // 1024
constexpr size_t WS_SHIFT1 = 38400;              // 1024
constexpr size_t WS_KW     = 39424;              // 256 (72 used)
constexpr size_t WS_SCALE2 = 39680;              // 1024
constexpr size_t WS_SHIFT2 = 40704;              // 1024
constexpr size_t WS_SATT   = 41728;              // 8192
constexpr size_t WS_AVGO   = 49920;              // 8192
constexpr size_t WS_MAXO   = 58112;              // 8192
constexpr size_t WS_SP     = 66304;              // 8192
constexpr size_t WS_PRE    = 74496;              // 2097152
constexpr size_t WS_T1B    = 2171648;            // bf16 t1
constexpr size_t WS_T2B    = 6365952;            // bf16 t2
constexpr size_t WS_XB     = 10560256;           // bf16 x
constexpr size_t WS_W1B    = 11608832;
constexpr size_t WS_PWB    = 11739904;           // (unused, kept for layout stability)
constexpr size_t WS_PWBF   = 11870976;           // folded per-batch weights, 8x256x1024 bf16 = 1048576 floats
constexpr size_t WS_BIAS2  = 12919552;           // 2048 floats (8x256)

__device__ __forceinline__ float gelu_exact(float v) {
    return 0.5f * v * (1.0f + erff(v * 0.70710678118654752440f));
}

__device__ __forceinline__ u16 f2bf(float f) {
    u32 u = __float_as_uint(f);
    u += 0x7fff + ((u >> 16) & 1);   // round-to-nearest-even
    return (u16)(u >> 16);
}

__device__ __forceinline__ float bf2f(u16 v) {
    return __uint_as_float(((u32)v) << 16);
}

// order-preserving float->u32 key
__device__ __forceinline__ u32 fkey(float f) {
    u32 u = __float_as_uint(f);
    return (u & 0x80000000u) ? ~u : (u | 0x80000000u);
}
__device__ __forceinline__ float fkeyinv(u32 k) {
    return __uint_as_float((k & 0x80000000u) ? (k ^ 0x80000000u) : ~k);
}

#define GLOAD(SRC, DST) __builtin_amdgcn_global_load_lds( \
    (const __attribute__((address_space(1))) void*)(SRC), \
    (__attribute__((address_space(3))) void*)(DST), 16, 0, 0)

// ---------------- K0: zero accumulators + cast fp32 -> bf16 for x, w1 ----------------
__global__ __launch_bounds__(256) void cvt_all_kernel(const float* __restrict__ x,
                                                      const float* __restrict__ w1,
                                                      u16* __restrict__ xb,
                                                      u16* __restrict__ w1b,
                                                      float* __restrict__ acc_zero) {
    const int i = blockIdx.x * 256 + threadIdx.x;     // grid covers 589824
    if (i < (int)WS_ACC_COUNT) acc_zero[i] = 0.f;     // 0x0 == fkey floor for max-keys too
    const float* src;
    u16* dst;
    int off;
    if (i < 524288) { src = x;  dst = xb;  off = i; }
    else            { src = w1; dst = w1b; off = i - 524288; }
    const float4 v = *(const float4*)(src + (size_t)off * 4);
    uint2 o;
    o.x = ((u32)f2bf(v.x)) | ((u32)f2bf(v.y) << 16);
    o.y = ((u32)f2bf(v.z)) | ((u32)f2bf(v.w) << 16);
    *(uint2*)(dst + (size_t)off * 4) = o;
}

// ---------------- MFMA bf16 GEMM — small-LDS dbuf + counted-vmcnt pipeline ----------------
// EPI 0: t = gelu(acc+bias); bf16 out; col stats + gsum.  Shared B, shared bias.
// EPI 1: t = rowscale*acc + bias; fp32 out; col stats.    PER-BATCH B (folded pwb) + bias2.
template<int KD, int EPI, int NS, int MB, int NB>
__global__ __launch_bounds__(256) void mfma_gemm_kernel(
    const u16* __restrict__ A,
    const u16* __restrict__ Bw,
    const float* __restrict__ bias,
    const float* __restrict__ rowscale,
    void* __restrict__ outv,
    float* __restrict__ csum,
    float* __restrict__ csq,
    float* __restrict__ gsum)
{
    constexpr int MI = MB / 32;
    constexpr int NJ = NB / 32;
    constexpr int ABUF = MB * 32;
    constexpr int BBUF = NB * 32;
    constexpr int BUFSZ = ABUF + BBUF;
    constexpr int GA = MB / 64;
    constexpr int GB = NB / 64;
    constexpr int LD = GA + GB;
    constexpr int NCH = KD / 32;
    constexpr int GX = NS / NB;
    constexpr int NWG = (M / MB) * GX;   // %8 == 0 for both instantiations
    constexpr int CPX = NWG / 8;
    extern __shared__ u16 smem[];
    const int t = threadIdx.x;
    const int lane = t & 63;

    // XCD-chunked bijective block swizzle
    const int lin = blockIdx.y * GX + blockIdx.x;
    const int swz = (lin & 7) * CPX + (lin >> 3);
    const int bx = swz % GX;
    const int by = swz / GX;
    const int row0 = by * MB;
    const int col0 = bx * NB;
    const int bb = row0 >> 10;           // batch index (MB divides 1024)

    const int wv = t >> 6;
    const int wrow = (wv >> 1) * (MB / 2);
    const int wcol = (wv & 1) * (NB / 2);
    const int lm = lane & 15;
    const int lk8 = (lane >> 4) * 8;
    const int srow = t >> 2;
    const int scol = (t & 3) * 8;
    const u16* gA = A + (size_t)(row0 + srow) * KD + scol;
    const u16* gB = Bw + (EPI == 1 ? (size_t)bb * NS * KD : (size_t)0)
                       + (size_t)(col0 + srow) * KD + scol;
    const float* biasp = bias + (EPI == 1 ? bb * NS : 0);

    const floatx4 zero = {0.f, 0.f, 0.f, 0.f};
    floatx4 acc[MI][NJ];
#pragma unroll
    for (int i = 0; i < MI; ++i)
#pragma unroll
        for (int j = 0; j < NJ; ++j) acc[i][j] = zero;

    auto stage = [&](u16* buf, int c) {
        const int kk = c * 32;
        u16* As = buf;
        u16* Bs = buf + ABUF;
#pragma unroll
        for (int g = 0; g < GA; ++g)
            GLOAD(gA + (size_t)g * 64 * KD + kk, As + g * 2048 + t * 8);
#pragma unroll
        for (int g = 0; g < GB; ++g)
            GLOAD(gB + (size_t)g * 64 * KD + kk, Bs + g * 2048 + t * 8);
    };
    auto compute = [&](const u16* buf) {
        const u16* As = buf;
        const u16* Bs = buf + ABUF;
        short8 af[MI], bf[NJ];
#pragma unroll
        for (int i = 0; i < MI; ++i)
            af[i] = *(const short8*)(As + (wrow + i * 16 + lm) * 32 + lk8);
#pragma unroll
        for (int j = 0; j < NJ; ++j)
            bf[j] = *(const short8*)(Bs + (wcol + j * 16 + lm) * 32 + lk8);
#pragma unroll
        for (int i = 0; i < MI; ++i)
#pragma unroll
            for (int j = 0; j < NJ; ++j)
                acc[i][j] = __builtin_amdgcn_mfma_f32_16x16x32_bf16(af[i], bf[j], acc[i][j], 0, 0, 0);
    };

    stage(smem, 0);
    for (int c = 0; c < NCH; ++c) {
        u16* curb = smem + (c & 1) * BUFSZ;
        if (c + 1 < NCH) {
            stage(smem + ((c + 1) & 1) * BUFSZ, c + 1);
            if constexpr (LD == 2) asm volatile("s_waitcnt vmcnt(2)" ::: "memory");
            else                   asm volatile("s_waitcnt vmcnt(3)" ::: "memory");
        } else {
            asm volatile("s_waitcnt vmcnt(0)" ::: "memory");
        }
        __builtin_amdgcn_s_barrier();
        compute(curb);
        asm volatile("s_waitcnt lgkmcnt(0)" ::: "memory");
        __builtin_amdgcn_s_barrier();
    }

    float colsum[NJ], colsq[NJ];
#pragma unroll
    for (int j = 0; j < NJ; ++j) { colsum[j] = 0.f; colsq[j] = 0.f; }

    if (EPI == 0) {
        u16* Cs = smem;
#pragma unroll
        for (int i = 0; i < MI; ++i) {
#pragma unroll
            for (int r = 0; r < 4; ++r) {
                const int lrow = wrow + i * 16 + (lane >> 4) * 4 + r;
#pragma unroll
                for (int j = 0; j < NJ; ++j) {
                    const int lcol = wcol + j * 16 + lm;
                    const float tv = gelu_exact(acc[i][j][r] + biasp[col0 + lcol]);
                    Cs[lrow * NB + lcol] = f2bf(tv);
                    colsum[j] += tv;
                    colsq[j] = fmaf(tv, tv, colsq[j]);
                }
            }
        }
        __syncthreads();
        constexpr int TPR = NB / 8;
        constexpr int RPP = 256 / TPR;
        u16* outp = (u16*)outv;
#pragma unroll
        for (int pp = 0; pp < MB / RPP; ++pp) {
            const int r = pp * RPP + t / TPR;
            const int cc = (t % TPR) * 8;
            *(uint4*)(outp + (size_t)(row0 + r) * NS + col0 + cc) =
                *(const uint4*)(Cs + r * NB + cc);
        }
    } else {
        float* Cs = (float*)smem;
#pragma unroll
        for (int i = 0; i < MI; ++i) {
#pragma unroll
            for (int r = 0; r < 4; ++r) {
                const int lrow = wrow + i * 16 + (lane >> 4) * 4 + r;
                const float rs = rowscale[row0 + lrow];
#pragma unroll
                for (int j = 0; j < NJ; ++j) {
                    const int lcol = wcol + j * 16 + lm;
                    const float tv = rs * (acc[i][j][r] + biasp[col0 + lcol]);
                    Cs[lrow * NB + lcol] = tv;
                    colsum[j] += tv;
                    colsq[j] = fmaf(tv, tv, colsq[j]);
                }
            }
        }
        __syncthreads();
        constexpr int TPR = NB / 4;
        constexpr int RPP = 256 / TPR;
        float* outp = (float*)outv;
#pragma unroll
        for (int pp = 0; pp < MB / RPP; ++pp) {
            const int r = pp * RPP + t / TPR;
            const int cc = (t % TPR) * 4;
            *(float4*)(outp + (size_t)(row0 + r) * NS + col0 + cc) =
                *(const float4*)(Cs + r * NB + cc);
        }
    }

#pragma unroll
    for (int j = 0; j < NJ; ++j) {
        float s = colsum[j];
        float q = colsq[j];
        s += __shfl_xor(s, 16); s += __shfl_xor(s, 32);
        q += __shfl_xor(q, 16); q += __shfl_xor(q, 32);
        if (lane < 16) {
            const int c = col0 + wcol + j * 16 + lm;
            atomicAdd(&csum[c], s);
            atomicAdd(&csq[c], q);
            if (EPI == 0) atomicAdd(&gsum[bb * NS + c], s);
        }
    }
}

// ---------------- K4: dynamic kernel MLP + fused BN1 stats ----------------
__global__ __launch_bounds__(1024) void dynmlp_kernel(const float* __restrict__ chsum1,
                                                      const float* __restrict__ chsq1,
                                                      const float* __restrict__ gapsum,
                                                      const float* __restrict__ g1,
                                                      const float* __restrict__ be1,
                                                      const float* __restrict__ aw1,
                                                      const float* __restrict__ ab1,
                                                      const float* __restrict__ aw2,
                                                      const float* __restrict__ ab2,
                                                      float* __restrict__ scale1,
                                                      float* __restrict__ shift1,
                                                      float* __restrict__ kw) {
    const int b = blockIdx.x;
    const int t = threadIdx.x;
    const int wave = t >> 6, lane = t & 63;
    __shared__ float g[1024];
    __shared__ float h1[128];
    __shared__ float logits[12];
    {
        const float m = chsum1[t] * (1.0f / (float)M);
        const float var = chsq1[t] * (1.0f / (float)M) - m * m;
        const float rstd = rsqrtf(var + EPS);
        const float sc = rstd * g1[t];
        const float sh = be1[t] - m * sc;
        if (b == 0) { scale1[t] = sc; shift1[t] = sh; }
        g[t] = gapsum[b * C + t] * (1.0f / (float)P) * sc + sh;
    }
    __syncthreads();
#pragma unroll
    for (int k = 0; k < 8; ++k) {
        const int u = wave * 8 + k;
        const float4* wr = (const float4*)(aw1 + (size_t)u * C);
        float s = 0.f;
#pragma unroll
        for (int ch = 0; ch < 4; ++ch) {
            const float4 wv = wr[lane + 64 * ch];
            const float4 sv = *(const float4*)(g + 4 * lane + 256 * ch);
            s += wv.x * sv.x + wv.y * sv.y + wv.z * sv.z + wv.w * sv.w;
        }
#pragma unroll
        for (int off = 1; off < 64; off <<= 1) s += __shfl_xor(s, off);
        if (lane == 0) h1[u] = fmaxf(s + ab1[u], 0.f);
    }
    __syncthreads();
    if (wave < 9) {
        float s = aw2[wave * 128 + lane] * h1[lane]
                + aw2[wave * 128 + 64 + lane] * h1[64 + lane];
#pragma unroll
        for (int off = 1; off < 64; off <<= 1) s += __shfl_xor(s, off);
        if (lane == 0) logits[wave] = s + ab2[wave];
    }
    __syncthreads();
    if (t == 0) {
        float mx = logits[0];
        for (int i = 1; i < 9; ++i) mx = fmaxf(mx, logits[i]);
        float e[9], den = 0.f;
        for (int i = 0; i < 9; ++i) { e[i] = expf(logits[i] - mx); den += e[i]; }
        const float inv = 1.0f / den;
        for (int i = 0; i < 9; ++i) kw[b * 9 + i] = e[i] * inv;
    }
}

// ---------------- K5: dyn depthwise conv — sliding-window registers ----------------
__global__ __launch_bounds__(256) void dwconv_kernel(const u16* __restrict__ t1b,
                                                     const float* __restrict__ scale1,
                                                     const float* __restrict__ shift1,
                                                     const float* __restrict__ kw,
                                                     u16* __restrict__ t2b,
                                                     float* __restrict__ chsum2,
                                                     float* __restrict__ chsq2,
                                                     float* __restrict__ bsum2,
                                                     u32* __restrict__ umax2,
                                                     u32* __restrict__ umaxn2) {
    __shared__ u16 rows[3 * 32 * 256];   // 48 KB: [r][w][ch]
    const int lin = blockIdx.y * 4 + blockIdx.x;     // nwg = 1024
    const int swz = (lin & 7) * 128 + (lin >> 3);
    const int cq = swz & 3;
    const int bh = swz >> 2;
    const int b = bh >> 5;
    const int h = bh & 31;
    const int t = threadIdx.x;

    const u16* gbase = t1b + (size_t)b * P * C + cq * 256;
#pragma unroll
    for (int i = 0; i < 12; ++i) {
        const int lin2 = i * 256 + t;
        const int chunk = lin2 >> 5;
        const int r = chunk >> 5;
        const int w = chunk & 31;
        const int off8 = (lin2 & 31) * 8;
        const int hr = h + r - 1;
        uint4 v = {0u, 0u, 0u, 0u};
        if (hr >= 0 && hr < H)
            v = *(const uint4*)(gbase + (size_t)(hr * W + w) * C + off8);
        *(uint4*)(&rows[chunk * 256 + off8]) = v;
    }
    __syncthreads();

    const int c = t;
    const int gc = cq * 256 + c;
    float kk[9];
#pragma unroll
    for (int i = 0; i < 9; ++i) kk[i] = kw[b * 9 + i];
    const float sc = scale1[gc];
    const float sh = shift1[gc];
    float scm[3], shm[3];
    scm[0] = (h > 0)     ? sc : 0.f;  shm[0] = (h > 0)     ? sh : 0.f;
    scm[1] = sc;                      shm[1] = sh;
    scm[2] = (h < H - 1) ? sc : 0.f;  shm[2] = (h < H - 1) ? sh : 0.f;

    const u16* rp0 = rows + c;
#define DWVAL(ri, w) fmaf(bf2f(rp0[((ri) * 32 + (w)) * 256]), scm[ri], shm[ri])

    float vm0 = 0.f, vm1 = 0.f, vm2 = 0.f;
    float vc0 = DWVAL(0, 0), vc1 = DWVAL(1, 0), vc2 = DWVAL(2, 0);
    float vp0 = DWVAL(0, 1), vp1 = DWVAL(1, 1), vp2 = DWVAL(2, 1);

    float s = 0.f, q = 0.f, mx = -INFINITY, mn = INFINITY;
    u16* orow = t2b + ((size_t)b * P + h * W) * C + gc;
    for (int w = 0; w < W; ++w) {
        float acc;
        acc = kk[0] * vm0;
        acc = fmaf(kk[1], vc0, acc);
        acc = fmaf(kk[2], vp0, acc);
        acc = fmaf(kk[3], vm1, acc);
        acc = fmaf(kk[4], vc1, acc);
        acc = fmaf(kk[5], vp1, acc);
        acc = fmaf(kk[6], vm2, acc);
        acc = fmaf(kk[7], vc2, acc);
        acc = fmaf(kk[8], vp2, acc);
        const float y = gelu_exact(acc);
        orow[(size_t)w * C] = f2bf(y);
        s += y;
        q = fmaf(y, y, q);
        mx = fmaxf(mx, y);
        mn = fminf(mn, y);
        vm0 = vc0; vc0 = vp0;
        vm1 = vc1; vc1 = vp1;
        vm2 = vc2; vc2 = vp2;
        if (w + 2 < W) {
            vp0 = DWVAL(0, w + 2);
            vp1 = DWVAL(1, w + 2);
            vp2 = DWVAL(2, w + 2);
        } else {
            vp0 = 0.f; vp1 = 0.f; vp2 = 0.f;
        }
    }
#undef DWVAL
    atomicAdd(&chsum2[gc], s);
    atomicAdd(&chsq2[gc], q);
    atomicAdd(&bsum2[b * C + gc], s);
    atomicMax(&umax2[b * C + gc], fkey(mx));
    atomicMax(&umaxn2[b * C + gc], fkey(-mn));
}

// ---------------- K8: channel attention + BN2 finalize + WEIGHT FOLDING ----------------
// After computing s_att for batch b, also emits:
//   pwb[b][d][c] = bf16( pw[d][c] * scale2[c] * s_att[b][c] )
//   bias2[b][d]  = pb[d] + sum_c shift2[c] * s_att[b][c] * pw[d][c]   (fp32 exact)
__global__ __launch_bounds__(1024) void chatt_kernel(const float* __restrict__ chsum2,
                                                     const float* __restrict__ chsq2,
                                                     const float* __restrict__ bsum2,
                                                     const u32* __restrict__ umax2,
                                                     const u32* __restrict__ umaxn2,
                                                     const float* __restrict__ g2,
                                                     const float* __restrict__ be2,
                                                     const float* __restrict__ caw1,
                                                     const float* __restrict__ caw2,
                                                     const float* __restrict__ pw,
                                                     const float* __restrict__ pb,
                                                     float* __restrict__ scale2,
                                                     float* __restrict__ shift2,
                                                     float* __restrict__ s_att,
                                                     u16* __restrict__ pwb,
                                                     float* __restrict__ bias2) {
    const int b = blockIdx.x;
    const int t = threadIdx.x;          // channel
    const int wave = t >> 6, lane = t & 63;
    __shared__ float la[1024], lx[1024], ha[64], hm[64];
    float sc, sh;
    {
        const float m = chsum2[t] * (1.0f / (float)M);
        const float var = chsq2[t] * (1.0f / (float)M) - m * m;
        const float rstd = rsqrtf(var + EPS);
        sc = rstd * g2[t];
        sh = be2[t] - m * sc;
        if (b == 0) { scale2[t] = sc; shift2[t] = sh; }
        la[t] = bsum2[b * C + t] * (1.0f / (float)P) * sc + sh;
        const float mx = fkeyinv(umax2[b * C + t]);
        const float mn = -fkeyinv(umaxn2[b * C + t]);
        lx[t] = (sc >= 0.f ? mx : mn) * sc + sh;
    }
    __syncthreads();
#pragma unroll
    for (int k = 0; k < 8; ++k) {
        const int u = wave * 8 + k;
        const int row = u & 63;
        const float* src = (u < 64) ? la : lx;
        const float4* wr = (const float4*)(caw1 + (size_t)row * C);
        float s = 0.f;
#pragma unroll
        for (int ch = 0; ch < 4; ++ch) {
            const float4 wv = wr[lane + 64 * ch];
            const float4 sv = *(const float4*)(src + 4 * lane + 256 * ch);
            s += wv.x * sv.x + wv.y * sv.y + wv.z * sv.z + wv.w * sv.w;
        }
#pragma unroll
        for (int off = 1; off < 64; off <<= 1) s += __shfl_xor(s, off);
        if (lane == 0) {
            s = fmaxf(s, 0.f);
            if (u < 64) ha[row] = s; else hm[row] = s;
        }
    }
    __syncthreads();
    float sat;
    {
        const float4* w2 = (const float4*)(caw2 + (size_t)t * 64);
        float s = 0.f;
#pragma unroll
        for (int j = 0; j < 16; ++j) {
            const float4 wv = w2[j];
            s += wv.x * (ha[j * 4 + 0] + hm[j * 4 + 0]);
            s += wv.y * (ha[j * 4 + 1] + hm[j * 4 + 1]);
            s += wv.z * (ha[j * 4 + 2] + hm[j * 4 + 2]);
            s += wv.w * (ha[j * 4 + 3] + hm[j * 4 + 3]);
        }
        sat = 1.0f / (1.0f + expf(-s));
        s_att[b * C + t] = sat;
    }
    // reuse la/lx: f1 = sc*sat (scale factor), f2 = sh*sat (shift factor)
    __syncthreads();
    la[t] = sc * sat;
    lx[t] = sh * sat;
    __syncthreads();
    // fold weights: thread t -> d = t>>2, c-range (t&3)*256..+255
    {
        const int d = t >> 2;
        const int cbase = (t & 3) * 256;
        const float* pwr = pw + (size_t)d * C + cbase;
        u16* pwbr = pwb + ((size_t)b * D + d) * C + cbase;
        float bacc = 0.f;
        for (int i = 0; i < 256; i += 4) {
            const float4 wv = *(const float4*)(pwr + i);
            const float4 f1 = *(const float4*)(la + cbase + i);
            const float4 f2 = *(const float4*)(lx + cbase + i);
            uint2 o;
            o.x = ((u32)f2bf(wv.x * f1.x)) | ((u32)f2bf(wv.y * f1.y) << 16);
            o.y = ((u32)f2bf(wv.z * f1.z)) | ((u32)f2bf(wv.w * f1.w) << 16);
            *(uint2*)(pwbr + i) = o;
            bacc += wv.x * f2.x + wv.y * f2.y + wv.z * f2.z + wv.w * f2.w;
        }
        bacc += __shfl_xor(bacc, 1);
        bacc += __shfl_xor(bacc, 2);
        if ((t & 3) == 0) bias2[b * D + d] = pb[d] + bacc;
    }
}

// ---------------- K9: per-row avg/max of y (no store of y) ----------------
__global__ __launch_bounds__(256) void yq_kernel(const u16* __restrict__ t2b,
                                                 const float* __restrict__ scale2,
                                                 const float* __restrict__ shift2,
                                                 const float* __restrict__ s_att,
                                                 float* __restrict__ avg_o,
                                                 float* __restrict__ max_o) {
    const int row = blockIdx.x;       // b*P + p
    const int b = row >> 10;
    const int t = threadIdx.x;
    const int c0 = t * 4;
    const uint2 vv = *(const uint2*)(t2b + (size_t)row * C + c0);
    const float v0 = bf2f((u16)(vv.x & 0xffff));
    const float v1 = bf2f((u16)(vv.x >> 16));
    const float v2 = bf2f((u16)(vv.y & 0xffff));
    const float v3 = bf2f((u16)(vv.y >> 16));
    const float4 sc = *(const float4*)(scale2 + c0);
    const float4 sh = *(const float4*)(shift2 + c0);
    const float4 sa = *(const float4*)(s_att + (size_t)b * C + c0);
    const float y0 = fmaf(v0, sc.x, sh.x) * sa.x;
    const float y1 = fmaf(v1, sc.y, sh.y) * sa.y;
    const float y2 = fmaf(v2, sc.z, sh.z) * sa.z;
    const float y3 = fmaf(v3, sc.w, sh.w) * sa.w;
    float s = (y0 + y1) + (y2 + y3);
    float mx = fmaxf(fmaxf(y0, y1), fmaxf(y2, y3));
#pragma unroll
    for (int off = 32; off > 0; off >>= 1) {
        s += __shfl_down(s, off);
        mx = fmaxf(mx, __shfl_down(mx, off));
    }
    __shared__ float ss[4], sm[4];
    const int wave = t >> 6, lane = t & 63;
    if (lane == 0) { ss[wave] = s; sm[wave] = mx; }
    __syncthreads();
    if (t == 0) {
        const float S = ss[0] + ss[1] + ss[2] + ss[3];
        const float Mx = fmaxf(fmaxf(sm[0], sm[1]), fmaxf(sm[2], sm[3]));
        avg_o[row] = S * (1.0f / (float)C);
        max_o[row] = Mx;
    }
}

// ---------------- K10: 7x7 spatial conv + sigmoid (1 pixel/thread) ----------------
__global__ __launch_bounds__(1024) void spconv_kernel(const float* __restrict__ avg_o,
                                                      const float* __restrict__ max_o,
                                                      const float* __restrict__ sw,
                                                      const float* __restrict__ sb,
                                                      float* __restrict__ sp) {
    const int b = blockIdx.x;
    const int t = threadIdx.x;
    __shared__ float pa[P], pm[P], wsh[98];
    pa[t] = avg_o[b * P + t];
    pm[t] = max_o[b * P + t];
    if (t < 98) wsh[t] = sw[t];
    const float sbv = sb[0];
    __syncthreads();
    const int h = t >> 5, w = t & 31;
    float acc = sbv;
#pragma unroll
    for (int i = 0; i < 7; ++i) {
        const int hh = h + i - 3;
        if (hh < 0 || hh >= H) continue;
#pragma unroll
        for (int j = 0; j < 7; ++j) {
            const int ww = w + j - 3;
            if (ww < 0 || ww >= W) continue;
            const int pidx = hh * W + ww;
            acc = fmaf(wsh[i * 7 + j], pa[pidx], acc);
            acc = fmaf(wsh[49 + i * 7 + j], pm[pidx], acc);
        }
    }
    sp[b * P + t] = 1.0f / (1.0f + expf(-acc));
}

// ---------------- K15: final residual add + fused BN3 stats ----------------
__global__ __launch_bounds__(256) void final_kernel(const float* __restrict__ x,
                                                    const float* __restrict__ pre,
                                                    const float* __restrict__ chsum3,
                                                    const float* __restrict__ chsq3,
                                                    const float* __restrict__ g3,
                                                    const float* __restrict__ be3,
                                                    float* __restrict__ out) {
    __shared__ float lsc[256], lsh[256];
    const int t = threadIdx.x;
    {
        const float m = chsum3[t] * (1.0f / (float)M);
        const float var = chsq3[t] * (1.0f / (float)M) - m * m;
        const float rstd = rsqrtf(var + EPS);
        const float sc = rstd * g3[t];
        lsc[t] = sc;
        lsh[t] = be3[t] - m * sc;
    }
    __syncthreads();
    const int i = blockIdx.x * 256 + t;   // float4 index
    const int e = i * 4;
    const int d = e & 255;
    const float4 xv = *(const float4*)(x + e);
    const float4 pv = *(const float4*)(pre + e);
    const float4 sc = *(const float4*)(lsc + d);
    const float4 sh = *(const float4*)(lsh + d);
    float4 o;
    o.x = xv.x + fmaf(pv.x, sc.x, sh.x);
    o.y = xv.y + fmaf(pv.y, sc.y, sh.y);
    o.z = xv.z + fmaf(pv.z, sc.z, sh.z);
    o.w = xv.w + fmaf(pv.w, sc.w, sh.w);
    *(float4*)(out + e) = o;
}

extern "C" void kernel_launch(void* const* d_in, const int* in_sizes, int n_in,
                              void* d_out, int out_size, void* d_ws, size_t ws_size,
                              hipStream_t stream) {
    const float* x    = (const float*)d_in[0];
    const float* w1   = (const float*)d_in[1];
    const float* b1   = (const float*)d_in[2];
    const float* g1   = (const float*)d_in[3];
    const float* be1  = (const float*)d_in[4];
    const float* aw1  = (const float*)d_in[5];
    const float* ab1  = (const float*)d_in[6];
    const float* aw2  = (const float*)d_in[7];
    const float* ab2  = (const float*)d_in[8];
    const float* g2   = (const float*)d_in[9];
    const float* be2  = (const float*)d_in[10];
    const float* caw1 = (const float*)d_in[11];
    const float* caw2 = (const float*)d_in[12];
    const float* pw   = (const float*)d_in[13];
    const float* pb   = (const float*)d_in[14];
    const float* g3   = (const float*)d_in[15];
    const float* be3  = (const float*)d_in[16];
    const float* sw   = (const float*)d_in[17];
    const float* sb   = (const float*)d_in[18];
    float* out = (float*)d_out;
    float* ws = (float*)d_ws;

    float* chsum1  = ws + WS_CHSUM1;
    float* chsq1   = ws + WS_CHSQ1;
    float* gapsum  = ws + WS_GAPSUM;
    float* chsum3  = ws + WS_CHSUM3;
    float* chsq3   = ws + WS_CHSQ3;
    float* chsum2  = ws + WS_CHSUM2;
    float* chsq2   = ws + WS_CHSQ2;
    float* bsum2   = ws + WS_BSUM2;
    u32*   umax2   = (u32*)(ws + WS_UMAX2);
    u32*   umaxn2  = (u32*)(ws + WS_UMAXN2);
    float* scale1  = ws + WS_SCALE1;
    float* shift1  = ws + WS_SHIFT1;
    float* kw      = ws + WS_KW;
    float* scale2  = ws + WS_SCALE2;
    float* shift2  = ws + WS_SHIFT2;
    float* s_att   = ws + WS_SATT;
    float* avg_o   = ws + WS_AVGO;
    float* max_o   = ws + WS_MAXO;
    float* sp      = ws + WS_SP;
    float* pre     = ws + WS_PRE;
    float* bias2   = ws + WS_BIAS2;
    u16* t1b  = (u16*)(ws + WS_T1B);
    u16* t2b  = (u16*)(ws + WS_T2B);
    u16* xb   = (u16*)(ws + WS_XB);
    u16* w1b  = (u16*)(ws + WS_W1B);
    u16* pwbf = (u16*)(ws + WS_PWBF);

    // K0: zero accumulators + casts (x, w1)
    cvt_all_kernel<<<dim3(2304), 256, 0, stream>>>(x, w1, xb, w1b, ws);
    // K1: expand GEMM (128x64 tile, BK=32 dbuf, counted vmcnt). 1024 blocks, 24 KB LDS
    mfma_gemm_kernel<256, 0, C, 128, 64><<<dim3(C / 64, M / 128), 256, 24576, stream>>>(
        xb, w1b, b1, nullptr, t1b, chsum1, chsq1, gapsum);
    // K4: BN1 stats + gap + dynamic kernel weights (fused)
    dynmlp_kernel<<<dim3(B), 1024, 0, stream>>>(chsum1, chsq1, gapsum, g1, be1,
                                                aw1, ab1, aw2, ab2, scale1, shift1, kw);
    // K5: depthwise conv (sliding-window regs, XCD swizzle) + GELU -> bf16 t2, BN2 atomics
    dwconv_kernel<<<dim3(4, B * H), 256, 0, stream>>>(t1b, scale1, shift1, kw, t2b,
                                                      chsum2, chsq2, bsum2, umax2, umaxn2);
    // K8: BN2 finalize + channel attention + per-batch weight folding (pwb, bias2)
    chatt_kernel<<<dim3(B), 1024, 0, stream>>>(chsum2, chsq2, bsum2, umax2, umaxn2,
                                               g2, be2, caw1, caw2, pw, pb,
                                               scale2, shift2, s_att, pwbf, bias2);
    // K9: per-row avg/max of y (no y materialization)
    yq_kernel<<<dim3(M), 256, 0, stream>>>(t2b, scale2, shift2, s_att, avg_o, max_o);
    // K10: 7x7 conv + sigmoid
    spconv_kernel<<<dim3(B), 1024, 0, stream>>>(avg_o, max_o, sw, sb, sp);
    // K12: project GEMM on folded weights: pre = sp * (t2b . pwb[b]^T + bias2[b]).
    //      128x64 tile, 256 blocks, dyn LDS 32 KB (epilogue fp32 staging needs 128*64*4)
    mfma_gemm_kernel<1024, 1, D, 128, 64><<<dim3(D / 64, M / 128), 256, 32768, stream>>>(
        t2b, pwbf, bias2, sp, pre, chsum3, chsq3, nullptr);
    // K15: BN3 stats + final residual add (fused)
    final_kernel<<<dim3((M * D / 4) / 256), 256, 0, stream>>>(x, pre, chsum3, chsq3, g3, be3, out);
}

// Round 5
// 205.255 us; speedup vs baseline: 5.2230x; 1.2934x over previous
//
#include <hip/hip_runtime.h>
#include <math.h>

// Problem constants
constexpr int B = 8;
constexpr int D = 256;     // model dim
constexpr int C = 1024;    // expanded channels
constexpr int H = 32, W = 32;
constexpr int P = H * W;            // 1024 spatial positions
constexpr int M = B * P;            // 8192 rows
constexpr float EPS = 1e-5f;

typedef unsigned short u16;
typedef unsigned int u32;
typedef __attribute__((ext_vector_type(8))) short short8;
typedef __attribute__((ext_vector_type(4))) float floatx4;

// ---------------- workspace layout (in floats) ----------------
constexpr size_t WS_CHSUM1 = 0;                  // 1024
constexpr size_t WS_CHSQ1  = 1024;               // 1024
constexpr size_t WS_GAPSUM = 2048;               // 8192
constexpr size_t WS_CHSUM3 = 10240;              // 256
constexpr size_t WS_CHSQ3  = 10496;              // 256
constexpr size_t WS_CHSUM2 = 10752;              // 1024
constexpr size_t WS_CHSQ2  = 11776;              // 1024
constexpr size_t WS_BSUM2  = 12800;              // 8192
constexpr size_t WS_UMAX2  = 20992;              // 8192 (u32 keys)
constexpr size_t WS_UMAXN2 = 29184;              // 8192 (u32 keys of -min)
constexpr size_t WS_ACC_COUNT = 37376;
constexpr size_t WS_SCALE1 = 37376;              // 1024
constexpr size_t WS_SHIFT1 = 38400;              // 1024
constexpr size_t WS_KW     = 39424;              // 256 (72 used)
constexpr size_t WS_SCALE2 = 39680;              // 1024
constexpr size_t WS_SHIFT2 = 40704;              // 1024
constexpr size_t WS_SATT   = 41728;              // 8192
constexpr size_t WS_AVGO   = 49920;              // 8192
constexpr size_t WS_MAXO   = 58112;              // 8192
constexpr size_t WS_SP     = 66304;              // 8192
constexpr size_t WS_PRE    = 74496;              // 2097152
constexpr size_t WS_T1B    = 2171648;            // bf16 t1
constexpr size_t WS_T2B    = 6365952;            // bf16 t2
constexpr size_t WS_XB     = 10560256;           // bf16 x
constexpr size_t WS_W1B    = 11608832;
constexpr size_t WS_PWB    = 11739904;           // (unused, kept for layout stability)
constexpr size_t WS_PWBF   = 11870976;           // folded per-batch weights, 8x256x1024 bf16
constexpr size_t WS_BIAS2  = 12919552;           // 2048 floats (8x256)

__device__ __forceinline__ float gelu_exact(float v) {
    return 0.5f * v * (1.0f + erff(v * 0.70710678118654752440f));
}

__device__ __forceinline__ u16 f2bf(float f) {
    u32 u = __float_as_uint(f);
    u += 0x7fff + ((u >> 16) & 1);   // round-to-nearest-even
    return (u16)(u >> 16);
}

__device__ __forceinline__ float bf2f(u16 v) {
    return __uint_as_float(((u32)v) << 16);
}

// order-preserving float->u32 key
__device__ __forceinline__ u32 fkey(float f) {
    u32 u = __float_as_uint(f);
    return (u & 0x80000000u) ? ~u : (u | 0x80000000u);
}
__device__ __forceinline__ float fkeyinv(u32 k) {
    return __uint_as_float((k & 0x80000000u) ? (k ^ 0x80000000u) : ~k);
}

#define GLOAD(SRC, DST) __builtin_amdgcn_global_load_lds( \
    (const __attribute__((address_space(1))) void*)(SRC), \
    (__attribute__((address_space(3))) void*)(DST), 16, 0, 0)

// ---------------- K0: zero accumulators + cast fp32 -> bf16 for x, w1 ----------------
__global__ __launch_bounds__(256) void cvt_all_kernel(const float* __restrict__ x,
                                                      const float* __restrict__ w1,
                                                      u16* __restrict__ xb,
                                                      u16* __restrict__ w1b,
                                                      float* __restrict__ acc_zero) {
    const int i = blockIdx.x * 256 + threadIdx.x;     // grid covers 589824
    if (i < (int)WS_ACC_COUNT) acc_zero[i] = 0.f;     // 0x0 == fkey floor for max-keys too
    const float* src;
    u16* dst;
    int off;
    if (i < 524288) { src = x;  dst = xb;  off = i; }
    else            { src = w1; dst = w1b; off = i - 524288; }
    const float4 v = *(const float4*)(src + (size_t)off * 4);
    uint2 o;
    o.x = ((u32)f2bf(v.x)) | ((u32)f2bf(v.y) << 16);
    o.y = ((u32)f2bf(v.z)) | ((u32)f2bf(v.w) << 16);
    *(uint2*)(dst + (size_t)off * 4) = o;
}

// ---------------- MFMA bf16 GEMM — small-LDS dbuf + counted-vmcnt pipeline ----------------
// EPI 0: t = gelu(acc+bias); bf16 out; col stats + gsum.  Shared B, shared bias.
// EPI 1: t = rowscale*(acc+bias); fp32 out; col stats.    PER-BATCH B (folded pwb) + bias2.
template<int KD, int EPI, int NS, int MB, int NB>
__global__ __launch_bounds__(256) void mfma_gemm_kernel(
    const u16* __restrict__ A,
    const u16* __restrict__ Bw,
    const float* __restrict__ bias,
    const float* __restrict__ rowscale,
    void* __restrict__ outv,
    float* __restrict__ csum,
    float* __restrict__ csq,
    float* __restrict__ gsum)
{
    constexpr int MI = MB / 32;
    constexpr int NJ = NB / 32;
    constexpr int ABUF = MB * 32;
    constexpr int BBUF = NB * 32;
    constexpr int BUFSZ = ABUF + BBUF;
    constexpr int GA = MB / 64;
    constexpr int GB = NB / 64;
    constexpr int LD = GA + GB;
    constexpr int NCH = KD / 32;
    constexpr int GX = NS / NB;
    constexpr int NWG = (M / MB) * GX;   // %8 == 0 for both instantiations
    constexpr int CPX = NWG / 8;
    extern __shared__ u16 smem[];
    const int t = threadIdx.x;
    const int lane = t & 63;

    // XCD-chunked bijective block swizzle
    const int lin = blockIdx.y * GX + blockIdx.x;
    const int swz = (lin & 7) * CPX + (lin >> 3);
    const int bx = swz % GX;
    const int by = swz / GX;
    const int row0 = by * MB;
    const int col0 = bx * NB;
    const int bb = row0 >> 10;           // batch index (MB divides 1024)

    const int wv = t >> 6;
    const int wrow = (wv >> 1) * (MB / 2);
    const int wcol = (wv & 1) * (NB / 2);
    const int lm = lane & 15;
    const int lk8 = (lane >> 4) * 8;
    const int srow = t >> 2;
    const int scol = (t & 3) * 8;
    const u16* gA = A + (size_t)(row0 + srow) * KD + scol;
    const u16* gB = Bw + (EPI == 1 ? (size_t)bb * NS * KD : (size_t)0)
                       + (size_t)(col0 + srow) * KD + scol;
    const float* biasp = bias + (EPI == 1 ? bb * NS : 0);

    const floatx4 zero = {0.f, 0.f, 0.f, 0.f};
    floatx4 acc[MI][NJ];
#pragma unroll
    for (int i = 0; i < MI; ++i)
#pragma unroll
        for (int j = 0; j < NJ; ++j) acc[i][j] = zero;

    auto stage = [&](u16* buf, int c) {
        const int kk = c * 32;
        u16* As = buf;
        u16* Bs = buf + ABUF;
#pragma unroll
        for (int g = 0; g < GA; ++g)
            GLOAD(gA + (size_t)g * 64 * KD + kk, As + g * 2048 + t * 8);
#pragma unroll
        for (int g = 0; g < GB; ++g)
            GLOAD(gB + (size_t)g * 64 * KD + kk, Bs + g * 2048 + t * 8);
    };
    auto compute = [&](const u16* buf) {
        const u16* As = buf;
        const u16* Bs = buf + ABUF;
        short8 af[MI], bf[NJ];
#pragma unroll
        for (int i = 0; i < MI; ++i)
            af[i] = *(const short8*)(As + (wrow + i * 16 + lm) * 32 + lk8);
#pragma unroll
        for (int j = 0; j < NJ; ++j)
            bf[j] = *(const short8*)(Bs + (wcol + j * 16 + lm) * 32 + lk8);
#pragma unroll
        for (int i = 0; i < MI; ++i)
#pragma unroll
            for (int j = 0; j < NJ; ++j)
                acc[i][j] = __builtin_amdgcn_mfma_f32_16x16x32_bf16(af[i], bf[j], acc[i][j], 0, 0, 0);
    };

    stage(smem, 0);
    for (int c = 0; c < NCH; ++c) {
        u16* curb = smem + (c & 1) * BUFSZ;
        if (c + 1 < NCH) {
            stage(smem + ((c + 1) & 1) * BUFSZ, c + 1);
            if constexpr (LD == 2) asm volatile("s_waitcnt vmcnt(2)" ::: "memory");
            else                   asm volatile("s_waitcnt vmcnt(3)" ::: "memory");
        } else {
            asm volatile("s_waitcnt vmcnt(0)" ::: "memory");
        }
        __builtin_amdgcn_s_barrier();
        compute(curb);
        asm volatile("s_waitcnt lgkmcnt(0)" ::: "memory");
        __builtin_amdgcn_s_barrier();
    }

    float colsum[NJ], colsq[NJ];
#pragma unroll
    for (int j = 0; j < NJ; ++j) { colsum[j] = 0.f; colsq[j] = 0.f; }

    if (EPI == 0) {
        u16* Cs = smem;
#pragma unroll
        for (int i = 0; i < MI; ++i) {
#pragma unroll
            for (int r = 0; r < 4; ++r) {
                const int lrow = wrow + i * 16 + (lane >> 4) * 4 + r;
#pragma unroll
                for (int j = 0; j < NJ; ++j) {
                    const int lcol = wcol + j * 16 + lm;
                    const float tv = gelu_exact(acc[i][j][r] + biasp[col0 + lcol]);
                    Cs[lrow * NB + lcol] = f2bf(tv);
                    colsum[j] += tv;
                    colsq[j] = fmaf(tv, tv, colsq[j]);
                }
            }
        }
        __syncthreads();
        constexpr int TPR = NB / 8;
        constexpr int RPP = 256 / TPR;
        u16* outp = (u16*)outv;
#pragma unroll
        for (int pp = 0; pp < MB / RPP; ++pp) {
            const int r = pp * RPP + t / TPR;
            const int cc = (t % TPR) * 8;
            *(uint4*)(outp + (size_t)(row0 + r) * NS + col0 + cc) =
                *(const uint4*)(Cs + r * NB + cc);
        }
    } else {
        float* Cs = (float*)smem;
#pragma unroll
        for (int i = 0; i < MI; ++i) {
#pragma unroll
            for (int r = 0; r < 4; ++r) {
                const int lrow = wrow + i * 16 + (lane >> 4) * 4 + r;
                const float rs = rowscale[row0 + lrow];
#pragma unroll
                for (int j = 0; j < NJ; ++j) {
                    const int lcol = wcol + j * 16 + lm;
                    const float tv = rs * (acc[i][j][r] + biasp[col0 + lcol]);
                    Cs[lrow * NB + lcol] = tv;
                    colsum[j] += tv;
                    colsq[j] = fmaf(tv, tv, colsq[j]);
                }
            }
        }
        __syncthreads();
        constexpr int TPR = NB / 4;
        constexpr int RPP = 256 / TPR;
        float* outp = (float*)outv;
#pragma unroll
        for (int pp = 0; pp < MB / RPP; ++pp) {
            const int r = pp * RPP + t / TPR;
            const int cc = (t % TPR) * 4;
            *(float4*)(outp + (size_t)(row0 + r) * NS + col0 + cc) =
                *(const float4*)(Cs + r * NB + cc);
        }
    }

#pragma unroll
    for (int j = 0; j < NJ; ++j) {
        float s = colsum[j];
        float q = colsq[j];
        s += __shfl_xor(s, 16); s += __shfl_xor(s, 32);
        q += __shfl_xor(q, 16); q += __shfl_xor(q, 32);
        if (lane < 16) {
            const int c = col0 + wcol + j * 16 + lm;
            atomicAdd(&csum[c], s);
            atomicAdd(&csq[c], q);
            if (EPI == 0) atomicAdd(&gsum[bb * NS + c], s);
        }
    }
}

// ---------------- K4: dynamic kernel MLP + fused BN1 stats ----------------
__global__ __launch_bounds__(1024) void dynmlp_kernel(const float* __restrict__ chsum1,
                                                      const float* __restrict__ chsq1,
                                                      const float* __restrict__ gapsum,
                                                      const float* __restrict__ g1,
                                                      const float* __restrict__ be1,
                                                      const float* __restrict__ aw1,
                                                      const float* __restrict__ ab1,
                                                      const float* __restrict__ aw2,
                                                      const float* __restrict__ ab2,
                                                      float* __restrict__ scale1,
                                                      float* __restrict__ shift1,
                                                      float* __restrict__ kw) {
    const int b = blockIdx.x;
    const int t = threadIdx.x;
    const int wave = t >> 6, lane = t & 63;
    __shared__ float g[1024];
    __shared__ float h1[128];
    __shared__ float logits[12];
    {
        const float m = chsum1[t] * (1.0f / (float)M);
        const float var = chsq1[t] * (1.0f / (float)M) - m * m;
        const float rstd = rsqrtf(var + EPS);
        const float sc = rstd * g1[t];
        const float sh = be1[t] - m * sc;
        if (b == 0) { scale1[t] = sc; shift1[t] = sh; }
        g[t] = gapsum[b * C + t] * (1.0f / (float)P) * sc + sh;
    }
    __syncthreads();
#pragma unroll
    for (int k = 0; k < 8; ++k) {
        const int u = wave * 8 + k;
        const float4* wr = (const float4*)(aw1 + (size_t)u * C);
        float s = 0.f;
#pragma unroll
        for (int ch = 0; ch < 4; ++ch) {
            const float4 wv = wr[lane + 64 * ch];
            const float4 sv = *(const float4*)(g + 4 * lane + 256 * ch);
            s += wv.x * sv.x + wv.y * sv.y + wv.z * sv.z + wv.w * sv.w;
        }
#pragma unroll
        for (int off = 1; off < 64; off <<= 1) s += __shfl_xor(s, off);
        if (lane == 0) h1[u] = fmaxf(s + ab1[u], 0.f);
    }
    __syncthreads();
    if (wave < 9) {
        float s = aw2[wave * 128 + lane] * h1[lane]
                + aw2[wave * 128 + 64 + lane] * h1[64 + lane];
#pragma unroll
        for (int off = 1; off < 64; off <<= 1) s += __shfl_xor(s, off);
        if (lane == 0) logits[wave] = s + ab2[wave];
    }
    __syncthreads();
    if (t == 0) {
        float mx = logits[0];
        for (int i = 1; i < 9; ++i) mx = fmaxf(mx, logits[i]);
        float e[9], den = 0.f;
        for (int i = 0; i < 9; ++i) { e[i] = expf(logits[i] - mx); den += e[i]; }
        const float inv = 1.0f / den;
        for (int i = 0; i < 9; ++i) kw[b * 9 + i] = e[i] * inv;
    }
}

// ---------------- K5: dyn depthwise conv — sliding-window registers ----------------
__global__ __launch_bounds__(256) void dwconv_kernel(const u16* __restrict__ t1b,
                                                     const float* __restrict__ scale1,
                                                     const float* __restrict__ shift1,
                                                     const float* __restrict__ kw,
                                                     u16* __restrict__ t2b,
                                                     float* __restrict__ chsum2,
                                                     float* __restrict__ chsq2,
                                                     float* __restrict__ bsum2,
                                                     u32* __restrict__ umax2,
                                                     u32* __restrict__ umaxn2) {
    __shared__ u16 rows[3 * 32 * 256];   // 48 KB: [r][w][ch]
    const int lin = blockIdx.y * 4 + blockIdx.x;     // nwg = 1024
    const int swz = (lin & 7) * 128 + (lin >> 3);
    const int cq = swz & 3;
    const int bh = swz >> 2;
    const int b = bh >> 5;
    const int h = bh & 31;
    const int t = threadIdx.x;

    const u16* gbase = t1b + (size_t)b * P * C + cq * 256;
#pragma unroll
    for (int i = 0; i < 12; ++i) {
        const int lin2 = i * 256 + t;
        const int chunk = lin2 >> 5;
        const int r = chunk >> 5;
        const int w = chunk & 31;
        const int off8 = (lin2 & 31) * 8;
        const int hr = h + r - 1;
        uint4 v = {0u, 0u, 0u, 0u};
        if (hr >= 0 && hr < H)
            v = *(const uint4*)(gbase + (size_t)(hr * W + w) * C + off8);
        *(uint4*)(&rows[chunk * 256 + off8]) = v;
    }
    __syncthreads();

    const int c = t;
    const int gc = cq * 256 + c;
    float kk[9];
#pragma unroll
    for (int i = 0; i < 9; ++i) kk[i] = kw[b * 9 + i];
    const float sc = scale1[gc];
    const float sh = shift1[gc];
    float scm[3], shm[3];
    scm[0] = (h > 0)     ? sc : 0.f;  shm[0] = (h > 0)     ? sh : 0.f;
    scm[1] = sc;                      shm[1] = sh;
    scm[2] = (h < H - 1) ? sc : 0.f;  shm[2] = (h < H - 1) ? sh : 0.f;

    const u16* rp0 = rows + c;
#define DWVAL(ri, w) fmaf(bf2f(rp0[((ri) * 32 + (w)) * 256]), scm[ri], shm[ri])

    float vm0 = 0.f, vm1 = 0.f, vm2 = 0.f;
    float vc0 = DWVAL(0, 0), vc1 = DWVAL(1, 0), vc2 = DWVAL(2, 0);
    float vp0 = DWVAL(0, 1), vp1 = DWVAL(1, 1), vp2 = DWVAL(2, 1);

    float s = 0.f, q = 0.f, mx = -INFINITY, mn = INFINITY;
    u16* orow = t2b + ((size_t)b * P + h * W) * C + gc;
    for (int w = 0; w < W; ++w) {
        float acc;
        acc = kk[0] * vm0;
        acc = fmaf(kk[1], vc0, acc);
        acc = fmaf(kk[2], vp0, acc);
        acc = fmaf(kk[3], vm1, acc);
        acc = fmaf(kk[4], vc1, acc);
        acc = fmaf(kk[5], vp1, acc);
        acc = fmaf(kk[6], vm2, acc);
        acc = fmaf(kk[7], vc2, acc);
        acc = fmaf(kk[8], vp2, acc);
        const float y = gelu_exact(acc);
        orow[(size_t)w * C] = f2bf(y);
        s += y;
        q = fmaf(y, y, q);
        mx = fmaxf(mx, y);
        mn = fminf(mn, y);
        vm0 = vc0; vc0 = vp0;
        vm1 = vc1; vc1 = vp1;
        vm2 = vc2; vc2 = vp2;
        if (w + 2 < W) {
            vp0 = DWVAL(0, w + 2);
            vp1 = DWVAL(1, w + 2);
            vp2 = DWVAL(2, w + 2);
        } else {
            vp0 = 0.f; vp1 = 0.f; vp2 = 0.f;
        }
    }
#undef DWVAL
    atomicAdd(&chsum2[gc], s);
    atomicAdd(&chsq2[gc], q);
    atomicAdd(&bsum2[b * C + gc], s);
    atomicMax(&umax2[b * C + gc], fkey(mx));
    atomicMax(&umaxn2[b * C + gc], fkey(-mn));
}

// ---------------- K8: channel attention + O(1) BN2 finalize (s_att only) ----------------
__global__ __launch_bounds__(1024) void chatt_kernel(const float* __restrict__ chsum2,
                                                     const float* __restrict__ chsq2,
                                                     const float* __restrict__ bsum2,
                                                     const u32* __restrict__ umax2,
                                                     const u32* __restrict__ umaxn2,
                                                     const float* __restrict__ g2,
                                                     const float* __restrict__ be2,
                                                     const float* __restrict__ caw1,
                                                     const float* __restrict__ caw2,
                                                     float* __restrict__ scale2,
                                                     float* __restrict__ shift2,
                                                     float* __restrict__ s_att) {
    const int b = blockIdx.x;
    const int t = threadIdx.x;          // channel
    const int wave = t >> 6, lane = t & 63;
    __shared__ float la[1024], lx[1024], ha[64], hm[64];
    {
        const float m = chsum2[t] * (1.0f / (float)M);
        const float var = chsq2[t] * (1.0f / (float)M) - m * m;
        const float rstd = rsqrtf(var + EPS);
        const float sc = rstd * g2[t];
        const float sh = be2[t] - m * sc;
        if (b == 0) { scale2[t] = sc; shift2[t] = sh; }
        la[t] = bsum2[b * C + t] * (1.0f / (float)P) * sc + sh;
        const float mx = fkeyinv(umax2[b * C + t]);
        const float mn = -fkeyinv(umaxn2[b * C + t]);
        lx[t] = (sc >= 0.f ? mx : mn) * sc + sh;
    }
    __syncthreads();
#pragma unroll
    for (int k = 0; k < 8; ++k) {
        const int u = wave * 8 + k;
        const int row = u & 63;
        const float* src = (u < 64) ? la : lx;
        const float4* wr = (const float4*)(caw1 + (size_t)row * C);
        float s = 0.f;
#pragma unroll
        for (int ch = 0; ch < 4; ++ch) {
            const float4 wv = wr[lane + 64 * ch];
            const float4 sv = *(const float4*)(src + 4 * lane + 256 * ch);
            s += wv.x * sv.x + wv.y * sv.y + wv.z * sv.z + wv.w * sv.w;
        }
#pragma unroll
        for (int off = 1; off < 64; off <<= 1) s += __shfl_xor(s, off);
        if (lane == 0) {
            s = fmaxf(s, 0.f);
            if (u < 64) ha[row] = s; else hm[row] = s;
        }
    }
    __syncthreads();
    {
        const float4* w2 = (const float4*)(caw2 + (size_t)t * 64);
        float s = 0.f;
#pragma unroll
        for (int j = 0; j < 16; ++j) {
            const float4 wv = w2[j];
            s += wv.x * (ha[j * 4 + 0] + hm[j * 4 + 0]);
            s += wv.y * (ha[j * 4 + 1] + hm[j * 4 + 1]);
            s += wv.z * (ha[j * 4 + 2] + hm[j * 4 + 2]);
            s += wv.w * (ha[j * 4 + 3] + hm[j * 4 + 3]);
        }
        s_att[b * C + t] = 1.0f / (1.0f + expf(-s));
    }
}

// ---------------- K8b: weight folding, fully parallel (2048 blocks) ----------------
// pwb[b][d][c] = bf16(pw[d][c] * scale2[c] * s_att[b][c])
// bias2[b][d]  = pb[d] + sum_c pw[d][c] * shift2[c] * s_att[b][c]
__global__ __launch_bounds__(256) void fold_kernel(const float* __restrict__ pw,
                                                   const float* __restrict__ pb,
                                                   const float* __restrict__ scale2,
                                                   const float* __restrict__ shift2,
                                                   const float* __restrict__ s_att,
                                                   u16* __restrict__ pwb,
                                                   float* __restrict__ bias2) {
    const int bd = blockIdx.x;          // 0..2047
    const int b = bd >> 8;
    const int d = bd & 255;
    const int t = threadIdx.x;
    const int c0 = t * 4;
    const float4 wv = *(const float4*)(pw + (size_t)d * C + c0);
    const float4 sc = *(const float4*)(scale2 + c0);
    const float4 sh = *(const float4*)(shift2 + c0);
    const float4 sa = *(const float4*)(s_att + (size_t)b * C + c0);
    uint2 o;
    o.x = ((u32)f2bf(wv.x * sc.x * sa.x)) | ((u32)f2bf(wv.y * sc.y * sa.y) << 16);
    o.y = ((u32)f2bf(wv.z * sc.z * sa.z)) | ((u32)f2bf(wv.w * sc.w * sa.w) << 16);
    *(uint2*)(pwb + ((size_t)b * D + d) * C + c0) = o;
    float s = wv.x * sh.x * sa.x + wv.y * sh.y * sa.y
            + wv.z * sh.z * sa.z + wv.w * sh.w * sa.w;
#pragma unroll
    for (int off = 1; off < 64; off <<= 1) s += __shfl_xor(s, off);
    __shared__ float ps[4];
    const int wave = t >> 6, lane = t & 63;
    if (lane == 0) ps[wave] = s;
    __syncthreads();
    if (t == 0) bias2[bd] = pb[d] + ps[0] + ps[1] + ps[2] + ps[3];
}

// ---------------- K9: per-row avg/max of y (no store of y) ----------------
__global__ __launch_bounds__(256) void yq_kernel(const u16* __restrict__ t2b,
                                                 const float* __restrict__ scale2,
                                                 const float* __restrict__ shift2,
                                                 const float* __restrict__ s_att,
                                                 float* __restrict__ avg_o,
                                                 float* __restrict__ max_o) {
    const int row = blockIdx.x;       // b*P + p
    const int b = row >> 10;
    const int t = threadIdx.x;
    const int c0 = t * 4;
    const uint2 vv = *(const uint2*)(t2b + (size_t)row * C + c0);
    const float v0 = bf2f((u16)(vv.x & 0xffff));
    const float v1 = bf2f((u16)(vv.x >> 16));
    const float v2 = bf2f((u16)(vv.y & 0xffff));
    const float v3 = bf2f((u16)(vv.y >> 16));
    const float4 sc = *(const float4*)(scale2 + c0);
    const float4 sh = *(const float4*)(shift2 + c0);
    const float4 sa = *(const float4*)(s_att + (size_t)b * C + c0);
    const float y0 = fmaf(v0, sc.x, sh.x) * sa.x;
    const float y1 = fmaf(v1, sc.y, sh.y) * sa.y;
    const float y2 = fmaf(v2, sc.z, sh.z) * sa.z;
    const float y3 = fmaf(v3, sc.w, sh.w) * sa.w;
    float s = (y0 + y1) + (y2 + y3);
    float mx = fmaxf(fmaxf(y0, y1), fmaxf(y2, y3));
#pragma unroll
    for (int off = 32; off > 0; off >>= 1) {
        s += __shfl_down(s, off);
        mx = fmaxf(mx, __shfl_down(mx, off));
    }
    __shared__ float ss[4], sm[4];
    const int wave = t >> 6, lane = t & 63;
    if (lane == 0) { ss[wave] = s; sm[wave] = mx; }
    __syncthreads();
    if (t == 0) {
        const float S = ss[0] + ss[1] + ss[2] + ss[3];
        const float Mx = fmaxf(fmaxf(sm[0], sm[1]), fmaxf(sm[2], sm[3]));
        avg_o[row] = S * (1.0f / (float)C);
        max_o[row] = Mx;
    }
}

// ---------------- K10: 7x7 spatial conv + sigmoid (1 pixel/thread) ----------------
__global__ __launch_bounds__(1024) void spconv_kernel(const float* __restrict__ avg_o,
                                                      const float* __restrict__ max_o,
                                                      const float* __restrict__ sw,
                                                      const float* __restrict__ sb,
                                                      float* __restrict__ sp) {
    const int b = blockIdx.x;
    const int t = threadIdx.x;
    __shared__ float pa[P], pm[P], wsh[98];
    pa[t] = avg_o[b * P + t];
    pm[t] = max_o[b * P + t];
    if (t < 98) wsh[t] = sw[t];
    const float sbv = sb[0];
    __syncthreads();
    const int h = t >> 5, w = t & 31;
    float acc = sbv;
#pragma unroll
    for (int i = 0; i < 7; ++i) {
        const int hh = h + i - 3;
        if (hh < 0 || hh >= H) continue;
#pragma unroll
        for (int j = 0; j < 7; ++j) {
            const int ww = w + j - 3;
            if (ww < 0 || ww >= W) continue;
            const int pidx = hh * W + ww;
            acc = fmaf(wsh[i * 7 + j], pa[pidx], acc);
            acc = fmaf(wsh[49 + i * 7 + j], pm[pidx], acc);
        }
    }
    sp[b * P + t] = 1.0f / (1.0f + expf(-acc));
}

// ---------------- K15: final residual add + fused BN3 stats ----------------
__global__ __launch_bounds__(256) void final_kernel(const float* __restrict__ x,
                                                    const float* __restrict__ pre,
                                                    const float* __restrict__ chsum3,
                                                    const float* __restrict__ chsq3,
                                                    const float* __restrict__ g3,
                                                    const float* __restrict__ be3,
                                                    float* __restrict__ out) {
    __shared__ float lsc[256], lsh[256];
    const int t = threadIdx.x;
    {
        const float m = chsum3[t] * (1.0f / (float)M);
        const float var = chsq3[t] * (1.0f / (float)M) - m * m;
        const float rstd = rsqrtf(var + EPS);
        const float sc = rstd * g3[t];
        lsc[t] = sc;
        lsh[t] = be3[t] - m * sc;
    }
    __syncthreads();
    const int i = blockIdx.x * 256 + t;   // float4 index
    const int e = i * 4;
    const int d = e & 255;
    const float4 xv = *(const float4*)(x + e);
    const float4 pv = *(const float4*)(pre + e);
    const float4 sc = *(const float4*)(lsc + d);
    const float4 sh = *(const float4*)(lsh + d);
    float4 o;
    o.x = xv.x + fmaf(pv.x, sc.x, sh.x);
    o.y = xv.y + fmaf(pv.y, sc.y, sh.y);
    o.z = xv.z + fmaf(pv.z, sc.z, sh.z);
    o.w = xv.w + fmaf(pv.w, sc.w, sh.w);
    *(float4*)(out + e) = o;
}

extern "C" void kernel_launch(void* const* d_in, const int* in_sizes, int n_in,
                              void* d_out, int out_size, void* d_ws, size_t ws_size,
                              hipStream_t stream) {
    const float* x    = (const float*)d_in[0];
    const float* w1   = (const float*)d_in[1];
    const float* b1   = (const float*)d_in[2];
    const float* g1   = (const float*)d_in[3];
    const float* be1  = (const float*)d_in[4];
    const float* aw1  = (const float*)d_in[5];
    const float* ab1  = (const float*)d_in[6];
    const float* aw2  = (const float*)d_in[7];
    const float* ab2  = (const float*)d_in[8];
    const float* g2   = (const float*)d_in[9];
    const float* be2  = (const float*)d_in[10];
    const float* caw1 = (const float*)d_in[11];
    const float* caw2 = (const float*)d_in[12];
    const float* pw   = (const float*)d_in[13];
    const float* pb   = (const float*)d_in[14];
    const float* g3   = (const float*)d_in[15];
    const float* be3  = (const float*)d_in[16];
    const float* sw   = (const float*)d_in[17];
    const float* sb   = (const float*)d_in[18];
    float* out = (float*)d_out;
    float* ws = (float*)d_ws;

    float* chsum1  = ws + WS_CHSUM1;
    float* chsq1   = ws + WS_CHSQ1;
    float* gapsum  = ws + WS_GAPSUM;
    float* chsum3  = ws + WS_CHSUM3;
    float* chsq3   = ws + WS_CHSQ3;
    float* chsum2  = ws + WS_CHSUM2;
    float* chsq2   = ws + WS_CHSQ2;
    float* bsum2   = ws + WS_BSUM2;
    u32*   umax2   = (u32*)(ws + WS_UMAX2);
    u32*   umaxn2  = (u32*)(ws + WS_UMAXN2);
    float* scale1  = ws + WS_SCALE1;
    float* shift1  = ws + WS_SHIFT1;
    float* kw      = ws + WS_KW;
    float* scale2  = ws + WS_SCALE2;
    float* shift2  = ws + WS_SHIFT2;
    float* s_att   = ws + WS_SATT;
    float* avg_o   = ws + WS_AVGO;
    float* max_o   = ws + WS_MAXO;
    float* sp      = ws + WS_SP;
    float* pre     = ws + WS_PRE;
    float* bias2   = ws + WS_BIAS2;
    u16* t1b  = (u16*)(ws + WS_T1B);
    u16* t2b  = (u16*)(ws + WS_T2B);
    u16* xb   = (u16*)(ws + WS_XB);
    u16* w1b  = (u16*)(ws + WS_W1B);
    u16* pwbf = (u16*)(ws + WS_PWBF);

    // K0: zero accumulators + casts (x, w1)
    cvt_all_kernel<<<dim3(2304), 256, 0, stream>>>(x, w1, xb, w1b, ws);
    // K1: expand GEMM (128x64 tile, BK=32 dbuf, counted vmcnt). 1024 blocks, 24 KB LDS
    mfma_gemm_kernel<256, 0, C, 128, 64><<<dim3(C / 64, M / 128), 256, 24576, stream>>>(
        xb, w1b, b1, nullptr, t1b, chsum1, chsq1, gapsum);
    // K4: BN1 stats + gap + dynamic kernel weights (fused)
    dynmlp_kernel<<<dim3(B), 1024, 0, stream>>>(chsum1, chsq1, gapsum, g1, be1,
                                                aw1, ab1, aw2, ab2, scale1, shift1, kw);
    // K5: depthwise conv (sliding-window regs, XCD swizzle) + GELU -> bf16 t2, BN2 atomics
    dwconv_kernel<<<dim3(4, B * H), 256, 0, stream>>>(t1b, scale1, shift1, kw, t2b,
                                                      chsum2, chsq2, bsum2, umax2, umaxn2);
    // K8: BN2 finalize + channel attention (s_att only)
    chatt_kernel<<<dim3(B), 1024, 0, stream>>>(chsum2, chsq2, bsum2, umax2, umaxn2,
                                               g2, be2, caw1, caw2, scale2, shift2, s_att);
    // K8b: weight folding, 2048 blocks (one per (b,d) row)
    fold_kernel<<<dim3(B * D), 256, 0, stream>>>(pw, pb, scale2, shift2, s_att, pwbf, bias2);
    // K9: per-row avg/max of y (no y materialization)
    yq_kernel<<<dim3(M), 256, 0, stream>>>(t2b, scale2, shift2, s_att, avg_o, max_o);
    // K10: 7x7 conv + sigmoid
    spconv_kernel<<<dim3(B), 1024, 0, stream>>>(avg_o, max_o, sw, sb, sp);
    // K12: project GEMM on folded weights: pre = sp * (t2b . pwb[b]^T + bias2[b]).
    //      128x64 tile, 256 blocks, dyn LDS 32 KB (epilogue fp32 staging needs 128*64*4)
    mfma_gemm_kernel<1024, 1, D, 128, 64><<<dim3(D / 64, M / 128), 256, 32768, stream>>>(
        t2b, pwbf, bias2, sp, pre, chsum3, chsq3, nullptr);
    // K15: BN3 stats + final residual add (fused)
    final_kernel<<<dim3((M * D / 4) / 256), 256, 0, stream>>>(x, pre, chsum3, chsq3, g3, be3, out);
}

// Round 6
// 202.151 us; speedup vs baseline: 5.3032x; 1.0154x over previous
//
#include <hip/hip_runtime.h>
#include <math.h>

// Problem constants
constexpr int B = 8;
constexpr int D = 256;     // model dim
constexpr int C = 1024;    // expanded channels
constexpr int H = 32, W = 32;
constexpr int P = H * W;            // 1024 spatial positions
constexpr int M = B * P;            // 8192 rows
constexpr float EPS = 1e-5f;

typedef unsigned short u16;
typedef unsigned int u32;
typedef __attribute__((ext_vector_type(8))) short short8;
typedef __attribute__((ext_vector_type(4))) float floatx4;

// ---------------- workspace layout (in floats) ----------------
constexpr size_t WS_CHSUM1 = 0;                  // 1024
constexpr size_t WS_CHSQ1  = 1024;               // 1024
constexpr size_t WS_GAPSUM = 2048;               // 8192
constexpr size_t WS_CHSUM3 = 10240;              // 256
constexpr size_t WS_CHSQ3  = 10496;              // 256
constexpr size_t WS_CHSUM2 = 10752;              // 1024
constexpr size_t WS_CHSQ2  = 11776;              // 1024
constexpr size_t WS_BSUM2  = 12800;              // 8192
constexpr size_t WS_UMAX2  = 20992;              // 8192 (u32 keys)
constexpr size_t WS_UMAXN2 = 29184;              // 8192 (u32 keys of -min)
constexpr size_t WS_ACC_COUNT = 37376;
constexpr size_t WS_SCALE1 = 37376;              // 1024
constexpr size_t WS_SHIFT1 = 38400;              // 1024
constexpr size_t WS_KW     = 39424;              // 256 (72 used)
constexpr size_t WS_SCALE2 = 39680;              // 1024
constexpr size_t WS_SHIFT2 = 40704;              // 1024
constexpr size_t WS_SATT   = 41728;              // 8192
constexpr size_t WS_AVGO   = 49920;              // 8192
constexpr size_t WS_MAXO   = 58112;              // 8192
constexpr size_t WS_SP     = 66304;              // (unused, kept for layout stability)
constexpr size_t WS_PRE    = 74496;              // 2097152
constexpr size_t WS_T1B    = 2171648;            // bf16 t1
constexpr size_t WS_T2B    = 6365952;            // bf16 t2
constexpr size_t WS_XB     = 10560256;           // bf16 x
constexpr size_t WS_W1B    = 11608832;
constexpr size_t WS_PWB    = 11739904;           // (unused, kept for layout stability)
constexpr size_t WS_PWBF   = 11870976;           // folded per-batch weights, 8x256x1024 bf16
constexpr size_t WS_BIAS2  = 12919552;           // 2048 floats (8x256), pb NOT included

__device__ __forceinline__ float gelu_exact(float v) {
    return 0.5f * v * (1.0f + erff(v * 0.70710678118654752440f));
}

__device__ __forceinline__ u16 f2bf(float f) {
    u32 u = __float_as_uint(f);
    u += 0x7fff + ((u >> 16) & 1);   // round-to-nearest-even
    return (u16)(u >> 16);
}

__device__ __forceinline__ float bf2f(u16 v) {
    return __uint_as_float(((u32)v) << 16);
}

// order-preserving float->u32 key
__device__ __forceinline__ u32 fkey(float f) {
    u32 u = __float_as_uint(f);
    return (u & 0x80000000u) ? ~u : (u | 0x80000000u);
}
__device__ __forceinline__ float fkeyinv(u32 k) {
    return __uint_as_float((k & 0x80000000u) ? (k ^ 0x80000000u) : ~k);
}

#define GLOAD(SRC, DST) __builtin_amdgcn_global_load_lds( \
    (const __attribute__((address_space(1))) void*)(SRC), \
    (__attribute__((address_space(3))) void*)(DST), 16, 0, 0)

// ---------------- K0: zero accumulators + cast fp32 -> bf16 for x, w1 ----------------
__global__ __launch_bounds__(256) void cvt_all_kernel(const float* __restrict__ x,
                                                      const float* __restrict__ w1,
                                                      u16* __restrict__ xb,
                                                      u16* __restrict__ w1b,
                                                      float* __restrict__ acc_zero) {
    const int i = blockIdx.x * 256 + threadIdx.x;     // grid covers 589824
    if (i < (int)WS_ACC_COUNT) acc_zero[i] = 0.f;     // 0x0 == fkey floor for max-keys too
    const float* src;
    u16* dst;
    int off;
    if (i < 524288) { src = x;  dst = xb;  off = i; }
    else            { src = w1; dst = w1b; off = i - 524288; }
    const float4 v = *(const float4*)(src + (size_t)off * 4);
    uint2 o;
    o.x = ((u32)f2bf(v.x)) | ((u32)f2bf(v.y) << 16);
    o.y = ((u32)f2bf(v.z)) | ((u32)f2bf(v.w) << 16);
    *(uint2*)(dst + (size_t)off * 4) = o;
}

// ---------------- MFMA bf16 GEMM — small-LDS dbuf + counted-vmcnt pipeline ----------------
// EPI 0: t = gelu(acc+bias); bf16 out; col stats + gsum.  Shared B, shared bias.
// EPI 1: t = sp*(acc+bias) + bias_post; fp32 out; col stats. PER-BATCH B (folded pwb).
//        sp (7x7 spatial-attention conv + sigmoid) computed IN-KERNEL from avg_o/max_o
//        for this block's 128 rows; lives in LDS above the 32KB Cs region (no aliasing).
template<int KD, int EPI, int NS, int MB, int NB>
__global__ __launch_bounds__(256) void mfma_gemm_kernel(
    const u16* __restrict__ A,
    const u16* __restrict__ Bw,
    const float* __restrict__ bias,
    const float* __restrict__ bias_post,
    const float* __restrict__ avg_o,
    const float* __restrict__ max_o,
    const float* __restrict__ swp,
    const float* __restrict__ sbp,
    void* __restrict__ outv,
    float* __restrict__ csum,
    float* __restrict__ csq,
    float* __restrict__ gsum)
{
    constexpr int MI = MB / 32;
    constexpr int NJ = NB / 32;
    constexpr int ABUF = MB * 32;
    constexpr int BBUF = NB * 32;
    constexpr int BUFSZ = ABUF + BBUF;
    constexpr int GA = MB / 64;
    constexpr int GB = NB / 64;
    constexpr int LD = GA + GB;
    constexpr int NCH = KD / 32;
    constexpr int GX = NS / NB;
    constexpr int NWG = (M / MB) * GX;   // %8 == 0 for both instantiations
    constexpr int CPX = NWG / 8;
    extern __shared__ u16 smem[];
    const int t = threadIdx.x;
    const int lane = t & 63;

    // XCD-chunked bijective block swizzle
    const int lin = blockIdx.y * GX + blockIdx.x;
    const int swz = (lin & 7) * CPX + (lin >> 3);
    const int bx = swz % GX;
    const int by = swz / GX;
    const int row0 = by * MB;
    const int col0 = bx * NB;
    const int bb = row0 >> 10;           // batch index (MB divides 1024)

    const int wv = t >> 6;
    const int wrow = (wv >> 1) * (MB / 2);
    const int wcol = (wv & 1) * (NB / 2);
    const int lm = lane & 15;
    const int lk8 = (lane >> 4) * 8;
    const int srow = t >> 2;
    const int scol = (t & 3) * 8;
    const u16* gA = A + (size_t)(row0 + srow) * KD + scol;
    const u16* gB = Bw + (EPI == 1 ? (size_t)bb * NS * KD : (size_t)0)
                       + (size_t)(col0 + srow) * KD + scol;
    const float* biasp = bias + (EPI == 1 ? bb * NS : 0);

    const floatx4 zero = {0.f, 0.f, 0.f, 0.f};
    floatx4 acc[MI][NJ];
#pragma unroll
    for (int i = 0; i < MI; ++i)
#pragma unroll
        for (int j = 0; j < NJ; ++j) acc[i][j] = zero;

    auto stage = [&](u16* buf, int c) {
        const int kk = c * 32;
        u16* As = buf;
        u16* Bs = buf + ABUF;
#pragma unroll
        for (int g = 0; g < GA; ++g)
            GLOAD(gA + (size_t)g * 64 * KD + kk, As + g * 2048 + t * 8);
#pragma unroll
        for (int g = 0; g < GB; ++g)
            GLOAD(gB + (size_t)g * 64 * KD + kk, Bs + g * 2048 + t * 8);
    };
    auto compute = [&](const u16* buf) {
        const u16* As = buf;
        const u16* Bs = buf + ABUF;
        short8 af[MI], bf[NJ];
#pragma unroll
        for (int i = 0; i < MI; ++i)
            af[i] = *(const short8*)(As + (wrow + i * 16 + lm) * 32 + lk8);
#pragma unroll
        for (int j = 0; j < NJ; ++j)
            bf[j] = *(const short8*)(Bs + (wcol + j * 16 + lm) * 32 + lk8);
#pragma unroll
        for (int i = 0; i < MI; ++i)
#pragma unroll
            for (int j = 0; j < NJ; ++j)
                acc[i][j] = __builtin_amdgcn_mfma_f32_16x16x32_bf16(af[i], bf[j], acc[i][j], 0, 0, 0);
    };

    stage(smem, 0);

    // EPI1 prologue: compute sp for this block's 128 rows (4 h-rows of batch bb).
    // LDS ext region sits at byte 32768+ (above Cs): pa[320], pm[320], sw[98], sp[128].
    float* ext = (float*)smem + 8192;
    if constexpr (EPI == 1) {
        const int p0 = (by & 7) * MB;        // first pixel of tile (MB==128)
        const int h0 = p0 >> 5;              // first h row
        const int bbase = bb * P;
        for (int e = t; e < 640; e += 256) {
            const bool isM = e >= 320;
            const int idx = isM ? e - 320 : e;
            const int r = idx >> 5, w = idx & 31;
            const int hh = h0 - 3 + r;
            float v = 0.f;
            if (hh >= 0 && hh < H) v = (isM ? max_o : avg_o)[bbase + hh * W + w];
            ext[e] = v;
        }
        if (t < 98) ext[640 + t] = swp[t];
        __syncthreads();
        if (t < 128) {
            const int hl = t >> 5, w = t & 31;
            float a = sbp[0];
#pragma unroll
            for (int i = 0; i < 7; ++i) {
                const int r = hl + i;        // pa row (h0+hl+i-3), zero-padded out of range
#pragma unroll
                for (int j = 0; j < 7; ++j) {
                    const int ww = w + j - 3;
                    if (ww < 0 || ww >= W) continue;
                    a = fmaf(ext[640 + i * 7 + j], ext[r * 32 + ww], a);
                    a = fmaf(ext[640 + 49 + i * 7 + j], ext[320 + r * 32 + ww], a);
                }
            }
            ext[768 + t] = 1.0f / (1.0f + expf(-a));
        }
    }

    for (int c = 0; c < NCH; ++c) {
        u16* curb = smem + (c & 1) * BUFSZ;
        if (c + 1 < NCH) {
            stage(smem + ((c + 1) & 1) * BUFSZ, c + 1);
            if constexpr (LD == 2) asm volatile("s_waitcnt vmcnt(2)" ::: "memory");
            else                   asm volatile("s_waitcnt vmcnt(3)" ::: "memory");
        } else {
            asm volatile("s_waitcnt vmcnt(0)" ::: "memory");
        }
        __builtin_amdgcn_s_barrier();
        compute(curb);
        asm volatile("s_waitcnt lgkmcnt(0)" ::: "memory");
        __builtin_amdgcn_s_barrier();
    }

    float colsum[NJ], colsq[NJ];
#pragma unroll
    for (int j = 0; j < NJ; ++j) { colsum[j] = 0.f; colsq[j] = 0.f; }

    if (EPI == 0) {
        u16* Cs = smem;
#pragma unroll
        for (int i = 0; i < MI; ++i) {
#pragma unroll
            for (int r = 0; r < 4; ++r) {
                const int lrow = wrow + i * 16 + (lane >> 4) * 4 + r;
#pragma unroll
                for (int j = 0; j < NJ; ++j) {
                    const int lcol = wcol + j * 16 + lm;
                    const float tv = gelu_exact(acc[i][j][r] + biasp[col0 + lcol]);
                    Cs[lrow * NB + lcol] = f2bf(tv);
                    colsum[j] += tv;
                    colsq[j] = fmaf(tv, tv, colsq[j]);
                }
            }
        }
        __syncthreads();
        constexpr int TPR = NB / 8;
        constexpr int RPP = 256 / TPR;
        u16* outp = (u16*)outv;
#pragma unroll
        for (int pp = 0; pp < MB / RPP; ++pp) {
            const int r = pp * RPP + t / TPR;
            const int cc = (t % TPR) * 8;
            *(uint4*)(outp + (size_t)(row0 + r) * NS + col0 + cc) =
                *(const uint4*)(Cs + r * NB + cc);
        }
    } else {
        float* Cs = (float*)smem;            // 32KB region; ext (sp) is above it
#pragma unroll
        for (int i = 0; i < MI; ++i) {
#pragma unroll
            for (int r = 0; r < 4; ++r) {
                const int lrow = wrow + i * 16 + (lane >> 4) * 4 + r;
                const float rs = ext[768 + lrow];
#pragma unroll
                for (int j = 0; j < NJ; ++j) {
                    const int lcol = wcol + j * 16 + lm;
                    const float tv = rs * (acc[i][j][r] + biasp[col0 + lcol])
                                   + bias_post[col0 + lcol];
                    Cs[lrow * NB + lcol] = tv;
                    colsum[j] += tv;
                    colsq[j] = fmaf(tv, tv, colsq[j]);
                }
            }
        }
        __syncthreads();
        constexpr int TPR = NB / 4;
        constexpr int RPP = 256 / TPR;
        float* outp = (float*)outv;
#pragma unroll
        for (int pp = 0; pp < MB / RPP; ++pp) {
            const int r = pp * RPP + t / TPR;
            const int cc = (t % TPR) * 4;
            *(float4*)(outp + (size_t)(row0 + r) * NS + col0 + cc) =
                *(const float4*)(Cs + r * NB + cc);
        }
    }

#pragma unroll
    for (int j = 0; j < NJ; ++j) {
        float s = colsum[j];
        float q = colsq[j];
        s += __shfl_xor(s, 16); s += __shfl_xor(s, 32);
        q += __shfl_xor(q, 16); q += __shfl_xor(q, 32);
        if (lane < 16) {
            const int c = col0 + wcol + j * 16 + lm;
            atomicAdd(&csum[c], s);
            atomicAdd(&csq[c], q);
            if (EPI == 0) atomicAdd(&gsum[bb * NS + c], s);
        }
    }
}

// ---------------- K4: dynamic kernel MLP + fused BN1 stats ----------------
__global__ __launch_bounds__(1024) void dynmlp_kernel(const float* __restrict__ chsum1,
                                                      const float* __restrict__ chsq1,
                                                      const float* __restrict__ gapsum,
                                                      const float* __restrict__ g1,
                                                      const float* __restrict__ be1,
                                                      const float* __restrict__ aw1,
                                                      const float* __restrict__ ab1,
                                                      const float* __restrict__ aw2,
                                                      const float* __restrict__ ab2,
                                                      float* __restrict__ scale1,
                                                      float* __restrict__ shift1,
                                                      float* __restrict__ kw) {
    const int b = blockIdx.x;
    const int t = threadIdx.x;
    const int wave = t >> 6, lane = t & 63;
    __shared__ float g[1024];
    __shared__ float h1[128];
    __shared__ float logits[12];
    {
        const float m = chsum1[t] * (1.0f / (float)M);
        const float var = chsq1[t] * (1.0f / (float)M) - m * m;
        const float rstd = rsqrtf(var + EPS);
        const float sc = rstd * g1[t];
        const float sh = be1[t] - m * sc;
        if (b == 0) { scale1[t] = sc; shift1[t] = sh; }
        g[t] = gapsum[b * C + t] * (1.0f / (float)P) * sc + sh;
    }
    __syncthreads();
#pragma unroll
    for (int k = 0; k < 8; ++k) {
        const int u = wave * 8 + k;
        const float4* wr = (const float4*)(aw1 + (size_t)u * C);
        float s = 0.f;
#pragma unroll
        for (int ch = 0; ch < 4; ++ch) {
            const float4 wv = wr[lane + 64 * ch];
            const float4 sv = *(const float4*)(g + 4 * lane + 256 * ch);
            s += wv.x * sv.x + wv.y * sv.y + wv.z * sv.z + wv.w * sv.w;
        }
#pragma unroll
        for (int off = 1; off < 64; off <<= 1) s += __shfl_xor(s, off);
        if (lane == 0) h1[u] = fmaxf(s + ab1[u], 0.f);
    }
    __syncthreads();
    if (wave < 9) {
        float s = aw2[wave * 128 + lane] * h1[lane]
                + aw2[wave * 128 + 64 + lane] * h1[64 + lane];
#pragma unroll
        for (int off = 1; off < 64; off <<= 1) s += __shfl_xor(s, off);
        if (lane == 0) logits[wave] = s + ab2[wave];
    }
    __syncthreads();
    if (t == 0) {
        float mx = logits[0];
        for (int i = 1; i < 9; ++i) mx = fmaxf(mx, logits[i]);
        float e[9], den = 0.f;
        for (int i = 0; i < 9; ++i) { e[i] = expf(logits[i] - mx); den += e[i]; }
        const float inv = 1.0f / den;
        for (int i = 0; i < 9; ++i) kw[b * 9 + i] = e[i] * inv;
    }
}

// ---------------- K5: dyn depthwise conv — sliding-window registers ----------------
__global__ __launch_bounds__(256) void dwconv_kernel(const u16* __restrict__ t1b,
                                                     const float* __restrict__ scale1,
                                                     const float* __restrict__ shift1,
                                                     const float* __restrict__ kw,
                                                     u16* __restrict__ t2b,
                                                     float* __restrict__ chsum2,
                                                     float* __restrict__ chsq2,
                                                     float* __restrict__ bsum2,
                                                     u32* __restrict__ umax2,
                                                     u32* __restrict__ umaxn2) {
    __shared__ u16 rows[3 * 32 * 256];   // 48 KB: [r][w][ch]
    const int lin = blockIdx.y * 4 + blockIdx.x;     // nwg = 1024
    const int swz = (lin & 7) * 128 + (lin >> 3);
    const int cq = swz & 3;
    const int bh = swz >> 2;
    const int b = bh >> 5;
    const int h = bh & 31;
    const int t = threadIdx.x;

    const u16* gbase = t1b + (size_t)b * P * C + cq * 256;
#pragma unroll
    for (int i = 0; i < 12; ++i) {
        const int lin2 = i * 256 + t;
        const int chunk = lin2 >> 5;
        const int r = chunk >> 5;
        const int w = chunk & 31;
        const int off8 = (lin2 & 31) * 8;
        const int hr = h + r - 1;
        uint4 v = {0u, 0u, 0u, 0u};
        if (hr >= 0 && hr < H)
            v = *(const uint4*)(gbase + (size_t)(hr * W + w) * C + off8);
        *(uint4*)(&rows[chunk * 256 + off8]) = v;
    }
    __syncthreads();

    const int c = t;
    const int gc = cq * 256 + c;
    float kk[9];
#pragma unroll
    for (int i = 0; i < 9; ++i) kk[i] = kw[b * 9 + i];
    const float sc = scale1[gc];
    const float sh = shift1[gc];
    float scm[3], shm[3];
    scm[0] = (h > 0)     ? sc : 0.f;  shm[0] = (h > 0)     ? sh : 0.f;
    scm[1] = sc;                      shm[1] = sh;
    scm[2] = (h < H - 1) ? sc : 0.f;  shm[2] = (h < H - 1) ? sh : 0.f;

    const u16* rp0 = rows + c;
#define DWVAL(ri, w) fmaf(bf2f(rp0[((ri) * 32 + (w)) * 256]), scm[ri], shm[ri])

    float vm0 = 0.f, vm1 = 0.f, vm2 = 0.f;
    float vc0 = DWVAL(0, 0), vc1 = DWVAL(1, 0), vc2 = DWVAL(2, 0);
    float vp0 = DWVAL(0, 1), vp1 = DWVAL(1, 1), vp2 = DWVAL(2, 1);

    float s = 0.f, q = 0.f, mx = -INFINITY, mn = INFINITY;
    u16* orow = t2b + ((size_t)b * P + h * W) * C + gc;
    for (int w = 0; w < W; ++w) {
        float acc;
        acc = kk[0] * vm0;
        acc = fmaf(kk[1], vc0, acc);
        acc = fmaf(kk[2], vp0, acc);
        acc = fmaf(kk[3], vm1, acc);
        acc = fmaf(kk[4], vc1, acc);
        acc = fmaf(kk[5], vp1, acc);
        acc = fmaf(kk[6], vm2, acc);
        acc = fmaf(kk[7], vc2, acc);
        acc = fmaf(kk[8], vp2, acc);
        const float y = gelu_exact(acc);
        orow[(size_t)w * C] = f2bf(y);
        s += y;
        q = fmaf(y, y, q);
        mx = fmaxf(mx, y);
        mn = fminf(mn, y);
        vm0 = vc0; vc0 = vp0;
        vm1 = vc1; vc1 = vp1;
        vm2 = vc2; vc2 = vp2;
        if (w + 2 < W) {
            vp0 = DWVAL(0, w + 2);
            vp1 = DWVAL(1, w + 2);
            vp2 = DWVAL(2, w + 2);
        } else {
            vp0 = 0.f; vp1 = 0.f; vp2 = 0.f;
        }
    }
#undef DWVAL
    atomicAdd(&chsum2[gc], s);
    atomicAdd(&chsq2[gc], q);
    atomicAdd(&bsum2[b * C + gc], s);
    atomicMax(&umax2[b * C + gc], fkey(mx));
    atomicMax(&umaxn2[b * C + gc], fkey(-mn));
}

// ---------------- K8: channel attention + O(1) BN2 finalize (s_att only) ----------------
__global__ __launch_bounds__(1024) void chatt_kernel(const float* __restrict__ chsum2,
                                                     const float* __restrict__ chsq2,
                                                     const float* __restrict__ bsum2,
                                                     const u32* __restrict__ umax2,
                                                     const u32* __restrict__ umaxn2,
                                                     const float* __restrict__ g2,
                                                     const float* __restrict__ be2,
                                                     const float* __restrict__ caw1,
                                                     const float* __restrict__ caw2,
                                                     float* __restrict__ scale2,
                                                     float* __restrict__ shift2,
                                                     float* __restrict__ s_att) {
    const int b = blockIdx.x;
    const int t = threadIdx.x;          // channel
    const int wave = t >> 6, lane = t & 63;
    __shared__ float la[1024], lx[1024], ha[64], hm[64];
    {
        const float m = chsum2[t] * (1.0f / (float)M);
        const float var = chsq2[t] * (1.0f / (float)M) - m * m;
        const float rstd = rsqrtf(var + EPS);
        const float sc = rstd * g2[t];
        const float sh = be2[t] - m * sc;
        if (b == 0) { scale2[t] = sc; shift2[t] = sh; }
        la[t] = bsum2[b * C + t] * (1.0f / (float)P) * sc + sh;
        const float mx = fkeyinv(umax2[b * C + t]);
        const float mn = -fkeyinv(umaxn2[b * C + t]);
        lx[t] = (sc >= 0.f ? mx : mn) * sc + sh;
    }
    __syncthreads();
#pragma unroll
    for (int k = 0; k < 8; ++k) {
        const int u = wave * 8 + k;
        const int row = u & 63;
        const float* src = (u < 64) ? la : lx;
        const float4* wr = (const float4*)(caw1 + (size_t)row * C);
        float s = 0.f;
#pragma unroll
        for (int ch = 0; ch < 4; ++ch) {
            const float4 wv = wr[lane + 64 * ch];
            const float4 sv = *(const float4*)(src + 4 * lane + 256 * ch);
            s += wv.x * sv.x + wv.y * sv.y + wv.z * sv.z + wv.w * sv.w;
        }
#pragma unroll
        for (int off = 1; off < 64; off <<= 1) s += __shfl_xor(s, off);
        if (lane == 0) {
            s = fmaxf(s, 0.f);
            if (u < 64) ha[row] = s; else hm[row] = s;
        }
    }
    __syncthreads();
    {
        const float4* w2 = (const float4*)(caw2 + (size_t)t * 64);
        float s = 0.f;
#pragma unroll
        for (int j = 0; j < 16; ++j) {
            const float4 wv = w2[j];
            s += wv.x * (ha[j * 4 + 0] + hm[j * 4 + 0]);
            s += wv.y * (ha[j * 4 + 1] + hm[j * 4 + 1]);
            s += wv.z * (ha[j * 4 + 2] + hm[j * 4 + 2]);
            s += wv.w * (ha[j * 4 + 3] + hm[j * 4 + 3]);
        }
        s_att[b * C + t] = 1.0f / (1.0f + expf(-s));
    }
}

// ---------------- K9: fused {per-row avg/max of y} + {weight folding} ----------------
// blocks [0, M): yq for row = bid.  blocks [M, M+B*D): fold for bd = bid - M.
// fold: pwb[b][d][c] = bf16(pw[d][c]*scale2[c]*s_att[b][c]);
//       bias2[b][d]  = sum_c pw[d][c]*shift2[c]*s_att[b][c]   (NO pb — added post-sp in gemm2)
__global__ __launch_bounds__(256) void yqfold_kernel(const u16* __restrict__ t2b,
                                                     const float* __restrict__ scale2,
                                                     const float* __restrict__ shift2,
                                                     const float* __restrict__ s_att,
                                                     const float* __restrict__ pw,
                                                     float* __restrict__ avg_o,
                                                     float* __restrict__ max_o,
                                                     u16* __restrict__ pwb,
                                                     float* __restrict__ bias2) {
    const int bid = blockIdx.x;
    const int t = threadIdx.x;
    const int wave = t >> 6, lane = t & 63;
    __shared__ float r0[4], r1[4];
    if (bid < M) {
        const int row = bid;
        const int b = row >> 10;
        const int c0 = t * 4;
        const uint2 vv = *(const uint2*)(t2b + (size_t)row * C + c0);
        const float v0 = bf2f((u16)(vv.x & 0xffff));
        const float v1 = bf2f((u16)(vv.x >> 16));
        const float v2 = bf2f((u16)(vv.y & 0xffff));
        const float v3 = bf2f((u16)(vv.y >> 16));
        const float4 sc = *(const float4*)(scale2 + c0);
        const float4 sh = *(const float4*)(shift2 + c0);
        const float4 sa = *(const float4*)(s_att + (size_t)b * C + c0);
        const float y0 = fmaf(v0, sc.x, sh.x) * sa.x;
        const float y1 = fmaf(v1, sc.y, sh.y) * sa.y;
        const float y2 = fmaf(v2, sc.z, sh.z) * sa.z;
        const float y3 = fmaf(v3, sc.w, sh.w) * sa.w;
        float s = (y0 + y1) + (y2 + y3);
        float mx = fmaxf(fmaxf(y0, y1), fmaxf(y2, y3));
#pragma unroll
        for (int off = 32; off > 0; off >>= 1) {
            s += __shfl_down(s, off);
            mx = fmaxf(mx, __shfl_down(mx, off));
        }
        if (lane == 0) { r0[wave] = s; r1[wave] = mx; }
        __syncthreads();
        if (t == 0) {
            const float S = r0[0] + r0[1] + r0[2] + r0[3];
            const float Mx = fmaxf(fmaxf(r1[0], r1[1]), fmaxf(r1[2], r1[3]));
            avg_o[row] = S * (1.0f / (float)C);
            max_o[row] = Mx;
        }
    } else {
        const int bd = bid - M;          // 0..2047
        const int b = bd >> 8;
        const int d = bd & 255;
        const int c0 = t * 4;
        const float4 wv = *(const float4*)(pw + (size_t)d * C + c0);
        const float4 sc = *(const float4*)(scale2 + c0);
        const float4 sh = *(const float4*)(shift2 + c0);
        const float4 sa = *(const float4*)(s_att + (size_t)b * C + c0);
        uint2 o;
        o.x = ((u32)f2bf(wv.x * sc.x * sa.x)) | ((u32)f2bf(wv.y * sc.y * sa.y) << 16);
        o.y = ((u32)f2bf(wv.z * sc.z * sa.z)) | ((u32)f2bf(wv.w * sc.w * sa.w) << 16);
        *(uint2*)(pwb + ((size_t)b * D + d) * C + c0) = o;
        float s = wv.x * sh.x * sa.x + wv.y * sh.y * sa.y
                + wv.z * sh.z * sa.z + wv.w * sh.w * sa.w;
#pragma unroll
        for (int off = 1; off < 64; off <<= 1) s += __shfl_xor(s, off);
        if (lane == 0) r0[wave] = s;
        __syncthreads();
        if (t == 0) bias2[bd] = r0[0] + r0[1] + r0[2] + r0[3];
    }
}

// ---------------- K15: final residual add + fused BN3 stats ----------------
__global__ __launch_bounds__(256) void final_kernel(const float* __restrict__ x,
                                                    const float* __restrict__ pre,
                                                    const float* __restrict__ chsum3,
                                                    const float* __restrict__ chsq3,
                                                    const float* __restrict__ g3,
                                                    const float* __restrict__ be3,
                                                    float* __restrict__ out) {
    __shared__ float lsc[256], lsh[256];
    const int t = threadIdx.x;
    {
        const float m = chsum3[t] * (1.0f / (float)M);
        const float var = chsq3[t] * (1.0f / (float)M) - m * m;
        const float rstd = rsqrtf(var + EPS);
        const float sc = rstd * g3[t];
        lsc[t] = sc;
        lsh[t] = be3[t] - m * sc;
    }
    __syncthreads();
    const int i = blockIdx.x * 256 + t;   // float4 index
    const int e = i * 4;
    const int d = e & 255;
    const float4 xv = *(const float4*)(x + e);
    const float4 pv = *(const float4*)(pre + e);
    const float4 sc = *(const float4*)(lsc + d);
    const float4 sh = *(const float4*)(lsh + d);
    float4 o;
    o.x = xv.x + fmaf(pv.x, sc.x, sh.x);
    o.y = xv.y + fmaf(pv.y, sc.y, sh.y);
    o.z = xv.z + fmaf(pv.z, sc.z, sh.z);
    o.w = xv.w + fmaf(pv.w, sc.w, sh.w);
    *(float4*)(out + e) = o;
}

extern "C" void kernel_launch(void* const* d_in, const int* in_sizes, int n_in,
                              void* d_out, int out_size, void* d_ws, size_t ws_size,
                              hipStream_t stream) {
    const float* x    = (const float*)d_in[0];
    const float* w1   = (const float*)d_in[1];
    const float* b1   = (const float*)d_in[2];
    const float* g1   = (const float*)d_in[3];
    const float* be1  = (const float*)d_in[4];
    const float* aw1  = (const float*)d_in[5];
    const float* ab1  = (const float*)d_in[6];
    const float* aw2  = (const float*)d_in[7];
    const float* ab2  = (const float*)d_in[8];
    const float* g2   = (const float*)d_in[9];
    const float* be2  = (const float*)d_in[10];
    const float* caw1 = (const float*)d_in[11];
    const float* caw2 = (const float*)d_in[12];
    const float* pw   = (const float*)d_in[13];
    const float* pb   = (const float*)d_in[14];
    const float* g3   = (const float*)d_in[15];
    const float* be3  = (const float*)d_in[16];
    const float* sw   = (const float*)d_in[17];
    const float* sb   = (const float*)d_in[18];
    float* out = (float*)d_out;
    float* ws = (float*)d_ws;

    float* chsum1  = ws + WS_CHSUM1;
    float* chsq1   = ws + WS_CHSQ1;
    float* gapsum  = ws + WS_GAPSUM;
    float* chsum3  = ws + WS_CHSUM3;
    float* chsq3   = ws + WS_CHSQ3;
    float* chsum2  = ws + WS_CHSUM2;
    float* chsq2   = ws + WS_CHSQ2;
    float* bsum2   = ws + WS_BSUM2;
    u32*   umax2   = (u32*)(ws + WS_UMAX2);
    u32*   umaxn2  = (u32*)(ws + WS_UMAXN2);
    float* scale1  = ws + WS_SCALE1;
    float* shift1  = ws + WS_SHIFT1;
    float* kw      = ws + WS_KW;
    float* scale2  = ws + WS_SCALE2;
    float* shift2  = ws + WS_SHIFT2;
    float* s_att   = ws + WS_SATT;
    float* avg_o   = ws + WS_AVGO;
    float* max_o   = ws + WS_MAXO;
    float* pre     = ws + WS_PRE;
    float* bias2   = ws + WS_BIAS2;
    u16* t1b  = (u16*)(ws + WS_T1B);
    u16* t2b  = (u16*)(ws + WS_T2B);
    u16* xb   = (u16*)(ws + WS_XB);
    u16* w1b  = (u16*)(ws + WS_W1B);
    u16* pwbf = (u16*)(ws + WS_PWBF);

    // K0: zero accumulators + casts (x, w1)
    cvt_all_kernel<<<dim3(2304), 256, 0, stream>>>(x, w1, xb, w1b, ws);
    // K1: expand GEMM (128x64 tile, BK=32 dbuf, counted vmcnt). 1024 blocks, 24 KB LDS
    mfma_gemm_kernel<256, 0, C, 128, 64><<<dim3(C / 64, M / 128), 256, 24576, stream>>>(
        xb, w1b, b1, nullptr, nullptr, nullptr, nullptr, nullptr,
        t1b, chsum1, chsq1, gapsum);
    // K4: BN1 stats + gap + dynamic kernel weights (fused)
    dynmlp_kernel<<<dim3(B), 1024, 0, stream>>>(chsum1, chsq1, gapsum, g1, be1,
                                                aw1, ab1, aw2, ab2, scale1, shift1, kw);
    // K5: depthwise conv (sliding-window regs, XCD swizzle) + GELU -> bf16 t2, BN2 atomics
    dwconv_kernel<<<dim3(4, B * H), 256, 0, stream>>>(t1b, scale1, shift1, kw, t2b,
                                                      chsum2, chsq2, bsum2, umax2, umaxn2);
    // K8: BN2 finalize + channel attention (s_att only)
    chatt_kernel<<<dim3(B), 1024, 0, stream>>>(chsum2, chsq2, bsum2, umax2, umaxn2,
                                               g2, be2, caw1, caw2, scale2, shift2, s_att);
    // K9: fused yq (rows) + weight folding (b,d rows). 8192 + 2048 blocks.
    yqfold_kernel<<<dim3(M + B * D), 256, 0, stream>>>(t2b, scale2, shift2, s_att, pw,
                                                       avg_o, max_o, pwbf, bias2);
    // K12: project GEMM on folded weights, sp computed IN-KERNEL from avg_o/max_o.
    //      128x64 tile, 256 blocks. Dyn LDS = 32KB Cs + 896 floats ext = 36352 B
    mfma_gemm_kernel<1024, 1, D, 128, 64><<<dim3(D / 64, M / 128), 256, 36352, stream>>>(
        t2b, pwbf, bias2, pb, avg_o, max_o, sw, sb,
        pre, chsum3, chsq3, nullptr);
    // K15: BN3 stats + final residual add (fused)
    final_kernel<<<dim3((M * D / 4) / 256), 256, 0, stream>>>(x, pre, chsum3, chsq3, g3, be3, out);
}

// Round 8
// 198.898 us; speedup vs baseline: 5.3899x; 1.0164x over previous
//
#include <hip/hip_runtime.h>
#include <math.h>

// Problem constants
constexpr int B = 8;
constexpr int D = 256;     // model dim
constexpr int C = 1024;    // expanded channels
constexpr int H = 32, W = 32;
constexpr int P = H * W;            // 1024 spatial positions
constexpr int M = B * P;            // 8192 rows
constexpr float EPS = 1e-5f;

typedef unsigned short u16;
typedef unsigned int u32;
typedef __attribute__((ext_vector_type(8))) short short8;
typedef __attribute__((ext_vector_type(4))) float floatx4;

// ---------------- workspace layout (in floats) ----------------
constexpr size_t WS_CHSUM1 = 0;                  // 1024
constexpr size_t WS_CHSQ1  = 1024;               // 1024
constexpr size_t WS_GAPSUM = 2048;               // 8192
constexpr size_t WS_CHSUM3 = 10240;              // 256
constexpr size_t WS_CHSQ3  = 10496;              // 256
constexpr size_t WS_CHSUM2 = 10752;              // 1024
constexpr size_t WS_CHSQ2  = 11776;              // 1024
constexpr size_t WS_BSUM2  = 12800;              // 8192
constexpr size_t WS_UMAX2  = 20992;              // 8192 (u32 keys)
constexpr size_t WS_UMAXN2 = 29184;              // 8192 (u32 keys of -min)
constexpr size_t WS_ACC_COUNT = 37376;
constexpr size_t WS_SCALE1 = 37376;              // 1024
constexpr size_t WS_SHIFT1 = 38400;              // 1024
constexpr size_t WS_KW     = 39424;              // 256 (72 used)
constexpr size_t WS_SCALE2 = 39680;              // 1024
constexpr size_t WS_SHIFT2 = 40704;              // 1024
constexpr size_t WS_SATT   = 41728;              // 8192
constexpr size_t WS_AVGO   = 49920;              // 8192
constexpr size_t WS_MAXO   = 58112;              // 8192
constexpr size_t WS_SP     = 66304;              // (unused, kept for layout stability)
constexpr size_t WS_PRE    = 74496;              // 2097152
constexpr size_t WS_T1B    = 2171648;            // bf16 t1
constexpr size_t WS_T2B    = 6365952;            // bf16 t2
constexpr size_t WS_XB     = 10560256;           // bf16 x
constexpr size_t WS_W1B    = 11608832;
constexpr size_t WS_PWB    = 11739904;           // (unused, kept for layout stability)
constexpr size_t WS_PWBF   = 11870976;           // folded per-batch weights, 8x256x1024 bf16
constexpr size_t WS_BIAS2  = 12919552;           // 2048 floats (8x256), pb NOT included

__device__ __forceinline__ float gelu_exact(float v) {
    return 0.5f * v * (1.0f + erff(v * 0.70710678118654752440f));
}

__device__ __forceinline__ u16 f2bf(float f) {
    u32 u = __float_as_uint(f);
    u += 0x7fff + ((u >> 16) & 1);   // round-to-nearest-even
    return (u16)(u >> 16);
}

__device__ __forceinline__ float bf2f(u16 v) {
    return __uint_as_float(((u32)v) << 16);
}

// order-preserving float->u32 key
__device__ __forceinline__ u32 fkey(float f) {
    u32 u = __float_as_uint(f);
    return (u & 0x80000000u) ? ~u : (u | 0x80000000u);
}
__device__ __forceinline__ float fkeyinv(u32 k) {
    return __uint_as_float((k & 0x80000000u) ? (k ^ 0x80000000u) : ~k);
}

#define GLOAD(SRC, DST) __builtin_amdgcn_global_load_lds( \
    (const __attribute__((address_space(1))) void*)(SRC), \
    (__attribute__((address_space(3))) void*)(DST), 16, 0, 0)

// ---------------- K0: zero accumulators + cast fp32 -> bf16 for x, w1 ----------------
__global__ __launch_bounds__(256) void cvt_all_kernel(const float* __restrict__ x,
                                                      const float* __restrict__ w1,
                                                      u16* __restrict__ xb,
                                                      u16* __restrict__ w1b,
                                                      float* __restrict__ acc_zero) {
    const int i = blockIdx.x * 256 + threadIdx.x;     // grid covers 589824
    if (i < (int)WS_ACC_COUNT) acc_zero[i] = 0.f;     // 0x0 == fkey floor for max-keys too
    const float* src;
    u16* dst;
    int off;
    if (i < 524288) { src = x;  dst = xb;  off = i; }
    else            { src = w1; dst = w1b; off = i - 524288; }
    const float4 v = *(const float4*)(src + (size_t)off * 4);
    uint2 o;
    o.x = ((u32)f2bf(v.x)) | ((u32)f2bf(v.y) << 16);
    o.y = ((u32)f2bf(v.z)) | ((u32)f2bf(v.w) << 16);
    *(uint2*)(dst + (size_t)off * 4) = o;
}

// ---------------- MFMA bf16 GEMM — 3-buffer 2-deep counted-vmcnt pipeline ----------------
// BK=32 chunks, THREE LDS buffers. While computing chunk c, chunks c+1 AND c+2 are in
// flight (LD=3 loads each): stage(c+2) -> vmcnt(6) [c landed, 6 newer loads in flight]
// -> barrier -> MFMA -> lgkmcnt(0) -> barrier. Drain to vmcnt(3)/(0) only at the tail.
// EPI 0: t = gelu(acc+bias); bf16 out; col stats + gsum.  Shared B, shared bias.
// EPI 1: t = sp*(acc+bias) + bias_post; fp32 out; col stats. PER-BATCH B (folded pwb).
//        sp (7x7 spatial conv + sigmoid) computed in-kernel from avg_o/max_o; lives in
//        LDS at byte 36864+ (above the 3 staging buffers AND the 32KB epilogue Cs).
template<int KD, int EPI, int NS, int MB, int NB>
__global__ __launch_bounds__(256) void mfma_gemm_kernel(
    const u16* __restrict__ A,
    const u16* __restrict__ Bw,
    const float* __restrict__ bias,
    const float* __restrict__ bias_post,
    const float* __restrict__ avg_o,
    const float* __restrict__ max_o,
    const float* __restrict__ swp,
    const float* __restrict__ sbp,
    void* __restrict__ outv,
    float* __restrict__ csum,
    float* __restrict__ csq,
    float* __restrict__ gsum)
{
    constexpr int MI = MB / 32;
    constexpr int NJ = NB / 32;
    constexpr int ABUF = MB * 32;
    constexpr int BBUF = NB * 32;
    constexpr int BUFSZ = ABUF + BBUF;
    constexpr int GA = MB / 64;
    constexpr int GB = NB / 64;
    constexpr int LD = GA + GB;
    static_assert(LD == 3, "vmcnt literals assume 3 loads per chunk");
    constexpr int NCH = KD / 32;
    constexpr int GX = NS / NB;
    constexpr int NWG = (M / MB) * GX;   // %8 == 0 for both instantiations
    constexpr int CPX = NWG / 8;
    extern __shared__ u16 smem[];
    const int t = threadIdx.x;
    const int lane = t & 63;

    // XCD-chunked bijective block swizzle
    const int lin = blockIdx.y * GX + blockIdx.x;
    const int swz = (lin & 7) * CPX + (lin >> 3);
    const int bx = swz % GX;
    const int by = swz / GX;
    const int row0 = by * MB;
    const int col0 = bx * NB;
    const int bb = row0 >> 10;           // batch index (MB divides 1024)

    const int wv = t >> 6;
    const int wrow = (wv >> 1) * (MB / 2);
    const int wcol = (wv & 1) * (NB / 2);
    const int lm = lane & 15;
    const int lk8 = (lane >> 4) * 8;
    const int srow = t >> 2;
    const int scol = (t & 3) * 8;
    const u16* gA = A + (size_t)(row0 + srow) * KD + scol;
    const u16* gB = Bw + (EPI == 1 ? (size_t)bb * NS * KD : (size_t)0)
                       + (size_t)(col0 + srow) * KD + scol;
    const float* biasp = bias + (EPI == 1 ? bb * NS : 0);

    const floatx4 zero = {0.f, 0.f, 0.f, 0.f};
    floatx4 acc[MI][NJ];
#pragma unroll
    for (int i = 0; i < MI; ++i)
#pragma unroll
        for (int j = 0; j < NJ; ++j) acc[i][j] = zero;

    auto stage = [&](u16* buf, int c) {
        const int kk = c * 32;
        u16* As = buf;
        u16* Bs = buf + ABUF;
#pragma unroll
        for (int g = 0; g < GA; ++g)
            GLOAD(gA + (size_t)g * 64 * KD + kk, As + g * 2048 + t * 8);
#pragma unroll
        for (int g = 0; g < GB; ++g)
            GLOAD(gB + (size_t)g * 64 * KD + kk, Bs + g * 2048 + t * 8);
    };
    auto compute = [&](const u16* buf) {
        const u16* As = buf;
        const u16* Bs = buf + ABUF;
        short8 af[MI], bf[NJ];
#pragma unroll
        for (int i = 0; i < MI; ++i)
            af[i] = *(const short8*)(As + (wrow + i * 16 + lm) * 32 + lk8);
#pragma unroll
        for (int j = 0; j < NJ; ++j)
            bf[j] = *(const short8*)(Bs + (wcol + j * 16 + lm) * 32 + lk8);
#pragma unroll
        for (int i = 0; i < MI; ++i)
#pragma unroll
            for (int j = 0; j < NJ; ++j)
                acc[i][j] = __builtin_amdgcn_mfma_f32_16x16x32_bf16(af[i], bf[j], acc[i][j], 0, 0, 0);
    };

    stage(smem, 0);
    if (NCH > 1) stage(smem + BUFSZ, 1);

    // EPI1 prologue: compute sp for this block's 128 rows (4 h-rows of batch bb).
    // LDS ext region at float offset 9216 (byte 36864): pa[320], pm[320], sw[98], sp[128].
    // NOTE: the __syncthreads() here drains the two staged chunks too — conservative, safe.
    float* ext = (float*)smem + 9216;
    if constexpr (EPI == 1) {
        const int p0 = (by & 7) * MB;        // first pixel of tile (MB==128)
        const int h0 = p0 >> 5;              // first h row
        const int bbase = bb * P;
        for (int e = t; e < 640; e += 256) {
            const bool isM = e >= 320;
            const int idx = isM ? e - 320 : e;
            const int r = idx >> 5, w = idx & 31;
            const int hh = h0 - 3 + r;
            float v = 0.f;
            if (hh >= 0 && hh < H) v = (isM ? max_o : avg_o)[bbase + hh * W + w];
            ext[e] = v;
        }
        if (t < 98) ext[640 + t] = swp[t];
        __syncthreads();
        if (t < 128) {
            const int hl = t >> 5, w = t & 31;
            float a = sbp[0];
#pragma unroll
            for (int i = 0; i < 7; ++i) {
                const int r = hl + i;        // pa row (h0+hl+i-3), zero-padded out of range
#pragma unroll
                for (int j = 0; j < 7; ++j) {
                    const int ww = w + j - 3;
                    if (ww < 0 || ww >= W) continue;
                    a = fmaf(ext[640 + i * 7 + j], ext[r * 32 + ww], a);
                    a = fmaf(ext[640 + 49 + i * 7 + j], ext[320 + r * 32 + ww], a);
                }
            }
            ext[768 + t] = 1.0f / (1.0f + expf(-a));
        }
    }

    int cur = 0;
    for (int c = 0; c < NCH; ++c) {
        if (c + 2 < NCH) {
            const int nb3 = (cur + 2 >= 3) ? cur - 1 : cur + 2;
            stage(smem + nb3 * BUFSZ, c + 2);
            asm volatile("s_waitcnt vmcnt(6)" ::: "memory");
        } else if (c + 1 < NCH) {
            asm volatile("s_waitcnt vmcnt(3)" ::: "memory");
        } else {
            asm volatile("s_waitcnt vmcnt(0)" ::: "memory");
        }
        __builtin_amdgcn_s_barrier();
        compute(smem + cur * BUFSZ);
        asm volatile("s_waitcnt lgkmcnt(0)" ::: "memory");
        __builtin_amdgcn_s_barrier();
        cur = (cur + 1 >= 3) ? 0 : cur + 1;
    }

    float colsum[NJ], colsq[NJ];
#pragma unroll
    for (int j = 0; j < NJ; ++j) { colsum[j] = 0.f; colsq[j] = 0.f; }

    if (EPI == 0) {
        u16* Cs = smem;
#pragma unroll
        for (int i = 0; i < MI; ++i) {
#pragma unroll
            for (int r = 0; r < 4; ++r) {
                const int lrow = wrow + i * 16 + (lane >> 4) * 4 + r;
#pragma unroll
                for (int j = 0; j < NJ; ++j) {
                    const int lcol = wcol + j * 16 + lm;
                    const float tv = gelu_exact(acc[i][j][r] + biasp[col0 + lcol]);
                    Cs[lrow * NB + lcol] = f2bf(tv);
                    colsum[j] += tv;
                    colsq[j] = fmaf(tv, tv, colsq[j]);
                }
            }
        }
        __syncthreads();
        constexpr int TPR = NB / 8;
        constexpr int RPP = 256 / TPR;
        u16* outp = (u16*)outv;
#pragma unroll
        for (int pp = 0; pp < MB / RPP; ++pp) {
            const int r = pp * RPP + t / TPR;
            const int cc = (t % TPR) * 8;
            *(uint4*)(outp + (size_t)(row0 + r) * NS + col0 + cc) =
                *(const uint4*)(Cs + r * NB + cc);
        }
    } else {
        float* Cs = (float*)smem;            // 32KB region; ext (sp) is above it at 36864
#pragma unroll
        for (int i = 0; i < MI; ++i) {
#pragma unroll
            for (int r = 0; r < 4; ++r) {
                const int lrow = wrow + i * 16 + (lane >> 4) * 4 + r;
                const float rs = ext[768 + lrow];
#pragma unroll
                for (int j = 0; j < NJ; ++j) {
                    const int lcol = wcol + j * 16 + lm;
                    const float tv = rs * (acc[i][j][r] + biasp[col0 + lcol])
                                   + bias_post[col0 + lcol];
                    Cs[lrow * NB + lcol] = tv;
                    colsum[j] += tv;
                    colsq[j] = fmaf(tv, tv, colsq[j]);
                }
            }
        }
        __syncthreads();
        constexpr int TPR = NB / 4;
        constexpr int RPP = 256 / TPR;
        float* outp = (float*)outv;
#pragma unroll
        for (int pp = 0; pp < MB / RPP; ++pp) {
            const int r = pp * RPP + t / TPR;
            const int cc = (t % TPR) * 4;
            *(float4*)(outp + (size_t)(row0 + r) * NS + col0 + cc) =
                *(const float4*)(Cs + r * NB + cc);
        }
    }

#pragma unroll
    for (int j = 0; j < NJ; ++j) {
        float s = colsum[j];
        float q = colsq[j];
        s += __shfl_xor(s, 16); s += __shfl_xor(s, 32);
        q += __shfl_xor(q, 16); q += __shfl_xor(q, 32);
        if (lane < 16) {
            const int c = col0 + wcol + j * 16 + lm;
            atomicAdd(&csum[c], s);
            atomicAdd(&csq[c], q);
            if (EPI == 0) atomicAdd(&gsum[bb * NS + c], s);
        }
    }
}

// ---------------- K4: dynamic kernel MLP + fused BN1 stats ----------------
__global__ __launch_bounds__(1024) void dynmlp_kernel(const float* __restrict__ chsum1,
                                                      const float* __restrict__ chsq1,
                                                      const float* __restrict__ gapsum,
                                                      const float* __restrict__ g1,
                                                      const float* __restrict__ be1,
                                                      const float* __restrict__ aw1,
                                                      const float* __restrict__ ab1,
                                                      const float* __restrict__ aw2,
                                                      const float* __restrict__ ab2,
                                                      float* __restrict__ scale1,
                                                      float* __restrict__ shift1,
                                                      float* __restrict__ kw) {
    const int b = blockIdx.x;
    const int t = threadIdx.x;
    const int wave = t >> 6, lane = t & 63;
    __shared__ float g[1024];
    __shared__ float h1[128];
    __shared__ float logits[12];
    {
        const float m = chsum1[t] * (1.0f / (float)M);
        const float var = chsq1[t] * (1.0f / (float)M) - m * m;
        const float rstd = rsqrtf(var + EPS);
        const float sc = rstd * g1[t];
        const float sh = be1[t] - m * sc;
        if (b == 0) { scale1[t] = sc; shift1[t] = sh; }
        g[t] = gapsum[b * C + t] * (1.0f / (float)P) * sc + sh;
    }
    __syncthreads();
#pragma unroll
    for (int k = 0; k < 8; ++k) {
        const int u = wave * 8 + k;
        const float4* wr = (const float4*)(aw1 + (size_t)u * C);
        float s = 0.f;
#pragma unroll
        for (int ch = 0; ch < 4; ++ch) {
            const float4 wv = wr[lane + 64 * ch];
            const float4 sv = *(const float4*)(g + 4 * lane + 256 * ch);
            s += wv.x * sv.x + wv.y * sv.y + wv.z * sv.z + wv.w * sv.w;
        }
#pragma unroll
        for (int off = 1; off < 64; off <<= 1) s += __shfl_xor(s, off);
        if (lane == 0) h1[u] = fmaxf(s + ab1[u], 0.f);
    }
    __syncthreads();
    if (wave < 9) {
        float s = aw2[wave * 128 + lane] * h1[lane]
                + aw2[wave * 128 + 64 + lane] * h1[64 + lane];
#pragma unroll
        for (int off = 1; off < 64; off <<= 1) s += __shfl_xor(s, off);
        if (lane == 0) logits[wave] = s + ab2[wave];
    }
    __syncthreads();
    if (t == 0) {
        float mx = logits[0];
        for (int i = 1; i < 9; ++i) mx = fmaxf(mx, logits[i]);
        float e[9], den = 0.f;
        for (int i = 0; i < 9; ++i) { e[i] = expf(logits[i] - mx); den += e[i]; }
        const float inv = 1.0f / den;
        for (int i = 0; i < 9; ++i) kw[b * 9 + i] = e[i] * inv;
    }
}

// ---------------- K5: dyn depthwise conv — sliding-window regs, h-band XCD swizzle ------
// XCD = h>>2 (hardware xcd = lin%8): h-1/h/h+1 halo rows land in the SAME per-XCD L2
// (except 25% band-boundary rows), so the 3x re-read of t1b rows hits L2 not L3.
__global__ __launch_bounds__(256) void dwconv_kernel(const u16* __restrict__ t1b,
                                                     const float* __restrict__ scale1,
                                                     const float* __restrict__ shift1,
                                                     const float* __restrict__ kw,
                                                     u16* __restrict__ t2b,
                                                     float* __restrict__ chsum2,
                                                     float* __restrict__ chsq2,
                                                     float* __restrict__ bsum2,
                                                     u32* __restrict__ umax2,
                                                     u32* __restrict__ umaxn2) {
    __shared__ u16 rows[3 * 32 * 256];   // 48 KB: [r][w][ch]
    const int lin = blockIdx.y * 4 + blockIdx.x;     // nwg = 1024
    const int xcd = lin & 7;
    const int i7 = lin >> 3;             // 0..127
    const int b = i7 >> 4;
    const int r4 = i7 & 15;
    const int h = xcd * 4 + (r4 >> 2);
    const int cq = r4 & 3;
    const int t = threadIdx.x;

    const u16* gbase = t1b + (size_t)b * P * C + cq * 256;
#pragma unroll
    for (int i = 0; i < 12; ++i) {
        const int lin2 = i * 256 + t;
        const int chunk = lin2 >> 5;
        const int r = chunk >> 5;
        const int w = chunk & 31;
        const int off8 = (lin2 & 31) * 8;
        const int hr = h + r - 1;
        uint4 v = {0u, 0u, 0u, 0u};
        if (hr >= 0 && hr < H)
            v = *(const uint4*)(gbase + (size_t)(hr * W + w) * C + off8);
        *(uint4*)(&rows[chunk * 256 + off8]) = v;
    }
    __syncthreads();

    const int c = t;
    const int gc = cq * 256 + c;
    float kk[9];
#pragma unroll
    for (int i = 0; i < 9; ++i) kk[i] = kw[b * 9 + i];
    const float sc = scale1[gc];
    const float sh = shift1[gc];
    float scm[3], shm[3];
    scm[0] = (h > 0)     ? sc : 0.f;  shm[0] = (h > 0)     ? sh : 0.f;
    scm[1] = sc;                      shm[1] = sh;
    scm[2] = (h < H - 1) ? sc : 0.f;  shm[2] = (h < H - 1) ? sh : 0.f;

    const u16* rp0 = rows + c;
#define DWVAL(ri, w) fmaf(bf2f(rp0[((ri) * 32 + (w)) * 256]), scm[ri], shm[ri])

    float vm0 = 0.f, vm1 = 0.f, vm2 = 0.f;
    float vc0 = DWVAL(0, 0), vc1 = DWVAL(1, 0), vc2 = DWVAL(2, 0);
    float vp0 = DWVAL(0, 1), vp1 = DWVAL(1, 1), vp2 = DWVAL(2, 1);

    float s = 0.f, q = 0.f, mx = -INFINITY, mn = INFINITY;
    u16* orow = t2b + ((size_t)b * P + h * W) * C + gc;
    for (int w = 0; w < W; ++w) {
        float acc;
        acc = kk[0] * vm0;
        acc = fmaf(kk[1], vc0, acc);
        acc = fmaf(kk[2], vp0, acc);
        acc = fmaf(kk[3], vm1, acc);
        acc = fmaf(kk[4], vc1, acc);
        acc = fmaf(kk[5], vp1, acc);
        acc = fmaf(kk[6], vm2, acc);
        acc = fmaf(kk[7], vc2, acc);
        acc = fmaf(kk[8], vp2, acc);
        const float y = gelu_exact(acc);
        orow[(size_t)w * C] = f2bf(y);
        s += y;
        q = fmaf(y, y, q);
        mx = fmaxf(mx, y);
        mn = fminf(mn, y);
        vm0 = vc0; vc0 = vp0;
        vm1 = vc1; vc1 = vp1;
        vm2 = vc2; vc2 = vp2;
        if (w + 2 < W) {
            vp0 = DWVAL(0, w + 2);
            vp1 = DWVAL(1, w + 2);
            vp2 = DWVAL(2, w + 2);
        } else {
            vp0 = 0.f; vp1 = 0.f; vp2 = 0.f;
        }
    }
#undef DWVAL
    atomicAdd(&chsum2[gc], s);
    atomicAdd(&chsq2[gc], q);
    atomicAdd(&bsum2[b * C + gc], s);
    atomicMax(&umax2[b * C + gc], fkey(mx));
    atomicMax(&umaxn2[b * C + gc], fkey(-mn));
}

// ---------------- K8: channel attention + O(1) BN2 finalize (s_att only) ----------------
__global__ __launch_bounds__(1024) void chatt_kernel(const float* __restrict__ chsum2,
                                                     const float* __restrict__ chsq2,
                                                     const float* __restrict__ bsum2,
                                                     const u32* __restrict__ umax2,
                                                     const u32* __restrict__ umaxn2,
                                                     const float* __restrict__ g2,
                                                     const float* __restrict__ be2,
                                                     const float* __restrict__ caw1,
                                                     const float* __restrict__ caw2,
                                                     float* __restrict__ scale2,
                                                     float* __restrict__ shift2,
                                                     float* __restrict__ s_att) {
    const int b = blockIdx.x;
    const int t = threadIdx.x;          // channel
    const int wave = t >> 6, lane = t & 63;
    __shared__ float la[1024], lx[1024], ha[64], hm[64];
    {
        const float m = chsum2[t] * (1.0f / (float)M);
        const float var = chsq2[t] * (1.0f / (float)M) - m * m;
        const float rstd = rsqrtf(var + EPS);
        const float sc = rstd * g2[t];
        const float sh = be2[t] - m * sc;
        if (b == 0) { scale2[t] = sc; shift2[t] = sh; }
        la[t] = bsum2[b * C + t] * (1.0f / (float)P) * sc + sh;
        const float mx = fkeyinv(umax2[b * C + t]);
        const float mn = -fkeyinv(umaxn2[b * C + t]);
        lx[t] = (sc >= 0.f ? mx : mn) * sc + sh;
    }
    __syncthreads();
#pragma unroll
    for (int k = 0; k < 8; ++k) {
        const int u = wave * 8 + k;
        const int row = u & 63;
        const float* src = (u < 64) ? la : lx;
        const float4* wr = (const float4*)(caw1 + (size_t)row * C);
        float s = 0.f;
#pragma unroll
        for (int ch = 0; ch < 4; ++ch) {
            const float4 wv = wr[lane + 64 * ch];
            const float4 sv = *(const float4*)(src + 4 * lane + 256 * ch);
            s += wv.x * sv.x + wv.y * sv.y + wv.z * sv.z + wv.w * sv.w;
        }
#pragma unroll
        for (int off = 1; off < 64; off <<= 1) s += __shfl_xor(s, off);
        if (lane == 0) {
            s = fmaxf(s, 0.f);
            if (u < 64) ha[row] = s; else hm[row] = s;
        }
    }
    __syncthreads();
    {
        const float4* w2 = (const float4*)(caw2 + (size_t)t * 64);
        float s = 0.f;
#pragma unroll
        for (int j = 0; j < 16; ++j) {
            const float4 wv = w2[j];
            s += wv.x * (ha[j * 4 + 0] + hm[j * 4 + 0]);
            s += wv.y * (ha[j * 4 + 1] + hm[j * 4 + 1]);
            s += wv.z * (ha[j * 4 + 2] + hm[j * 4 + 2]);
            s += wv.w * (ha[j * 4 + 3] + hm[j * 4 + 3]);
        }
        s_att[b * C + t] = 1.0f / (1.0f + expf(-s));
    }
}

// ---------------- K9: fused {per-row avg/max of y} + {weight folding} ----------------
__global__ __launch_bounds__(256) void yqfold_kernel(const u16* __restrict__ t2b,
                                                     const float* __restrict__ scale2,
                                                     const float* __restrict__ shift2,
                                                     const float* __restrict__ s_att,
                                                     const float* __restrict__ pw,
                                                     float* __restrict__ avg_o,
                                                     float* __restrict__ max_o,
                                                     u16* __restrict__ pwb,
                                                     float* __restrict__ bias2) {
    const int bid = blockIdx.x;
    const int t = threadIdx.x;
    const int wave = t >> 6, lane = t & 63;
    __shared__ float r0[4], r1[4];
    if (bid < M) {
        const int row = bid;
        const int b = row >> 10;
        const int c0 = t * 4;
        const uint2 vv = *(const uint2*)(t2b + (size_t)row * C + c0);
        const float v0 = bf2f((u16)(vv.x & 0xffff));
        const float v1 = bf2f((u16)(vv.x >> 16));
        const float v2 = bf2f((u16)(vv.y & 0xffff));
        const float v3 = bf2f((u16)(vv.y >> 16));
        const float4 sc = *(const float4*)(scale2 + c0);
        const float4 sh = *(const float4*)(shift2 + c0);
        const float4 sa = *(const float4*)(s_att + (size_t)b * C + c0);
        const float y0 = fmaf(v0, sc.x, sh.x) * sa.x;
        const float y1 = fmaf(v1, sc.y, sh.y) * sa.y;
        const float y2 = fmaf(v2, sc.z, sh.z) * sa.z;
        const float y3 = fmaf(v3, sc.w, sh.w) * sa.w;
        float s = (y0 + y1) + (y2 + y3);
        float mx = fmaxf(fmaxf(y0, y1), fmaxf(y2, y3));
#pragma unroll
        for (int off = 32; off > 0; off >>= 1) {
            s += __shfl_down(s, off);
            mx = fmaxf(mx, __shfl_down(mx, off));
        }
        if (lane == 0) { r0[wave] = s; r1[wave] = mx; }
        __syncthreads();
        if (t == 0) {
            const float S = r0[0] + r0[1] + r0[2] + r0[3];
            const float Mx = fmaxf(fmaxf(r1[0], r1[1]), fmaxf(r1[2], r1[3]));
            avg_o[row] = S * (1.0f / (float)C);
            max_o[row] = Mx;
        }
    } else {
        const int bd = bid - M;          // 0..2047
        const int b = bd >> 8;
        const int d = bd & 255;
        const int c0 = t * 4;
        const float4 wv = *(const float4*)(pw + (size_t)d * C + c0);
        const float4 sc = *(const float4*)(scale2 + c0);
        const float4 sh = *(const float4*)(shift2 + c0);
        const float4 sa = *(const float4*)(s_att + (size_t)b * C + c0);
        uint2 o;
        o.x = ((u32)f2bf(wv.x * sc.x * sa.x)) | ((u32)f2bf(wv.y * sc.y * sa.y) << 16);
        o.y = ((u32)f2bf(wv.z * sc.z * sa.z)) | ((u32)f2bf(wv.w * sc.w * sa.w) << 16);
        *(uint2*)(pwb + ((size_t)b * D + d) * C + c0) = o;
        float s = wv.x * sh.x * sa.x + wv.y * sh.y * sa.y
                + wv.z * sh.z * sa.z + wv.w * sh.w * sa.w;
#pragma unroll
        for (int off = 1; off < 64; off <<= 1) s += __shfl_xor(s, off);
        if (lane == 0) r0[wave] = s;
        __syncthreads();
        if (t == 0) bias2[bd] = r0[0] + r0[1] + r0[2] + r0[3];
    }
}

// ---------------- K15: final residual add + fused BN3 stats ----------------
__global__ __launch_bounds__(256) void final_kernel(const float* __restrict__ x,
                                                    const float* __restrict__ pre,
                                                    const float* __restrict__ chsum3,
                                                    const float* __restrict__ chsq3,
                                                    const float* __restrict__ g3,
                                                    const float* __restrict__ be3,
                                                    float* __restrict__ out) {
    __shared__ float lsc[256], lsh[256];
    const int t = threadIdx.x;
    {
        const float m = chsum3[t] * (1.0f / (float)M);
        const float var = chsq3[t] * (1.0f / (float)M) - m * m;
        const float rstd = rsqrtf(var + EPS);
        const float sc = rstd * g3[t];
        lsc[t] = sc;
        lsh[t] = be3[t] - m * sc;
    }
    __syncthreads();
    const int i = blockIdx.x * 256 + t;   // float4 index
    const int e = i * 4;
    const int d = e & 255;
    const float4 xv = *(const float4*)(x + e);
    const float4 pv = *(const float4*)(pre + e);
    const float4 sc = *(const float4*)(lsc + d);
    const float4 sh = *(const float4*)(lsh + d);
    float4 o;
    o.x = xv.x + fmaf(pv.x, sc.x, sh.x);
    o.y = xv.y + fmaf(pv.y, sc.y, sh.y);
    o.z = xv.z + fmaf(pv.z, sc.z, sh.z);
    o.w = xv.w + fmaf(pv.w, sc.w, sh.w);
    *(float4*)(out + e) = o;
}

extern "C" void kernel_launch(void* const* d_in, const int* in_sizes, int n_in,
                              void* d_out, int out_size, void* d_ws, size_t ws_size,
                              hipStream_t stream) {
    const float* x    = (const float*)d_in[0];
    const float* w1   = (const float*)d_in[1];
    const float* b1   = (const float*)d_in[2];
    const float* g1   = (const float*)d_in[3];
    const float* be1  = (const float*)d_in[4];
    const float* aw1  = (const float*)d_in[5];
    const float* ab1  = (const float*)d_in[6];
    const float* aw2  = (const float*)d_in[7];
    const float* ab2  = (const float*)d_in[8];
    const float* g2   = (const float*)d_in[9];
    const float* be2  = (const float*)d_in[10];
    const float* caw1 = (const float*)d_in[11];
    const float* caw2 = (const float*)d_in[12];
    const float* pw   = (const float*)d_in[13];
    const float* pb   = (const float*)d_in[14];
    const float* g3   = (const float*)d_in[15];
    const float* be3  = (const float*)d_in[16];
    const float* sw   = (const float*)d_in[17];
    const float* sb   = (const float*)d_in[18];
    float* out = (float*)d_out;
    float* ws = (float*)d_ws;

    float* chsum1  = ws + WS_CHSUM1;
    float* chsq1   = ws + WS_CHSQ1;
    float* gapsum  = ws + WS_GAPSUM;
    float* chsum3  = ws + WS_CHSUM3;
    float* chsq3   = ws + WS_CHSQ3;
    float* chsum2  = ws + WS_CHSUM2;
    float* chsq2   = ws + WS_CHSQ2;
    float* bsum2   = ws + WS_BSUM2;
    u32*   umax2   = (u32*)(ws + WS_UMAX2);
    u32*   umaxn2  = (u32*)(ws + WS_UMAXN2);
    float* scale1  = ws + WS_SCALE1;
    float* shift1  = ws + WS_SHIFT1;
    float* kw      = ws + WS_KW;
    float* scale2  = ws + WS_SCALE2;
    float* shift2  = ws + WS_SHIFT2;
    float* s_att   = ws + WS_SATT;
    float* avg_o   = ws + WS_AVGO;
    float* max_o   = ws + WS_MAXO;
    float* pre     = ws + WS_PRE;
    float* bias2   = ws + WS_BIAS2;
    u16* t1b  = (u16*)(ws + WS_T1B);
    u16* t2b  = (u16*)(ws + WS_T2B);
    u16* xb   = (u16*)(ws + WS_XB);
    u16* w1b  = (u16*)(ws + WS_W1B);
    u16* pwbf = (u16*)(ws + WS_PWBF);

    // K0: zero accumulators + casts (x, w1)
    cvt_all_kernel<<<dim3(2304), 256, 0, stream>>>(x, w1, xb, w1b, ws);
    // K1: expand GEMM (128x64 tile, BK=32 3-buffer 2-deep pipeline). 1024 blocks,
    //     dyn LDS = 3*(128+64)*32*2 = 36864 B -> 4 blocks/CU
    mfma_gemm_kernel<256, 0, C, 128, 64><<<dim3(C / 64, M / 128), 256, 36864, stream>>>(
        xb, w1b, b1, nullptr, nullptr, nullptr, nullptr, nullptr,
        t1b, chsum1, chsq1, gapsum);
    // K4: BN1 stats + gap + dynamic kernel weights (fused)
    dynmlp_kernel<<<dim3(B), 1024, 0, stream>>>(chsum1, chsq1, gapsum, g1, be1,
                                                aw1, ab1, aw2, ab2, scale1, shift1, kw);
    // K5: depthwise conv (sliding-window regs, h-band XCD swizzle) -> bf16 t2, BN2 atomics
    dwconv_kernel<<<dim3(4, B * H), 256, 0, stream>>>(t1b, scale1, shift1, kw, t2b,
                                                      chsum2, chsq2, bsum2, umax2, umaxn2);
    // K8: BN2 finalize + channel attention (s_att only)
    chatt_kernel<<<dim3(B), 1024, 0, stream>>>(chsum2, chsq2, bsum2, umax2, umaxn2,
                                               g2, be2, caw1, caw2, scale2, shift2, s_att);
    // K9: fused yq (rows) + weight folding (b,d rows). 8192 + 2048 blocks.
    yqfold_kernel<<<dim3(M + B * D), 256, 0, stream>>>(t2b, scale2, shift2, s_att, pw,
                                                       avg_o, max_o, pwbf, bias2);
    // K12: project GEMM on folded weights, sp computed in-kernel from avg_o/max_o.
    //      Dyn LDS = 36864 staging (3 buf) + 896*4 ext = 40448 B; Cs (32KB) aliases staging
    mfma_gemm_kernel<1024, 1, D, 128, 64><<<dim3(D / 64, M / 128), 256, 40448, stream>>>(
        t2b, pwbf, bias2, pb, avg_o, max_o, sw, sb,
        pre, chsum3, chsq3, nullptr);
    // K15: BN3 stats + final residual add (fused)
    final_kernel<<<dim3((M * D / 4) / 256), 256, 0, stream>>>(x, pre, chsum3, chsq3, g3, be3, out);
}

// Round 9
// 197.606 us; speedup vs baseline: 5.4251x; 1.0065x over previous
//
#include <hip/hip_runtime.h>
#include <math.h>

// Problem constants
constexpr int B = 8;
constexpr int D = 256;     // model dim
constexpr int C = 1024;    // expanded channels
constexpr int H = 32, W = 32;
constexpr int P = H * W;            // 1024 spatial positions
constexpr int M = B * P;            // 8192 rows
constexpr float EPS = 1e-5f;

typedef unsigned short u16;
typedef unsigned int u32;
typedef __attribute__((ext_vector_type(8))) short short8;
typedef __attribute__((ext_vector_type(4))) float floatx4;

// ---------------- workspace layout (in floats) ----------------
constexpr size_t WS_CHSUM1 = 0;                  // 1024
constexpr size_t WS_CHSQ1  = 1024;               // 1024
constexpr size_t WS_GAPSUM = 2048;               // 8192
constexpr size_t WS_CHSUM3 = 10240;              // 256
constexpr size_t WS_CHSQ3  = 10496;              // 256
constexpr size_t WS_CHSUM2 = 10752;              // 1024
constexpr size_t WS_CHSQ2  = 11776;              // 1024
constexpr size_t WS_BSUM2  = 12800;              // 8192
constexpr size_t WS_UMAX2  = 20992;              // 8192 (u32 keys)
constexpr size_t WS_UMAXN2 = 29184;              // 8192 (u32 keys of -min)
constexpr size_t WS_ACC_COUNT = 37376;
constexpr size_t WS_SCALE1 = 37376;              // 1024
constexpr size_t WS_SHIFT1 = 38400;              // 1024
constexpr size_t WS_KW     = 39424;              // 256 (72 used)
constexpr size_t WS_SCALE2 = 39680;              // 1024
constexpr size_t WS_SHIFT2 = 40704;              // 1024
constexpr size_t WS_SATT   = 41728;              // 8192
constexpr size_t WS_AVGO   = 49920;              // 8192
constexpr size_t WS_MAXO   = 58112;              // 8192
constexpr size_t WS_SP     = 66304;              // (unused, kept for layout stability)
constexpr size_t WS_PRE    = 74496;              // 2097152
constexpr size_t WS_T1B    = 2171648;            // bf16 t1
constexpr size_t WS_T2B    = 6365952;            // bf16 t2
constexpr size_t WS_XB     = 10560256;           // bf16 x
constexpr size_t WS_W1B    = 11608832;
constexpr size_t WS_PWB    = 11739904;           // (unused, kept for layout stability)
constexpr size_t WS_PWBF   = 11870976;           // folded per-batch weights, 8x256x1024 bf16
constexpr size_t WS_BIAS2  = 12919552;           // 2048 floats (8x256), pb NOT included

__device__ __forceinline__ float gelu_exact(float v) {
    return 0.5f * v * (1.0f + erff(v * 0.70710678118654752440f));
}

__device__ __forceinline__ u16 f2bf(float f) {
    u32 u = __float_as_uint(f);
    u += 0x7fff + ((u >> 16) & 1);   // round-to-nearest-even
    return (u16)(u >> 16);
}

__device__ __forceinline__ float bf2f(u16 v) {
    return __uint_as_float(((u32)v) << 16);
}

// order-preserving float->u32 key
__device__ __forceinline__ u32 fkey(float f) {
    u32 u = __float_as_uint(f);
    return (u & 0x80000000u) ? ~u : (u | 0x80000000u);
}
__device__ __forceinline__ float fkeyinv(u32 k) {
    return __uint_as_float((k & 0x80000000u) ? (k ^ 0x80000000u) : ~k);
}

#define GLOAD(SRC, DST) __builtin_amdgcn_global_load_lds( \
    (const __attribute__((address_space(1))) void*)(SRC), \
    (__attribute__((address_space(3))) void*)(DST), 16, 0, 0)

// ---------------- K0: zero accumulators + cast fp32 -> bf16 for x, w1 ----------------
__global__ __launch_bounds__(256) void cvt_all_kernel(const float* __restrict__ x,
                                                      const float* __restrict__ w1,
                                                      u16* __restrict__ xb,
                                                      u16* __restrict__ w1b,
                                                      float* __restrict__ acc_zero) {
    const int i = blockIdx.x * 256 + threadIdx.x;     // grid covers 589824
    if (i < (int)WS_ACC_COUNT) acc_zero[i] = 0.f;     // 0x0 == fkey floor for max-keys too
    const float* src;
    u16* dst;
    int off;
    if (i < 524288) { src = x;  dst = xb;  off = i; }
    else            { src = w1; dst = w1b; off = i - 524288; }
    const float4 v = *(const float4*)(src + (size_t)off * 4);
    uint2 o;
    o.x = ((u32)f2bf(v.x)) | ((u32)f2bf(v.y) << 16);
    o.y = ((u32)f2bf(v.z)) | ((u32)f2bf(v.w) << 16);
    *(uint2*)(dst + (size_t)off * 4) = o;
}

// ---------------- MFMA bf16 GEMM — 3-buffer 2-deep pipeline + intra-block K-split -------
// WSPLIT=1 (gemm1): 256 threads, 4 waves, one pipeline over all NCH chunks.
// WSPLIT=2 (gemm2): 512 threads, 8 waves in 2 groups; group g pipelines K-range
//   [g*KD/2, (g+1)*KD/2) in its OWN 3-buffer LDS region (36864 B each). After the
//   K-loops, group 1 dumps acc through LDS, group 0 adds -> 4x the waves/CU vs the
//   256-thread version (which left 1 wave/SIMD — zero TLP).
// Per chunk: stage(c+2) -> vmcnt(6) -> barrier -> MFMA -> lgkmcnt(0) -> barrier.
// EPI 0: t = gelu(acc+bias); bf16 out; col stats + gsum.  Shared B, shared bias.
// EPI 1: t = sp*(acc+bias) + bias_post; fp32 out; col stats. PER-BATCH B (folded pwb).
//        sp (7x7 spatial conv + sigmoid) computed in-kernel from avg_o/max_o; lives in
//        LDS above all staging buffers (and above the 32KB epilogue Cs).
template<int KD, int EPI, int NS, int MB, int NB, int WSPLIT>
__global__ __launch_bounds__(256 * WSPLIT) void mfma_gemm_kernel(
    const u16* __restrict__ A,
    const u16* __restrict__ Bw,
    const float* __restrict__ bias,
    const float* __restrict__ bias_post,
    const float* __restrict__ avg_o,
    const float* __restrict__ max_o,
    const float* __restrict__ swp,
    const float* __restrict__ sbp,
    void* __restrict__ outv,
    float* __restrict__ csum,
    float* __restrict__ csq,
    float* __restrict__ gsum)
{
    constexpr int NT = 256 * WSPLIT;
    constexpr int MI = MB / 32;
    constexpr int NJ = NB / 32;
    constexpr int ABUF = MB * 32;
    constexpr int BBUF = NB * 32;
    constexpr int BUFSZ = ABUF + BBUF;
    constexpr int GA = MB / 64;
    constexpr int GB = NB / 64;
    constexpr int LD = GA + GB;
    static_assert(LD == 3, "vmcnt literals assume 3 loads per chunk");
    constexpr int NCH = KD / 32;
    constexpr int NCHG = NCH / WSPLIT;   // chunks per wave-group
    constexpr int GX = NS / NB;
    constexpr int NWG = (M / MB) * GX;   // %8 == 0 for both instantiations
    constexpr int CPX = NWG / 8;
    extern __shared__ u16 smem[];
    const int t = threadIdx.x;
    const int lane = t & 63;
    const int wv = t >> 6;
    const int grp = (WSPLIT == 2) ? (wv >> 2) : 0;
    const int wg = wv & 3;               // wave index within group
    const int tg = t & 255;              // thread index within group

    // XCD-chunked bijective block swizzle
    const int lin = blockIdx.y * GX + blockIdx.x;
    const int swz = (lin & 7) * CPX + (lin >> 3);
    const int bx = swz % GX;
    const int by = swz / GX;
    const int row0 = by * MB;
    const int col0 = bx * NB;
    const int bb = row0 >> 10;           // batch index (MB divides 1024)

    const int wrow = (wg >> 1) * (MB / 2);
    const int wcol = (wg & 1) * (NB / 2);
    const int lm = lane & 15;
    const int lk8 = (lane >> 4) * 8;
    const int srow = tg >> 2;
    const int scol = (tg & 3) * 8;
    const u16* gA = A + (size_t)(row0 + srow) * KD + scol;
    const u16* gB = Bw + (EPI == 1 ? (size_t)bb * NS * KD : (size_t)0)
                       + (size_t)(col0 + srow) * KD + scol;
    const float* biasp = bias + (EPI == 1 ? bb * NS : 0);

    u16* gsmem = smem + grp * (3 * BUFSZ);
    const int kbase = grp * NCHG;        // first chunk of this group's K-range

    const floatx4 zero = {0.f, 0.f, 0.f, 0.f};
    floatx4 acc[MI][NJ];
#pragma unroll
    for (int i = 0; i < MI; ++i)
#pragma unroll
        for (int j = 0; j < NJ; ++j) acc[i][j] = zero;

    auto stage = [&](u16* buf, int c) {
        const int kk = (kbase + c) * 32;
        u16* As = buf;
        u16* Bs = buf + ABUF;
#pragma unroll
        for (int g = 0; g < GA; ++g)
            GLOAD(gA + (size_t)g * 64 * KD + kk, As + g * 2048 + tg * 8);
#pragma unroll
        for (int g = 0; g < GB; ++g)
            GLOAD(gB + (size_t)g * 64 * KD + kk, Bs + g * 2048 + tg * 8);
    };
    auto compute = [&](const u16* buf) {
        const u16* As = buf;
        const u16* Bs = buf + ABUF;
        short8 af[MI], bf[NJ];
#pragma unroll
        for (int i = 0; i < MI; ++i)
            af[i] = *(const short8*)(As + (wrow + i * 16 + lm) * 32 + lk8);
#pragma unroll
        for (int j = 0; j < NJ; ++j)
            bf[j] = *(const short8*)(Bs + (wcol + j * 16 + lm) * 32 + lk8);
#pragma unroll
        for (int i = 0; i < MI; ++i)
#pragma unroll
            for (int j = 0; j < NJ; ++j)
                acc[i][j] = __builtin_amdgcn_mfma_f32_16x16x32_bf16(af[i], bf[j], acc[i][j], 0, 0, 0);
    };

    stage(gsmem, 0);
    if (NCHG > 1) stage(gsmem + BUFSZ, 1);

    // EPI1 prologue: compute sp for this block's 128 rows (4 h-rows of batch bb).
    // LDS ext region above all staging buffers: pa[320], pm[320], sw[98], sp@768[128].
    float* ext = (float*)(smem + (size_t)WSPLIT * 3 * BUFSZ);
    if constexpr (EPI == 1) {
        const int p0 = (by & 7) * MB;        // first pixel of tile (MB==128)
        const int h0 = p0 >> 5;              // first h row
        const int bbase = bb * P;
        for (int e = t; e < 640; e += NT) {
            const bool isM = e >= 320;
            const int idx = isM ? e - 320 : e;
            const int r = idx >> 5, w = idx & 31;
            const int hh = h0 - 3 + r;
            float v = 0.f;
            if (hh >= 0 && hh < H) v = (isM ? max_o : avg_o)[bbase + hh * W + w];
            ext[e] = v;
        }
        if (t < 98) ext[640 + t] = swp[t];
        __syncthreads();
        if (t < 128) {
            const int hl = t >> 5, w = t & 31;
            float a = sbp[0];
#pragma unroll
            for (int i = 0; i < 7; ++i) {
                const int r = hl + i;        // pa row (h0+hl+i-3), zero-padded out of range
#pragma unroll
                for (int j = 0; j < 7; ++j) {
                    const int ww = w + j - 3;
                    if (ww < 0 || ww >= W) continue;
                    a = fmaf(ext[640 + i * 7 + j], ext[r * 32 + ww], a);
                    a = fmaf(ext[640 + 49 + i * 7 + j], ext[320 + r * 32 + ww], a);
                }
            }
            ext[768 + t] = 1.0f / (1.0f + expf(-a));
        }
    }

    int cur = 0;
    for (int c = 0; c < NCHG; ++c) {
        if (c + 2 < NCHG) {
            const int nb3 = (cur + 2 >= 3) ? cur - 1 : cur + 2;
            stage(gsmem + nb3 * BUFSZ, c + 2);
            asm volatile("s_waitcnt vmcnt(6)" ::: "memory");
        } else if (c + 1 < NCHG) {
            asm volatile("s_waitcnt vmcnt(3)" ::: "memory");
        } else {
            asm volatile("s_waitcnt vmcnt(0)" ::: "memory");
        }
        __builtin_amdgcn_s_barrier();
        compute(gsmem + cur * BUFSZ);
        asm volatile("s_waitcnt lgkmcnt(0)" ::: "memory");
        __builtin_amdgcn_s_barrier();
        cur = (cur + 1 >= 3) ? 0 : cur + 1;
    }

    // K-split reduction: group 1 dumps acc via LDS (its own staging region), group 0 adds.
    if constexpr (WSPLIT == 2) {
        float* red = (float*)(smem + 3 * BUFSZ);   // 32KB fits in group1's 36864B region
        if (grp == 1) {
#pragma unroll
            for (int i = 0; i < MI; ++i)
#pragma unroll
                for (int r = 0; r < 4; ++r) {
                    const int lrow = wrow + i * 16 + (lane >> 4) * 4 + r;
#pragma unroll
                    for (int j = 0; j < NJ; ++j)
                        red[lrow * NB + wcol + j * 16 + lm] = acc[i][j][r];
                }
        }
        __syncthreads();
        if (grp == 0) {
#pragma unroll
            for (int i = 0; i < MI; ++i)
#pragma unroll
                for (int r = 0; r < 4; ++r) {
                    const int lrow = wrow + i * 16 + (lane >> 4) * 4 + r;
#pragma unroll
                    for (int j = 0; j < NJ; ++j)
                        acc[i][j][r] += red[lrow * NB + wcol + j * 16 + lm];
                }
        }
        __syncthreads();
    }

    float colsum[NJ], colsq[NJ];
#pragma unroll
    for (int j = 0; j < NJ; ++j) { colsum[j] = 0.f; colsq[j] = 0.f; }

    if (EPI == 0) {
        u16* Cs = smem;
#pragma unroll
        for (int i = 0; i < MI; ++i) {
#pragma unroll
            for (int r = 0; r < 4; ++r) {
                const int lrow = wrow + i * 16 + (lane >> 4) * 4 + r;
#pragma unroll
                for (int j = 0; j < NJ; ++j) {
                    const int lcol = wcol + j * 16 + lm;
                    const float tv = gelu_exact(acc[i][j][r] + biasp[col0 + lcol]);
                    Cs[lrow * NB + lcol] = f2bf(tv);
                    colsum[j] += tv;
                    colsq[j] = fmaf(tv, tv, colsq[j]);
                }
            }
        }
        __syncthreads();
        constexpr int TPR = NB / 8;
        constexpr int RPP = NT / TPR;
        u16* outp = (u16*)outv;
#pragma unroll
        for (int pp = 0; pp < MB / RPP; ++pp) {
            const int r = pp * RPP + t / TPR;
            const int cc = (t % TPR) * 8;
            *(uint4*)(outp + (size_t)(row0 + r) * NS + col0 + cc) =
                *(const uint4*)(Cs + r * NB + cc);
        }
    } else {
        float* Cs = (float*)smem;            // 32KB at base; ext and red are above it
        if (grp == 0) {
#pragma unroll
            for (int i = 0; i < MI; ++i) {
#pragma unroll
                for (int r = 0; r < 4; ++r) {
                    const int lrow = wrow + i * 16 + (lane >> 4) * 4 + r;
                    const float rs = ext[768 + lrow];
#pragma unroll
                    for (int j = 0; j < NJ; ++j) {
                        const int lcol = wcol + j * 16 + lm;
                        const float tv = rs * (acc[i][j][r] + biasp[col0 + lcol])
                                       + bias_post[col0 + lcol];
                        Cs[lrow * NB + lcol] = tv;
                        colsum[j] += tv;
                        colsq[j] = fmaf(tv, tv, colsq[j]);
                    }
                }
            }
        }
        __syncthreads();
        constexpr int TPR = NB / 4;
        constexpr int RPP = NT / TPR;
        float* outp = (float*)outv;
#pragma unroll
        for (int pp = 0; pp < MB / RPP; ++pp) {
            const int r = pp * RPP + t / TPR;
            const int cc = (t % TPR) * 4;
            *(float4*)(outp + (size_t)(row0 + r) * NS + col0 + cc) =
                *(const float4*)(Cs + r * NB + cc);
        }
    }

#pragma unroll
    for (int j = 0; j < NJ; ++j) {
        float s = colsum[j];
        float q = colsq[j];
        s += __shfl_xor(s, 16); s += __shfl_xor(s, 32);
        q += __shfl_xor(q, 16); q += __shfl_xor(q, 32);
        if (grp == 0 && lane < 16) {
            const int c = col0 + wcol + j * 16 + lm;
            atomicAdd(&csum[c], s);
            atomicAdd(&csq[c], q);
            if (EPI == 0) atomicAdd(&gsum[bb * NS + c], s);
        }
    }
}

// ---------------- K4: dynamic kernel MLP + fused BN1 stats ----------------
__global__ __launch_bounds__(1024) void dynmlp_kernel(const float* __restrict__ chsum1,
                                                      const float* __restrict__ chsq1,
                                                      const float* __restrict__ gapsum,
                                                      const float* __restrict__ g1,
                                                      const float* __restrict__ be1,
                                                      const float* __restrict__ aw1,
                                                      const float* __restrict__ ab1,
                                                      const float* __restrict__ aw2,
                                                      const float* __restrict__ ab2,
                                                      float* __restrict__ scale1,
                                                      float* __restrict__ shift1,
                                                      float* __restrict__ kw) {
    const int b = blockIdx.x;
    const int t = threadIdx.x;
    const int wave = t >> 6, lane = t & 63;
    __shared__ float g[1024];
    __shared__ float h1[128];
    __shared__ float logits[12];
    {
        const float m = chsum1[t] * (1.0f / (float)M);
        const float var = chsq1[t] * (1.0f / (float)M) - m * m;
        const float rstd = rsqrtf(var + EPS);
        const float sc = rstd * g1[t];
        const float sh = be1[t] - m * sc;
        if (b == 0) { scale1[t] = sc; shift1[t] = sh; }
        g[t] = gapsum[b * C + t] * (1.0f / (float)P) * sc + sh;
    }
    __syncthreads();
#pragma unroll
    for (int k = 0; k < 8; ++k) {
        const int u = wave * 8 + k;
        const float4* wr = (const float4*)(aw1 + (size_t)u * C);
        float s = 0.f;
#pragma unroll
        for (int ch = 0; ch < 4; ++ch) {
            const float4 wv = wr[lane + 64 * ch];
            const float4 sv = *(const float4*)(g + 4 * lane + 256 * ch);
            s += wv.x * sv.x + wv.y * sv.y + wv.z * sv.z + wv.w * sv.w;
        }
#pragma unroll
        for (int off = 1; off < 64; off <<= 1) s += __shfl_xor(s, off);
        if (lane == 0) h1[u] = fmaxf(s + ab1[u], 0.f);
    }
    __syncthreads();
    if (wave < 9) {
        float s = aw2[wave * 128 + lane] * h1[lane]
                + aw2[wave * 128 + 64 + lane] * h1[64 + lane];
#pragma unroll
        for (int off = 1; off < 64; off <<= 1) s += __shfl_xor(s, off);
        if (lane == 0) logits[wave] = s + ab2[wave];
    }
    __syncthreads();
    if (t == 0) {
        float mx = logits[0];
        for (int i = 1; i < 9; ++i) mx = fmaxf(mx, logits[i]);
        float e[9], den = 0.f;
        for (int i = 0; i < 9; ++i) { e[i] = expf(logits[i] - mx); den += e[i]; }
        const float inv = 1.0f / den;
        for (int i = 0; i < 9; ++i) kw[b * 9 + i] = e[i] * inv;
    }
}

// ---------------- K5: dyn depthwise conv — sliding-window regs, h-band XCD swizzle ------
__global__ __launch_bounds__(256) void dwconv_kernel(const u16* __restrict__ t1b,
                                                     const float* __restrict__ scale1,
                                                     const float* __restrict__ shift1,
                                                     const float* __restrict__ kw,
                                                     u16* __restrict__ t2b,
                                                     float* __restrict__ chsum2,
                                                     float* __restrict__ chsq2,
                                                     float* __restrict__ bsum2,
                                                     u32* __restrict__ umax2,
                                                     u32* __restrict__ umaxn2) {
    __shared__ u16 rows[3 * 32 * 256];   // 48 KB: [r][w][ch]
    const int lin = blockIdx.y * 4 + blockIdx.x;     // nwg = 1024
    const int xcd = lin & 7;
    const int i7 = lin >> 3;             // 0..127
    const int b = i7 >> 4;
    const int r4 = i7 & 15;
    const int h = xcd * 4 + (r4 >> 2);
    const int cq = r4 & 3;
    const int t = threadIdx.x;

    const u16* gbase = t1b + (size_t)b * P * C + cq * 256;
#pragma unroll
    for (int i = 0; i < 12; ++i) {
        const int lin2 = i * 256 + t;
        const int chunk = lin2 >> 5;
        const int r = chunk >> 5;
        const int w = chunk & 31;
        const int off8 = (lin2 & 31) * 8;
        const int hr = h + r - 1;
        uint4 v = {0u, 0u, 0u, 0u};
        if (hr >= 0 && hr < H)
            v = *(const uint4*)(gbase + (size_t)(hr * W + w) * C + off8);
        *(uint4*)(&rows[chunk * 256 + off8]) = v;
    }
    __syncthreads();

    const int c = t;
    const int gc = cq * 256 + c;
    float kk[9];
#pragma unroll
    for (int i = 0; i < 9; ++i) kk[i] = kw[b * 9 + i];
    const float sc = scale1[gc];
    const float sh = shift1[gc];
    float scm[3], shm[3];
    scm[0] = (h > 0)     ? sc : 0.f;  shm[0] = (h > 0)     ? sh : 0.f;
    scm[1] = sc;                      shm[1] = sh;
    scm[2] = (h < H - 1) ? sc : 0.f;  shm[2] = (h < H - 1) ? sh : 0.f;

    const u16* rp0 = rows + c;
#define DWVAL(ri, w) fmaf(bf2f(rp0[((ri) * 32 + (w)) * 256]), scm[ri], shm[ri])

    float vm0 = 0.f, vm1 = 0.f, vm2 = 0.f;
    float vc0 = DWVAL(0, 0), vc1 = DWVAL(1, 0), vc2 = DWVAL(2, 0);
    float vp0 = DWVAL(0, 1), vp1 = DWVAL(1, 1), vp2 = DWVAL(2, 1);

    float s = 0.f, q = 0.f, mx = -INFINITY, mn = INFINITY;
    u16* orow = t2b + ((size_t)b * P + h * W) * C + gc;
    for (int w = 0; w < W; ++w) {
        float acc;
        acc = kk[0] * vm0;
        acc = fmaf(kk[1], vc0, acc);
        acc = fmaf(kk[2], vp0, acc);
        acc = fmaf(kk[3], vm1, acc);
        acc = fmaf(kk[4], vc1, acc);
        acc = fmaf(kk[5], vp1, acc);
        acc = fmaf(kk[6], vm2, acc);
        acc = fmaf(kk[7], vc2, acc);
        acc = fmaf(kk[8], vp2, acc);
        const float y = gelu_exact(acc);
        orow[(size_t)w * C] = f2bf(y);
        s += y;
        q = fmaf(y, y, q);
        mx = fmaxf(mx, y);
        mn = fminf(mn, y);
        vm0 = vc0; vc0 = vp0;
        vm1 = vc1; vc1 = vp1;
        vm2 = vc2; vc2 = vp2;
        if (w + 2 < W) {
            vp0 = DWVAL(0, w + 2);
            vp1 = DWVAL(1, w + 2);
            vp2 = DWVAL(2, w + 2);
        } else {
            vp0 = 0.f; vp1 = 0.f; vp2 = 0.f;
        }
    }
#undef DWVAL
    atomicAdd(&chsum2[gc], s);
    atomicAdd(&chsq2[gc], q);
    atomicAdd(&bsum2[b * C + gc], s);
    atomicMax(&umax2[b * C + gc], fkey(mx));
    atomicMax(&umaxn2[b * C + gc], fkey(-mn));
}

// ---------------- K8: channel attention + O(1) BN2 finalize (s_att only) ----------------
__global__ __launch_bounds__(1024) void chatt_kernel(const float* __restrict__ chsum2,
                                                     const float* __restrict__ chsq2,
                                                     const float* __restrict__ bsum2,
                                                     const u32* __restrict__ umax2,
                                                     const u32* __restrict__ umaxn2,
                                                     const float* __restrict__ g2,
                                                     const float* __restrict__ be2,
                                                     const float* __restrict__ caw1,
                                                     const float* __restrict__ caw2,
                                                     float* __restrict__ scale2,
                                                     float* __restrict__ shift2,
                                                     float* __restrict__ s_att) {
    const int b = blockIdx.x;
    const int t = threadIdx.x;          // channel
    const int wave = t >> 6, lane = t & 63;
    __shared__ float la[1024], lx[1024], ha[64], hm[64];
    {
        const float m = chsum2[t] * (1.0f / (float)M);
        const float var = chsq2[t] * (1.0f / (float)M) - m * m;
        const float rstd = rsqrtf(var + EPS);
        const float sc = rstd * g2[t];
        const float sh = be2[t] - m * sc;
        if (b == 0) { scale2[t] = sc; shift2[t] = sh; }
        la[t] = bsum2[b * C + t] * (1.0f / (float)P) * sc + sh;
        const float mx = fkeyinv(umax2[b * C + t]);
        const float mn = -fkeyinv(umaxn2[b * C + t]);
        lx[t] = (sc >= 0.f ? mx : mn) * sc + sh;
    }
    __syncthreads();
#pragma unroll
    for (int k = 0; k < 8; ++k) {
        const int u = wave * 8 + k;
        const int row = u & 63;
        const float* src = (u < 64) ? la : lx;
        const float4* wr = (const float4*)(caw1 + (size_t)row * C);
        float s = 0.f;
#pragma unroll
        for (int ch = 0; ch < 4; ++ch) {
            const float4 wv = wr[lane + 64 * ch];
            const float4 sv = *(const float4*)(src + 4 * lane + 256 * ch);
            s += wv.x * sv.x + wv.y * sv.y + wv.z * sv.z + wv.w * sv.w;
        }
#pragma unroll
        for (int off = 1; off < 64; off <<= 1) s += __shfl_xor(s, off);
        if (lane == 0) {
            s = fmaxf(s, 0.f);
            if (u < 64) ha[row] = s; else hm[row] = s;
        }
    }
    __syncthreads();
    {
        const float4* w2 = (const float4*)(caw2 + (size_t)t * 64);
        float s = 0.f;
#pragma unroll
        for (int j = 0; j < 16; ++j) {
            const float4 wv = w2[j];
            s += wv.x * (ha[j * 4 + 0] + hm[j * 4 + 0]);
            s += wv.y * (ha[j * 4 + 1] + hm[j * 4 + 1]);
            s += wv.z * (ha[j * 4 + 2] + hm[j * 4 + 2]);
            s += wv.w * (ha[j * 4 + 3] + hm[j * 4 + 3]);
        }
        s_att[b * C + t] = 1.0f / (1.0f + expf(-s));
    }
}

// ---------------- K9: fused {per-row avg/max of y} + {weight folding} ----------------
__global__ __launch_bounds__(256) void yqfold_kernel(const u16* __restrict__ t2b,
                                                     const float* __restrict__ scale2,
                                                     const float* __restrict__ shift2,
                                                     const float* __restrict__ s_att,
                                                     const float* __restrict__ pw,
                                                     float* __restrict__ avg_o,
                                                     float* __restrict__ max_o,
                                                     u16* __restrict__ pwb,
                                                     float* __restrict__ bias2) {
    const int bid = blockIdx.x;
    const int t = threadIdx.x;
    const int wave = t >> 6, lane = t & 63;
    __shared__ float r0[4], r1[4];
    if (bid < M) {
        const int row = bid;
        const int b = row >> 10;
        const int c0 = t * 4;
        const uint2 vv = *(const uint2*)(t2b + (size_t)row * C + c0);
        const float v0 = bf2f((u16)(vv.x & 0xffff));
        const float v1 = bf2f((u16)(vv.x >> 16));
        const float v2 = bf2f((u16)(vv.y & 0xffff));
        const float v3 = bf2f((u16)(vv.y >> 16));
        const float4 sc = *(const float4*)(scale2 + c0);
        const float4 sh = *(const float4*)(shift2 + c0);
        const float4 sa = *(const float4*)(s_att + (size_t)b * C + c0);
        const float y0 = fmaf(v0, sc.x, sh.x) * sa.x;
        const float y1 = fmaf(v1, sc.y, sh.y) * sa.y;
        const float y2 = fmaf(v2, sc.z, sh.z) * sa.z;
        const float y3 = fmaf(v3, sc.w, sh.w) * sa.w;
        float s = (y0 + y1) + (y2 + y3);
        float mx = fmaxf(fmaxf(y0, y1), fmaxf(y2, y3));
#pragma unroll
        for (int off = 32; off > 0; off >>= 1) {
            s += __shfl_down(s, off);
            mx = fmaxf(mx, __shfl_down(mx, off));
        }
        if (lane == 0) { r0[wave] = s; r1[wave] = mx; }
        __syncthreads();
        if (t == 0) {
            const float S = r0[0] + r0[1] + r0[2] + r0[3];
            const float Mx = fmaxf(fmaxf(r1[0], r1[1]), fmaxf(r1[2], r1[3]));
            avg_o[row] = S * (1.0f / (float)C);
            max_o[row] = Mx;
        }
    } else {
        const int bd = bid - M;          // 0..2047
        const int b = bd >> 8;
        const int d = bd & 255;
        const int c0 = t * 4;
        const float4 wv = *(const float4*)(pw + (size_t)d * C + c0);
        const float4 sc = *(const float4*)(scale2 + c0);
        const float4 sh = *(const float4*)(shift2 + c0);
        const float4 sa = *(const float4*)(s_att + (size_t)b * C + c0);
        uint2 o;
        o.x = ((u32)f2bf(wv.x * sc.x * sa.x)) | ((u32)f2bf(wv.y * sc.y * sa.y) << 16);
        o.y = ((u32)f2bf(wv.z * sc.z * sa.z)) | ((u32)f2bf(wv.w * sc.w * sa.w) << 16);
        *(uint2*)(pwb + ((size_t)b * D + d) * C + c0) = o;
        float s = wv.x * sh.x * sa.x + wv.y * sh.y * sa.y
                + wv.z * sh.z * sa.z + wv.w * sh.w * sa.w;
#pragma unroll
        for (int off = 1; off < 64; off <<= 1) s += __shfl_xor(s, off);
        if (lane == 0) r0[wave] = s;
        __syncthreads();
        if (t == 0) bias2[bd] = r0[0] + r0[1] + r0[2] + r0[3];
    }
}

// ---------------- K15: final residual add + fused BN3 stats ----------------
__global__ __launch_bounds__(256) void final_kernel(const float* __restrict__ x,
                                                    const float* __restrict__ pre,
                                                    const float* __restrict__ chsum3,
                                                    const float* __restrict__ chsq3,
                                                    const float* __restrict__ g3,
                                                    const float* __restrict__ be3,
                                                    float* __restrict__ out) {
    __shared__ float lsc[256], lsh[256];
    const int t = threadIdx.x;
    {
        const float m = chsum3[t] * (1.0f / (float)M);
        const float var = chsq3[t] * (1.0f / (float)M) - m * m;
        const float rstd = rsqrtf(var + EPS);
        const float sc = rstd * g3[t];
        lsc[t] = sc;
        lsh[t] = be3[t] - m * sc;
    }
    __syncthreads();
    const int i = blockIdx.x * 256 + t;   // float4 index
    const int e = i * 4;
    const int d = e & 255;
    const float4 xv = *(const float4*)(x + e);
    const float4 pv = *(const float4*)(pre + e);
    const float4 sc = *(const float4*)(lsc + d);
    const float4 sh = *(const float4*)(lsh + d);
    float4 o;
    o.x = xv.x + fmaf(pv.x, sc.x, sh.x);
    o.y = xv.y + fmaf(pv.y, sc.y, sh.y);
    o.z = xv.z + fmaf(pv.z, sc.z, sh.z);
    o.w = xv.w + fmaf(pv.w, sc.w, sh.w);
    *(float4*)(out + e) = o;
}

extern "C" void kernel_launch(void* const* d_in, const int* in_sizes, int n_in,
                              void* d_out, int out_size, void* d_ws, size_t ws_size,
                              hipStream_t stream) {
    const float* x    = (const float*)d_in[0];
    const float* w1   = (const float*)d_in[1];
    const float* b1   = (const float*)d_in[2];
    const float* g1   = (const float*)d_in[3];
    const float* be1  = (const float*)d_in[4];
    const float* aw1  = (const float*)d_in[5];
    const float* ab1  = (const float*)d_in[6];
    const float* aw2  = (const float*)d_in[7];
    const float* ab2  = (const float*)d_in[8];
    const float* g2   = (const float*)d_in[9];
    const float* be2  = (const float*)d_in[10];
    const float* caw1 = (const float*)d_in[11];
    const float* caw2 = (const float*)d_in[12];
    const float* pw   = (const float*)d_in[13];
    const float* pb   = (const float*)d_in[14];
    const float* g3   = (const float*)d_in[15];
    const float* be3  = (const float*)d_in[16];
    const float* sw   = (const float*)d_in[17];
    const float* sb   = (const float*)d_in[18];
    float* out = (float*)d_out;
    float* ws = (float*)d_ws;

    float* chsum1  = ws + WS_CHSUM1;
    float* chsq1   = ws + WS_CHSQ1;
    float* gapsum  = ws + WS_GAPSUM;
    float* chsum3  = ws + WS_CHSUM3;
    float* chsq3   = ws + WS_CHSQ3;
    float* chsum2  = ws + WS_CHSUM2;
    float* chsq2   = ws + WS_CHSQ2;
    float* bsum2   = ws + WS_BSUM2;
    u32*   umax2   = (u32*)(ws + WS_UMAX2);
    u32*   umaxn2  = (u32*)(ws + WS_UMAXN2);
    float* scale1  = ws + WS_SCALE1;
    float* shift1  = ws + WS_SHIFT1;
    float* kw      = ws + WS_KW;
    float* scale2  = ws + WS_SCALE2;
    float* shift2  = ws + WS_SHIFT2;
    float* s_att   = ws + WS_SATT;
    float* avg_o   = ws + WS_AVGO;
    float* max_o   = ws + WS_MAXO;
    float* pre     = ws + WS_PRE;
    float* bias2   = ws + WS_BIAS2;
    u16* t1b  = (u16*)(ws + WS_T1B);
    u16* t2b  = (u16*)(ws + WS_T2B);
    u16* xb   = (u16*)(ws + WS_XB);
    u16* w1b  = (u16*)(ws + WS_W1B);
    u16* pwbf = (u16*)(ws + WS_PWBF);

    // K0: zero accumulators + casts (x, w1)
    cvt_all_kernel<<<dim3(2304), 256, 0, stream>>>(x, w1, xb, w1b, ws);
    // K1: expand GEMM (128x64 tile, BK=32 3-buffer 2-deep pipeline). 1024 blocks,
    //     dyn LDS = 3*(128+64)*32*2 = 36864 B -> 4 blocks/CU, 16 waves/CU
    mfma_gemm_kernel<256, 0, C, 128, 64, 1><<<dim3(C / 64, M / 128), 256, 36864, stream>>>(
        xb, w1b, b1, nullptr, nullptr, nullptr, nullptr, nullptr,
        t1b, chsum1, chsq1, gapsum);
    // K4: BN1 stats + gap + dynamic kernel weights (fused)
    dynmlp_kernel<<<dim3(B), 1024, 0, stream>>>(chsum1, chsq1, gapsum, g1, be1,
                                                aw1, ab1, aw2, ab2, scale1, shift1, kw);
    // K5: depthwise conv (sliding-window regs, h-band XCD swizzle) -> bf16 t2, BN2 atomics
    dwconv_kernel<<<dim3(4, B * H), 256, 0, stream>>>(t1b, scale1, shift1, kw, t2b,
                                                      chsum2, chsq2, bsum2, umax2, umaxn2);
    // K8: BN2 finalize + channel attention (s_att only)
    chatt_kernel<<<dim3(B), 1024, 0, stream>>>(chsum2, chsq2, bsum2, umax2, umaxn2,
                                               g2, be2, caw1, caw2, scale2, shift2, s_att);
    // K9: fused yq (rows) + weight folding (b,d rows). 8192 + 2048 blocks.
    yqfold_kernel<<<dim3(M + B * D), 256, 0, stream>>>(t2b, scale2, shift2, s_att, pw,
                                                       avg_o, max_o, pwbf, bias2);
    // K12: project GEMM, 512-thread blocks, intra-block K-split (2 groups x 16 chunks).
    //      256 blocks -> 2 blocks/CU, 16 waves/CU (was 4). Dyn LDS = 2*36864 + 3584 = 77312 B
    mfma_gemm_kernel<1024, 1, D, 128, 64, 2><<<dim3(D / 64, M / 128), 512, 77312, stream>>>(
        t2b, pwbf, bias2, pb, avg_o, max_o, sw, sb,
        pre, chsum3, chsq3, nullptr);
    // K15: BN3 stats + final residual add (fused)
    final_kernel<<<dim3((M * D / 4) / 256), 256, 0, stream>>>(x, pre, chsum3, chsq3, g3, be3, out);
}